// Round 3
// baseline (732.959 us; speedup 1.0000x reference)
//
#include <hip/hip_runtime.h>
#include <hip/hip_bf16.h>

// ---------------------------------------------------------------------------
// DeltaNet forward, round 10 (r9 resubmit + fold precision hardening):
//  - Native CHUNK=128 delta scan: T128 composed from the 32x32 T's via
//    block forward substitution (B_ij = -T_i (sum_m G_im B_mj), G = kb kn^T),
//    folded into w/u in prep:  w~ = w + sum B_ij kb_j, u~ = u + sum B_ij vb_j
//    (fold products now hi/lo 3-MFMA, matching r8's verified precision).
//    attn is a precomputed 128x128 block-tril matrix (hi/lo bf16),
//    off-diag blocks = q_i kn_j^T (== r8's Y matrices, same precision).
//  - chain: 16 serial iterations, 2 raw (lgkm-only) barriers each
//    (was 32 iters x 3 barriers): u2 for all 128 rows in one pass, one
//    S writeback per 128 tokens. kn frags hoisted to iteration top.
//  - r9 bench was an infra failure (container died, no counters); source
//    audited for OOB/deadlock/alignment -- none found.
// ---------------------------------------------------------------------------

#define DEVI __device__ __forceinline__
typedef unsigned int u32;
typedef unsigned short ushort_t;
typedef __attribute__((ext_vector_type(8))) short short8;
typedef __attribute__((ext_vector_type(4))) float floatx4;

constexpr int Ls = 2048, NH = 4;

// workspace offsets (floats)
constexpr size_t off_xq   = 0;         // x3 [m][3072] cols 0-1023 -> kn_bf -> firs
constexpr size_t off_xk   = 4194304;   // x3 cols 1024-2047 -> firl
constexpr size_t off_xv   = 8388608;   // x3 cols 2048-3071 -> u -> o_bf
constexpr size_t off_q    = 12582912;  // qn -> delta
constexpr size_t off_k    = 16777216;  // kn -> w1_t (bf16)
constexpr size_t off_v    = 20971520;  // v (alive to the end)
constexpr size_t off_beta = 25165824;  // beta -> Wo_t (bf16, spans into T_g)
constexpr size_t off_attn = 25182208;  // T_g (f32, 524288) -> dead after group_prep
constexpr size_t off_firs = 25706496;  // x_bf -> {wn_bf, q_bf} (bf16)
constexpr size_t off_firl = 29900800;  // Wqkv_t -> knT_bf (bf16)
constexpr size_t off_gin  = 34095104;  // kb (f32) -> gin_bf
constexpr size_t off_mlph = 38420480;  // vb (f32) -> mlph_bf
constexpr size_t off_at   = 42614784;  // attn128 hi (1048576 fl) + lo (1048576 fl)
constexpr size_t off_gates= 46809088;  // gates

DEVI float sigmoidf_(float x) { return 1.f / (1.f + expf(-x)); }
DEVI float siluf_(float x) { return x / (1.f + expf(-x)); }
DEVI float geluf_(float x) { return 0.5f * x * (1.f + erff(x * 0.7071067811865476f)); }
DEVI ushort_t f2bf(float f) {
  union { float f; u32 u; } c{f};
  u32 r = (c.u + 0x7fffu + ((c.u >> 16) & 1u)) >> 16;
  return (ushort_t)r;
}
DEVI float bf2f(ushort_t h) {
  union { u32 u; float f; } c; c.u = ((u32)h) << 16; return c.f;
}
DEVI void cvt8(float4 a, float4 b, short8& hi, short8& lo) {
  float f[8] = {a.x,a.y,a.z,a.w,b.x,b.y,b.z,b.w};
#pragma unroll
  for (int j = 0; j < 8; ++j) {
    ushort_t h = f2bf(f[j]);
    hi[j] = (short)h;
    lo[j] = (short)f2bf(f[j] - bf2f(h));
  }
}
DEVI void async16(const void* g, void* l) {
  __builtin_amdgcn_global_load_lds(
      (const u32 __attribute__((address_space(1)))*)g,
      (u32 __attribute__((address_space(3)))*)l, 16, 0, 0);
}
// Raw workgroup barrier: waits LDS ops only (lgkmcnt); global loads/stores
// stay in flight (all cross-wave deps in the chain loop are LDS-only).
DEVI void wave_barrier() {
  __builtin_amdgcn_sched_barrier(0);
  asm volatile("s_waitcnt lgkmcnt(0)" ::: "memory");
  __builtin_amdgcn_s_barrier();
  __builtin_amdgcn_sched_barrier(0);
}

// ---------------- f32 -> bf16 ----------------------------------------------
__global__ __launch_bounds__(256) void to_bf16(
    const float* __restrict__ in, ushort_t* __restrict__ out, int n)
{
  int i = (blockIdx.x * 256 + threadIdx.x) * 8;
  if (i >= n) return;
  float4 a = *(const float4*)(in + i);
  float4 b = *(const float4*)(in + i + 4);
  ushort_t o[8] = { f2bf(a.x), f2bf(a.y), f2bf(a.z), f2bf(a.w),
                    f2bf(b.x), f2bf(b.y), f2bf(b.z), f2bf(b.w) };
  *(uint4*)(out + i) = *(uint4*)o;
}

// ---------------- f32 [K][N] -> bf16 [N][K] --------------------------------
__global__ __launch_bounds__(256) void convT(
    const float* __restrict__ W, ushort_t* __restrict__ out, int Kq, int Nq)
{
  __shared__ ushort_t tile[32][33];
  int n0 = blockIdx.x * 32, k0 = blockIdx.y * 32;
  int tx = threadIdx.x & 31, ty = threadIdx.x >> 5;
#pragma unroll
  for (int r = 0; r < 32; r += 8)
    tile[ty + r][tx] = f2bf(W[(size_t)(k0 + ty + r) * Nq + n0 + tx]);
  __syncthreads();
#pragma unroll
  for (int r = 0; r < 32; r += 8)
    out[(size_t)(n0 + ty + r) * Kq + k0 + tx] = tile[tx][ty + r];
}

// ---------------- bf16 MFMA GEMM -------------------------------------------
__global__ __launch_bounds__(256) void gemm_bf16(
    const ushort_t* __restrict__ A, const ushort_t* __restrict__ Bt,
    float* __restrict__ C, int Nq, int Kq,
    const float* __restrict__ bias, int act, int outbf)
{
  __shared__ ushort_t As[128 * 32];
  __shared__ ushort_t Bs[128 * 32];
  int t = threadIdx.x;
  int w = t >> 6, lane = t & 63;
  int m0 = blockIdx.y * 128, n0 = blockIdx.x * 128;
  floatx4 acc[4][4];
#pragma unroll
  for (int i = 0; i < 4; ++i)
#pragma unroll
    for (int j = 0; j < 4; ++j)
#pragma unroll
      for (int r = 0; r < 4; ++r) acc[i][j][r] = 0.f;

  int lrow = lane >> 2, lk8 = (lane & 3) * 8;
  for (int kt = 0; kt < Kq; kt += 32) {
#pragma unroll
    for (int r = 0; r < 2; ++r) {
      int seg = w * 2 + r;
      int row = seg * 16 + lrow;
      async16(A  + (size_t)(m0 + row) * Kq + kt + lk8, &As[seg * 512]);
      async16(Bt + (size_t)(n0 + row) * Kq + kt + lk8, &Bs[seg * 512]);
    }
    __syncthreads();
    short8 af[4], bf[4];
#pragma unroll
    for (int i = 0; i < 4; ++i) {
      int row = (w >> 1) * 64 + i * 16 + (lane & 15);
      af[i] = *(const short8*)&As[row * 32 + (lane >> 4) * 8];
    }
#pragma unroll
    for (int j = 0; j < 4; ++j) {
      int col = (w & 1) * 64 + j * 16 + (lane & 15);
      bf[j] = *(const short8*)&Bs[col * 32 + (lane >> 4) * 8];
    }
#pragma unroll
    for (int i = 0; i < 4; ++i)
#pragma unroll
      for (int j = 0; j < 4; ++j)
        acc[i][j] = __builtin_amdgcn_mfma_f32_16x16x32_bf16(af[i], bf[j], acc[i][j], 0, 0, 0);
    __syncthreads();
  }
#pragma unroll
  for (int i = 0; i < 4; ++i) {
    int rbase = m0 + (w >> 1) * 64 + i * 16 + ((lane >> 4) << 2);
#pragma unroll
    for (int j = 0; j < 4; ++j) {
      int col = n0 + (w & 1) * 64 + j * 16 + (lane & 15);
      float bv = act ? bias[col] : 0.f;
#pragma unroll
      for (int r = 0; r < 4; ++r) {
        float v = acc[i][j][r];
        if (act) v = geluf_(v + bv);
        if (outbf) ((ushort_t*)C)[(size_t)(rbase + r) * Nq + col] = f2bf(v);
        else       C[(size_t)(rbase + r) * Nq + col] = v;
      }
    }
  }
}

// ---------------- beta = sigmoid(x @ Wb) -----------------------------------
__global__ __launch_bounds__(256) void beta_sigmoid(
    const float* __restrict__ x, const float* __restrict__ Wb,
    float* __restrict__ beta)
{
  int mtok = blockIdx.x, t = threadIdx.x;
  int b = mtok >> 11, l = mtok & 2047;
  float a0 = 0, a1 = 0, a2 = 0, a3 = 0;
  for (int k = t; k < 1024; k += 256) {
    float xv = x[(size_t)mtok * 1024 + k];
    float4 w4 = *(const float4*)(Wb + k * 4);
    a0 = fmaf(xv, w4.x, a0); a1 = fmaf(xv, w4.y, a1);
    a2 = fmaf(xv, w4.z, a2); a3 = fmaf(xv, w4.w, a3);
  }
#pragma unroll
  for (int off = 32; off; off >>= 1) {
    a0 += __shfl_down(a0, off); a1 += __shfl_down(a1, off);
    a2 += __shfl_down(a2, off); a3 += __shfl_down(a3, off);
  }
  __shared__ float red[4][4];
  int w = t >> 6;
  if ((t & 63) == 0) { red[w][0] = a0; red[w][1] = a1; red[w][2] = a2; red[w][3] = a3; }
  __syncthreads();
  if (t < 4) {
    float s = red[0][t] + red[1][t] + red[2][t] + red[3][t];
    beta[((size_t)(b * NH + t)) * Ls + l] = sigmoidf_(s);
  }
}

// ------- fused conv4+silu (from fused x3 [m][3072]) + l2norm + beta --------
__global__ __launch_bounds__(256) void conv_prep(
    const float* __restrict__ x3, const float* __restrict__ wq,
    const float* __restrict__ wk, const float* __restrict__ wv,
    const float* __restrict__ beta_g,
    float* __restrict__ qn, float* __restrict__ kn,
    float* __restrict__ kb, float* __restrict__ vb,
    float* __restrict__ v_out)
{
  int i = blockIdx.x;              // bh*Ls + l
  int t = threadIdx.x;
  int l = i & 2047, bh = i >> 11;
  int b = bh >> 2, h = bh & 3;
  int c = h * 256 + t;
  const float* p = x3 + ((size_t)b * Ls) * 3072 + c;
  float4 wq4 = *(const float4*)(wq + c * 4);
  float4 wk4 = *(const float4*)(wk + c * 4);
  float4 wv4 = *(const float4*)(wv + c * 4);
  float qw[4] = {wq4.x, wq4.y, wq4.z, wq4.w};
  float kw[4] = {wk4.x, wk4.y, wk4.z, wk4.w};
  float vw[4] = {wv4.x, wv4.y, wv4.z, wv4.w};
  float aq = 0.f, ak = 0.f, av = 0.f;
#pragma unroll
  for (int j = 0; j < 4; ++j) {
    int ls = l - 3 + j;
    if (ls >= 0) {
      size_t rb = (size_t)ls * 3072;
      aq = fmaf(qw[j], p[rb], aq);
      ak = fmaf(kw[j], p[rb + 1024], ak);
      av = fmaf(vw[j], p[rb + 2048], av);
    }
  }
  float qv = siluf_(aq), kv = siluf_(ak), vv = siluf_(av);
  float sq = qv * qv, sk = kv * kv;
#pragma unroll
  for (int off = 32; off; off >>= 1) {
    sq += __shfl_down(sq, off);
    sk += __shfl_down(sk, off);
  }
  __shared__ float rq_[4], rk_[4];
  int w = t >> 6;
  if ((t & 63) == 0) { rq_[w] = sq; rk_[w] = sk; }
  __syncthreads();
  sq = rq_[0] + rq_[1] + rq_[2] + rq_[3];
  sk = rk_[0] + rk_[1] + rk_[2] + rk_[3];
  float rq = rsqrtf(sq + 1e-6f), rk = rsqrtf(sk + 1e-6f);
  float bt = beta_g[i];
  size_t base = (size_t)i * 256 + t;
  qn[base] = qv * rq;
  kn[base] = kv * rk;
  kb[base] = kv * rk * bt;
  vb[base] = vv * bt;
  v_out[base] = vv;
}

// ------- per (b,h,chunk) MFMA: Gram, substitution, w/u applies, T out ------
__global__ __launch_bounds__(256) void chunk_prep(
    const float* __restrict__ kb, const float* __restrict__ kn,
    const float* __restrict__ qn, const float* __restrict__ vb,
    float* __restrict__ u_out,
    ushort_t* __restrict__ wn_bf, ushort_t* __restrict__ q_bf,
    ushort_t* __restrict__ knT_bf, ushort_t* __restrict__ kn_bf,
    float* __restrict__ T_g)
{
  __shared__ float Am[32][33];
  __shared__ float Tm[32][36];
  __shared__ ushort_t KT_hi[256][40];
  __shared__ ushort_t KT_lo[256][40];
  int t = threadIdx.x;
  int cc = blockIdx.x & 63, bh = blockIdx.x >> 6;
  size_t gbase = ((size_t)bh * Ls + cc * 32) * 256;
  int wv = t >> 6, lane = t & 63;
  int l16 = lane & 15, quad = lane >> 4;
  int mi = wv >> 1, ni = wv & 1;

  floatx4 Aacc = {0.f,0.f,0.f,0.f};
  {
    int mrow = mi * 16 + l16, nrow = ni * 16 + l16;
    const float* kbp = kb + gbase + (size_t)mrow * 256;
    const float* qnp = qn + gbase + (size_t)mrow * 256;
    const float* knp = kn + gbase + (size_t)nrow * 256;
#pragma unroll
    for (int ks = 0; ks < 8; ++ks) {
      int koff = ks * 32 + quad * 8;
      short8 kbh, kbl, qnh, qnl, knh, knl;
      cvt8(*(const float4*)(kbp + koff), *(const float4*)(kbp + koff + 4), kbh, kbl);
      cvt8(*(const float4*)(qnp + koff), *(const float4*)(qnp + koff + 4), qnh, qnl);
      cvt8(*(const float4*)(knp + koff), *(const float4*)(knp + koff + 4), knh, knl);
      Aacc = __builtin_amdgcn_mfma_f32_16x16x32_bf16(kbh, knh, Aacc, 0, 0, 0);
      Aacc = __builtin_amdgcn_mfma_f32_16x16x32_bf16(kbh, knl, Aacc, 0, 0, 0);
      Aacc = __builtin_amdgcn_mfma_f32_16x16x32_bf16(kbl, knh, Aacc, 0, 0, 0);
      if (ni == 0)
        *(uint4*)(q_bf + gbase + (size_t)mrow * 256 + koff) = *(uint4*)&qnh;
      if (mi == 0)
        *(uint4*)(kn_bf + gbase + (size_t)nrow * 256 + koff) = *(uint4*)&knh;
    }
  }
#pragma unroll
  for (int r = 0; r < 4; ++r) {
    int row = mi * 16 + quad * 4 + r, col = ni * 16 + l16;
    Am[row][col] = (col < row) ? Aacc[r] : 0.f;
  }
  __syncthreads();

  if (wv == 0) {
    if (t < 32) {
#pragma unroll
      for (int i = 0; i < 32; ++i) Tm[i][t] = (i == t) ? 1.f : 0.f;
      for (int i2 = 1; i2 < 32; ++i2) {
        if (t < i2) {
          float s = 0.f;
          for (int m2 = t; m2 < i2; ++m2) s = fmaf(Am[i2][m2], Tm[m2][t], s);
          Tm[i2][t] = -s;
        }
      }
    }
  } else {
    int base = t - 64;
#pragma unroll
    for (int pass = 0; pass < 2; ++pass) {
      int d = base + pass * 192;
      if (d < 256) {
        u32 hp[16], lp[16], kp2[16];
#pragma unroll
        for (int m2 = 0; m2 < 16; ++m2) {
          float f0 = kb[gbase + (size_t)(2 * m2) * 256 + d];
          float f1 = kb[gbase + (size_t)(2 * m2 + 1) * 256 + d];
          ushort_t h0 = f2bf(f0), h1 = f2bf(f1);
          hp[m2] = (u32)h0 | ((u32)h1 << 16);
          lp[m2] = (u32)f2bf(f0 - bf2f(h0)) | ((u32)f2bf(f1 - bf2f(h1)) << 16);
          float g0 = kn[gbase + (size_t)(2 * m2) * 256 + d];
          float g1 = kn[gbase + (size_t)(2 * m2 + 1) * 256 + d];
          kp2[m2] = (u32)f2bf(g0) | ((u32)f2bf(g1) << 16);
        }
#pragma unroll
        for (int q2 = 0; q2 < 4; ++q2) {
          *(uint4*)&KT_hi[d][q2 * 8] = *(uint4*)&hp[q2 * 4];
          *(uint4*)&KT_lo[d][q2 * 8] = *(uint4*)&lp[q2 * 4];
          *(uint4*)(knT_bf + gbase + (size_t)d * 32 + q2 * 8) = *(uint4*)&kp2[q2 * 4];
        }
      }
    }
  }
  __syncthreads();

  // persist T (f32) for group_prep
  *(float4*)(T_g + ((size_t)(bh * 64 + cc)) * 1024 + t * 4) =
      *(const float4*)&Tm[t >> 3][(t & 7) * 4];

  int lt = wv & 1, dgrp = wv >> 1;
  short8 Th, Tl;
  {
    int lrow = lt * 16 + l16;
    cvt8(*(const float4*)&Tm[lrow][quad * 8],
         *(const float4*)&Tm[lrow][quad * 8 + 4], Th, Tl);
  }
#pragma unroll
  for (int j = 0; j < 8; ++j) {
    int dt = dgrp * 8 + j;
    short8 Bh = *(const short8*)&KT_hi[dt * 16 + l16][quad * 8];
    short8 Bl = *(const short8*)&KT_lo[dt * 16 + l16][quad * 8];
    floatx4 acc = {0.f,0.f,0.f,0.f};
    acc = __builtin_amdgcn_mfma_f32_16x16x32_bf16(Th, Bh, acc, 0, 0, 0);
    acc = __builtin_amdgcn_mfma_f32_16x16x32_bf16(Th, Bl, acc, 0, 0, 0);
    acc = __builtin_amdgcn_mfma_f32_16x16x32_bf16(Tl, Bh, acc, 0, 0, 0);
#pragma unroll
    for (int r = 0; r < 4; ++r) {
      int row = lt * 16 + quad * 4 + r;
      wn_bf[gbase + (size_t)row * 256 + dt * 16 + l16] = f2bf(-acc[r]);
    }
  }
  __syncthreads();

  {
    int d = t;
    u32 hp[16], lp[16];
#pragma unroll
    for (int m2 = 0; m2 < 16; ++m2) {
      float f0 = vb[gbase + (size_t)(2 * m2) * 256 + d];
      float f1 = vb[gbase + (size_t)(2 * m2 + 1) * 256 + d];
      ushort_t h0 = f2bf(f0), h1 = f2bf(f1);
      hp[m2] = (u32)h0 | ((u32)h1 << 16);
      lp[m2] = (u32)f2bf(f0 - bf2f(h0)) | ((u32)f2bf(f1 - bf2f(h1)) << 16);
    }
#pragma unroll
    for (int q2 = 0; q2 < 4; ++q2) {
      *(uint4*)&KT_hi[d][q2 * 8] = *(uint4*)&hp[q2 * 4];
      *(uint4*)&KT_lo[d][q2 * 8] = *(uint4*)&lp[q2 * 4];
    }
  }
  __syncthreads();

#pragma unroll
  for (int j = 0; j < 8; ++j) {
    int dt = dgrp * 8 + j;
    short8 Bh = *(const short8*)&KT_hi[dt * 16 + l16][quad * 8];
    short8 Bl = *(const short8*)&KT_lo[dt * 16 + l16][quad * 8];
    floatx4 acc = {0.f,0.f,0.f,0.f};
    acc = __builtin_amdgcn_mfma_f32_16x16x32_bf16(Th, Bh, acc, 0, 0, 0);
    acc = __builtin_amdgcn_mfma_f32_16x16x32_bf16(Th, Bl, acc, 0, 0, 0);
    acc = __builtin_amdgcn_mfma_f32_16x16x32_bf16(Tl, Bh, acc, 0, 0, 0);
#pragma unroll
    for (int r = 0; r < 4; ++r) {
      int row = lt * 16 + quad * 4 + r;
      u_out[gbase + (size_t)row * 256 + dt * 16 + l16] = acc[r];
    }
  }
}

// ------- group_prep helpers -------------------------------------------------
DEVI void rowfrag_hl(const float (*M)[36], int row, int q4, short8& h, short8& l) {
  const float* p = &M[row][q4 * 8];
#pragma unroll
  for (int jj = 0; jj < 8; ++jj) {
    ushort_t hi = f2bf(p[jj]);
    h[jj] = (short)hi;
    l[jj] = (short)f2bf(p[jj] - bf2f(hi));
  }
}
DEVI void colfrag_hl(const float* M, int q4, int col, short8& h, short8& l) {
#pragma unroll
  for (int jj = 0; jj < 8; ++jj) {
    float f = M[(size_t)(q4 * 8 + jj) * 256 + col];
    ushort_t hi = f2bf(f);
    h[jj] = (short)hi;
    l[jj] = (short)f2bf(f - bf2f(hi));
  }
}
// one wave: acc[2][2] += (negA? -A : A) * B  (32x32 @ 32x32, hi/lo 3-mfma)
DEVI void mm32(const float (*A)[36], const float (*B)[36],
               floatx4 acc[2][2], int l16, int q4, bool negA)
{
#pragma unroll
  for (int mt = 0; mt < 2; ++mt) {
    float4 a0 = *(const float4*)&A[mt * 16 + l16][q4 * 8];
    float4 a1 = *(const float4*)&A[mt * 16 + l16][q4 * 8 + 4];
    if (negA) {
      a0.x = -a0.x; a0.y = -a0.y; a0.z = -a0.z; a0.w = -a0.w;
      a1.x = -a1.x; a1.y = -a1.y; a1.z = -a1.z; a1.w = -a1.w;
    }
    short8 Ah, Al; cvt8(a0, a1, Ah, Al);
#pragma unroll
    for (int nt = 0; nt < 2; ++nt) {
      float4 b0, b1;
      b0.x = B[q4*8+0][nt*16+l16]; b0.y = B[q4*8+1][nt*16+l16];
      b0.z = B[q4*8+2][nt*16+l16]; b0.w = B[q4*8+3][nt*16+l16];
      b1.x = B[q4*8+4][nt*16+l16]; b1.y = B[q4*8+5][nt*16+l16];
      b1.z = B[q4*8+6][nt*16+l16]; b1.w = B[q4*8+7][nt*16+l16];
      short8 Bh, Bl; cvt8(b0, b1, Bh, Bl);
      acc[mt][nt] = __builtin_amdgcn_mfma_f32_16x16x32_bf16(Ah, Bh, acc[mt][nt], 0, 0, 0);
      acc[mt][nt] = __builtin_amdgcn_mfma_f32_16x16x32_bf16(Ah, Bl, acc[mt][nt], 0, 0, 0);
      acc[mt][nt] = __builtin_amdgcn_mfma_f32_16x16x32_bf16(Al, Bh, acc[mt][nt], 0, 0, 0);
    }
  }
}
DEVI void st32(float (*O)[36], floatx4 acc[2][2], int l16, int q4)
{
#pragma unroll
  for (int mt = 0; mt < 2; ++mt)
#pragma unroll
    for (int nt = 0; nt < 2; ++nt)
#pragma unroll
      for (int r = 0; r < 4; ++r)
        O[mt * 16 + q4 * 4 + r][nt * 16 + l16] = acc[mt][nt][r];
}

// ------- per (b,h,128-group): T128 cascade, fold into w/u, attn128 ---------
__global__ __launch_bounds__(256) void group_prep(
    const float* __restrict__ T_g, const float* __restrict__ kb,
    const float* __restrict__ vb, const float* __restrict__ qn,
    const float* __restrict__ knf, const ushort_t* __restrict__ kn_bf,
    const ushort_t* __restrict__ q_bf, ushort_t* __restrict__ wn_bf,
    float* __restrict__ u_g, ushort_t* __restrict__ at_hi,
    ushort_t* __restrict__ at_lo)
{
  __shared__ float Ts[4][32][36];
  __shared__ float Gs[6][32][36];
  __shared__ float Bs[6][32][36];
  int t = threadIdx.x;
  int grp = blockIdx.x & 15, bh = blockIdx.x >> 4;
  int wv = t >> 6, lane = t & 63;
  int l16 = lane & 15, q4 = lane >> 4;
  size_t base = ((size_t)bh * Ls + grp * 128) * 256;
  size_t abase = ((size_t)bh * 16 + grp) * 16384;
  floatx4 z4 = {0.f, 0.f, 0.f, 0.f};

  // load T (one chunk per wave); zero upper-tri attn blocks
  {
    const float* tp = T_g + ((size_t)(bh * 64 + grp * 4 + wv)) * 1024;
    for (int e = lane; e < 1024; e += 64)
      Ts[wv][e >> 5][e & 31] = tp[e];
  }
  for (int e = t; e < 6144; e += 256) {
    int blk = e >> 10, idx = e & 1023;
    int bi = blk < 3 ? 0 : (blk < 5 ? 1 : 2);
    int bj = blk < 3 ? blk + 1 : (blk < 5 ? blk - 1 : 3);
    size_t off = abase + (size_t)(bi * 32 + (idx >> 5)) * 128 + bj * 32 + (idx & 31);
    at_hi[off] = 0; at_lo[off] = 0;
  }
  __syncthreads();

  // cross Grams G_ij = kb_i kn_j^T (f32 sources, hi/lo 3-mfma) + diag attn
  {
    int mt = wv >> 1, nt = wv & 1;
#pragma unroll
    for (int pid = 0; pid < 6; ++pid) {
      int gi = (pid < 1) ? 1 : (pid < 3 ? 2 : 3);
      int gj = pid - gi * (gi - 1) / 2;
      const float* ap = kb + base + (size_t)(gi * 32 + mt * 16 + l16) * 256;
      const float* bp = knf + base + (size_t)(gj * 32 + nt * 16 + l16) * 256;
      floatx4 acc = z4;
#pragma unroll
      for (int ks = 0; ks < 8; ++ks) {
        int ko = ks * 32 + q4 * 8;
        short8 ah, al, bbh, bbl;
        cvt8(*(const float4*)(ap + ko), *(const float4*)(ap + ko + 4), ah, al);
        cvt8(*(const float4*)(bp + ko), *(const float4*)(bp + ko + 4), bbh, bbl);
        acc = __builtin_amdgcn_mfma_f32_16x16x32_bf16(ah, bbh, acc, 0, 0, 0);
        acc = __builtin_amdgcn_mfma_f32_16x16x32_bf16(ah, bbl, acc, 0, 0, 0);
        acc = __builtin_amdgcn_mfma_f32_16x16x32_bf16(al, bbh, acc, 0, 0, 0);
      }
#pragma unroll
      for (int r = 0; r < 4; ++r)
        Gs[pid][mt * 16 + q4 * 4 + r][nt * 16 + l16] = acc[r];
    }
#pragma unroll
    for (int c = 0; c < 4; ++c) {
      const float* ap = qn + base + (size_t)(c * 32 + mt * 16 + l16) * 256;
      const float* bp = knf + base + (size_t)(c * 32 + nt * 16 + l16) * 256;
      floatx4 acc = z4;
#pragma unroll
      for (int ks = 0; ks < 8; ++ks) {
        int ko = ks * 32 + q4 * 8;
        short8 ah, al, bbh, bbl;
        cvt8(*(const float4*)(ap + ko), *(const float4*)(ap + ko + 4), ah, al);
        cvt8(*(const float4*)(bp + ko), *(const float4*)(bp + ko + 4), bbh, bbl);
        acc = __builtin_amdgcn_mfma_f32_16x16x32_bf16(ah, bbh, acc, 0, 0, 0);
        acc = __builtin_amdgcn_mfma_f32_16x16x32_bf16(ah, bbl, acc, 0, 0, 0);
        acc = __builtin_amdgcn_mfma_f32_16x16x32_bf16(al, bbh, acc, 0, 0, 0);
      }
#pragma unroll
      for (int r = 0; r < 4; ++r) {
        int row = mt * 16 + q4 * 4 + r, col = nt * 16 + l16;
        float vv2 = (col <= row) ? acc[r] : 0.f;
        ushort_t hi = f2bf(vv2);
        size_t off = abase + (size_t)(c * 32 + row) * 128 + c * 32 + col;
        at_hi[off] = hi;
        at_lo[off] = f2bf(vv2 - bf2f(hi));
      }
    }
  }
  __syncthreads();

  // cascade: B_ij blocks of T128
  if (wv < 3) {   // L1: B10, B21, B32
    int ii = wv + 1, jj = wv;
    int pid = ii * (ii - 1) / 2 + jj;
    floatx4 acc[2][2] = {{z4, z4}, {z4, z4}};
    mm32(Gs[pid], Ts[jj], acc, l16, q4, false);
    st32(Bs[pid], acc, l16, q4);
    floatx4 acc2[2][2] = {{z4, z4}, {z4, z4}};
    mm32(Ts[ii], Bs[pid], acc2, l16, q4, true);
    st32(Bs[pid], acc2, l16, q4);
  }
  __syncthreads();
  if (wv < 2) {   // L2: B20 = -T2(G20 T0 + G21 B10); B31 = -T3(G31 T1 + G32 B21)
    int ii = wv + 2, jj = wv;
    int pid  = ii * (ii - 1) / 2 + jj;
    int pidA = ii * (ii - 1) / 2 + jj + 1;
    int pidB = (jj + 1) * jj / 2 + jj;
    floatx4 acc[2][2] = {{z4, z4}, {z4, z4}};
    mm32(Gs[pid],  Ts[jj],   acc, l16, q4, false);
    mm32(Gs[pidA], Bs[pidB], acc, l16, q4, false);
    st32(Bs[pid], acc, l16, q4);
    floatx4 acc2[2][2] = {{z4, z4}, {z4, z4}};
    mm32(Ts[ii], Bs[pid], acc2, l16, q4, true);
    st32(Bs[pid], acc2, l16, q4);
  }
  __syncthreads();
  if (wv == 0) {  // L3: B30 = -T3(G30 T0 + G31 B10 + G32 B20)
    floatx4 acc[2][2] = {{z4, z4}, {z4, z4}};
    mm32(Gs[3], Ts[0], acc, l16, q4, false);
    mm32(Gs[4], Bs[0], acc, l16, q4, false);
    mm32(Gs[5], Bs[1], acc, l16, q4, false);
    st32(Bs[3], acc, l16, q4);
    floatx4 acc2[2][2] = {{z4, z4}, {z4, z4}};
    mm32(Ts[3], Bs[3], acc2, l16, q4, true);
    st32(Bs[3], acc2, l16, q4);
  }
  __syncthreads();

  // fold: wn_i -= sum_j B_ij kb_j ; u_i += sum_j B_ij vb_j  (hi/lo 3-mfma)
#pragma unroll
  for (int i = 1; i < 4; ++i) {
#pragma unroll
    for (int Rt = 0; Rt < 2; ++Rt) {
      short8 Ah[3], Al[3];
#pragma unroll
      for (int j = 0; j < 3; ++j)
        if (j < i) rowfrag_hl(Bs[i * (i - 1) / 2 + j], Rt * 16 + l16, q4, Ah[j], Al[j]);
#pragma unroll
      for (int dt = 0; dt < 4; ++dt) {
        int dcol = (wv * 4 + dt) * 16 + l16;
        floatx4 accW = z4, accU = z4;
#pragma unroll
        for (int j = 0; j < 3; ++j) {
          if (j < i) {
            short8 Bwh, Bwl, Buh, Bul;
            colfrag_hl(kb + base + (size_t)j * 8192, q4, dcol, Bwh, Bwl);
            colfrag_hl(vb + base + (size_t)j * 8192, q4, dcol, Buh, Bul);
            accW = __builtin_amdgcn_mfma_f32_16x16x32_bf16(Ah[j], Bwh, accW, 0, 0, 0);
            accW = __builtin_amdgcn_mfma_f32_16x16x32_bf16(Ah[j], Bwl, accW, 0, 0, 0);
            accW = __builtin_amdgcn_mfma_f32_16x16x32_bf16(Al[j], Bwh, accW, 0, 0, 0);
            accU = __builtin_amdgcn_mfma_f32_16x16x32_bf16(Ah[j], Buh, accU, 0, 0, 0);
            accU = __builtin_amdgcn_mfma_f32_16x16x32_bf16(Ah[j], Bul, accU, 0, 0, 0);
            accU = __builtin_amdgcn_mfma_f32_16x16x32_bf16(Al[j], Buh, accU, 0, 0, 0);
          }
        }
#pragma unroll
        for (int r = 0; r < 4; ++r) {
          size_t off = base + (size_t)(i * 32 + Rt * 16 + q4 * 4 + r) * 256 + dcol;
          wn_bf[off] = f2bf(bf2f(wn_bf[off]) - accW[r]);
          u_g[off] += accU[r];
        }
      }
    }
  }

  // attn off-diag blocks: q_i kn_j^T (bf16 sources, hi/lo split of f32 acc)
  for (int tt = wv; tt < 24; tt += 4) {
    int pid = tt >> 2, mt = (tt >> 1) & 1, nt = tt & 1;
    int gi = (pid < 1) ? 1 : (pid < 3 ? 2 : 3);
    int gj = pid - gi * (gi - 1) / 2;
    const ushort_t* ap = q_bf + base + (size_t)(gi * 32 + mt * 16 + l16) * 256;
    const ushort_t* bp = kn_bf + base + (size_t)(gj * 32 + nt * 16 + l16) * 256;
    floatx4 acc = z4;
#pragma unroll
    for (int ks = 0; ks < 8; ++ks) {
      short8 aq = *(const short8*)(ap + ks * 32 + q4 * 8);
      short8 bk = *(const short8*)(bp + ks * 32 + q4 * 8);
      acc = __builtin_amdgcn_mfma_f32_16x16x32_bf16(aq, bk, acc, 0, 0, 0);
    }
#pragma unroll
    for (int r = 0; r < 4; ++r) {
      float vv2 = acc[r];
      ushort_t hi = f2bf(vv2);
      size_t off = abase + (size_t)(gi * 32 + mt * 16 + q4 * 4 + r) * 128
                 + gj * 32 + nt * 16 + l16;
      at_hi[off] = hi;
      at_lo[off] = f2bf(vv2 - bf2f(hi));
    }
  }
}

// ------- merged: 128-token MFMA serial scan (blocks 0-127) + FIR (128+) ----
__global__ __launch_bounds__(256, 1) void delta_fir(
    const ushort_t* __restrict__ wn_bf, const ushort_t* __restrict__ q_bf,
    const ushort_t* __restrict__ knT_bf, const ushort_t* __restrict__ at_hi,
    const ushort_t* __restrict__ at_lo, const float* __restrict__ u_g,
    float* __restrict__ delta_g,
    const float* __restrict__ v, const float* __restrict__ wlg,
    const float* __restrict__ wsg, float* __restrict__ firl,
    float* __restrict__ firs)
{
  __shared__ __attribute__((aligned(16))) char smem[72704];
  int t = threadIdx.x;

  if (blockIdx.x >= 128) {
    // ---------------- FIR part ----------------
    float (*vt)[71] = (float(*)[71])smem;
    int bid = blockIdx.x - 128;
    int lt = bid & 255;
    int bh = bid >> 8;
    int b = bh >> 2, h = bh & 3;
    int l0 = lt * 8;
    const float* vp = v + (size_t)bh * Ls * 256;
    for (int r = 0; r < 70; ++r) {
      int ls = l0 - 62 + r;
      vt[t][r] = (ls >= 0) ? vp[(size_t)ls * 256 + t] : 0.f;
    }
    float TL[63], TS3[3];
#pragma unroll
    for (int j = 0; j < 63; ++j) TL[j] = wlg[((size_t)h * 256 + t) * 63 + j];
#pragma unroll
    for (int j = 0; j < 3; ++j) TS3[j] = wsg[((size_t)h * 256 + t) * 3 + j];
    __syncthreads();
    float aL[8] = {0,0,0,0,0,0,0,0}, aS[8] = {0,0,0,0,0,0,0,0};
#pragma unroll
    for (int r = 0; r < 70; ++r) {
      float vm = vt[t][r];
#pragma unroll
      for (int p = 0; p < 8; ++p) {
        int jl = r - p;
        if (jl >= 0 && jl < 63) aL[p] = fmaf(vm, TL[jl], aL[p]);
        int jssrc = r - 60 - p;
        if (jssrc >= 0 && jssrc < 3) aS[p] = fmaf(vm, TS3[jssrc], aS[p]);
      }
    }
#pragma unroll
    for (int p = 0; p < 8; ++p) {
      int l = l0 + p;
      size_t ob = (((size_t)b * Ls + l) * NH + h) * 256 + t;
      firl[ob] = aL[p];
      firs[ob] = aS[p];
    }
    return;
  }

  // ---------------- chain part: 16 x 128-token groups ----------------
  ushort_t (*Shi)[264] = (ushort_t(*)[264])(smem);
  ushort_t (*Slo)[264] = (ushort_t(*)[264])(smem + 8448);
  float (*u2L)[18] = (float(*)[18])(smem + 16896);
  int bh = blockIdx.x & 7, g = blockIdx.x >> 3;
  int b = bh >> 2, h = bh & 3;
  int wv = t >> 6, lane = t & 63;
  int q4 = lane >> 4, l16 = lane & 15;
  int j0 = g * 16;
  bool isU = (wv < 2);
  int rb = (isU ? wv : (wv - 2)) * 64;   // this wave's 64-row band
  const ushort_t* ap_ = (isU ? wn_bf : q_bf) + (size_t)bh * Ls * 256;
  const ushort_t* krb = knT_bf + (size_t)bh * Ls * 256;
  const float* ub = u_g + (size_t)bh * Ls * 256;
  const ushort_t* ahb = at_hi + (size_t)bh * 16 * 16384;
  const ushort_t* alb = at_lo + (size_t)bh * 16 * 16384;

  floatx4 Sacc[4], SaccL[4];
#pragma unroll
  for (int i = 0; i < 4; ++i)
#pragma unroll
    for (int r = 0; r < 4; ++r) { Sacc[i][r] = 0.f; SaccL[i][r] = 0.f; }
  for (int i = t; i < 4224; i += 256) ((u32*)smem)[i] = 0;
  wave_barrier();

  for (int grp = 0; grp < 16; ++grp) {
    size_t gb = (size_t)grp * 32768;
    size_t ab = (size_t)grp * 16384;
    // hoisted: kn frags (all kt,i) + u-init -> full phase-A of latency cover
    short8 kf[4][4];
#pragma unroll
    for (int kt = 0; kt < 4; ++kt)
#pragma unroll
      for (int i = 0; i < 4; ++i)
        kf[kt][i] = *(const short8*)(krb + gb + (size_t)kt * 8192
                     + (size_t)((wv * 4 + i) * 16 + l16) * 32 + q4 * 8);
    floatx4 uin[4];
    floatx4 po[4];
    if (isU) {
#pragma unroll
      for (int mt = 0; mt < 4; ++mt)
#pragma unroll
        for (int r = 0; r < 4; ++r)
          uin[mt][r] = ub[gb + (size_t)(rb + mt * 16 + q4 * 4 + r) * 256 + j0 + l16];
    }
    // phase A: u2 = u + wn*S (u2 waves) / po = q*S (o waves), per 16-row tile
    short8 frA[8], frB[8];
#pragma unroll
    for (int ks = 0; ks < 8; ++ks)
      frA[ks] = *(const short8*)(ap_ + gb + (size_t)(rb + l16) * 256 + ks * 32 + q4 * 8);
#pragma unroll
    for (int mt = 0; mt < 4; ++mt) {
      if (mt < 3) {
#pragma unroll
        for (int ks = 0; ks < 8; ++ks) {
          short8 ld = *(const short8*)(ap_ + gb
                       + (size_t)(rb + (mt + 1) * 16 + l16) * 256 + ks * 32 + q4 * 8);
          if (mt & 1) frA[ks] = ld; else frB[ks] = ld;
        }
      }
      if (isU) {
        floatx4 A0 = uin[mt], A1 = {0,0,0,0}, A2 = {0,0,0,0}, A3 = {0,0,0,0};
#pragma unroll
        for (int ks = 0; ks < 8; ++ks) {
          short8 aw = (mt & 1) ? frB[ks] : frA[ks];
          short8 sh = *(const short8*)&Shi[l16][ks * 32 + q4 * 8];
          short8 sl = *(const short8*)&Slo[l16][ks * 32 + q4 * 8];
          if (ks & 1) {
            A1 = __builtin_amdgcn_mfma_f32_16x16x32_bf16(aw, sh, A1, 0, 0, 0);
            A3 = __builtin_amdgcn_mfma_f32_16x16x32_bf16(aw, sl, A3, 0, 0, 0);
          } else {
            A0 = __builtin_amdgcn_mfma_f32_16x16x32_bf16(aw, sh, A0, 0, 0, 0);
            A2 = __builtin_amdgcn_mfma_f32_16x16x32_bf16(aw, sl, A2, 0, 0, 0);
          }
        }
#pragma unroll
        for (int r = 0; r < 4; ++r)
          u2L[rb + mt * 16 + q4 * 4 + r][l16] = (A0[r] + A1[r]) + (A2[r] + A3[r]);
      } else {
        floatx4 A0 = {0,0,0,0}, A1 = {0,0,0,0};
#pragma unroll
        for (int ks = 0; ks < 8; ++ks) {
          short8 aw = (mt & 1) ? frB[ks] : frA[ks];
          short8 sh = *(const short8*)&Shi[l16][ks * 32 + q4 * 8];
          if (ks & 1) A1 = __builtin_amdgcn_mfma_f32_16x16x32_bf16(aw, sh, A1, 0, 0, 0);
          else        A0 = __builtin_amdgcn_mfma_f32_16x16x32_bf16(aw, sh, A0, 0, 0, 0);
        }
#pragma unroll
        for (int r = 0; r < 4; ++r) po[mt][r] = A0[r] + A1[r];
      }
    }
    wave_barrier();   // u2 visible; phase-A Shi/Slo reads retired

    // phase B: S += kn^T u2 ; o += attn * u2
#pragma unroll
    for (int kt = 0; kt < 4; ++kt) {
      short8 uh, ul;
      {
        float4 a_, b_;
        a_.x = u2L[kt * 32 + q4 * 8 + 0][l16];
        a_.y = u2L[kt * 32 + q4 * 8 + 1][l16];
        a_.z = u2L[kt * 32 + q4 * 8 + 2][l16];
        a_.w = u2L[kt * 32 + q4 * 8 + 3][l16];
        b_.x = u2L[kt * 32 + q4 * 8 + 4][l16];
        b_.y = u2L[kt * 32 + q4 * 8 + 5][l16];
        b_.z = u2L[kt * 32 + q4 * 8 + 6][l16];
        b_.w = u2L[kt * 32 + q4 * 8 + 7][l16];
        cvt8(a_, b_, uh, ul);
      }
#pragma unroll
      for (int i = 0; i < 4; ++i) {
        Sacc[i]  = __builtin_amdgcn_mfma_f32_16x16x32_bf16(kf[kt][i], uh, Sacc[i], 0, 0, 0);
        SaccL[i] = __builtin_amdgcn_mfma_f32_16x16x32_bf16(kf[kt][i], ul, SaccL[i], 0, 0, 0);
      }
      if (!isU) {
#pragma unroll
        for (int mt = 0; mt < 4; ++mt) {
          size_t ao = ab + (size_t)(rb + mt * 16 + l16) * 128 + kt * 32 + q4 * 8;
          short8 ath = *(const short8*)(ahb + ao);
          short8 atl = *(const short8*)(alb + ao);
          po[mt] = __builtin_amdgcn_mfma_f32_16x16x32_bf16(ath, uh, po[mt], 0, 0, 0);
          po[mt] = __builtin_amdgcn_mfma_f32_16x16x32_bf16(ath, ul, po[mt], 0, 0, 0);
          po[mt] = __builtin_amdgcn_mfma_f32_16x16x32_bf16(atl, uh, po[mt], 0, 0, 0);
        }
      }
    }
    if (!isU) {
#pragma unroll
      for (int mt = 0; mt < 4; ++mt)
#pragma unroll
        for (int r = 0; r < 4; ++r) {
          int l = grp * 128 + rb + mt * 16 + q4 * 4 + r;
          delta_g[(((size_t)b * Ls + l) * NH + h) * 256 + j0 + l16] = po[mt][r];
        }
    }
    // S writeback (once per 128 tokens)
#pragma unroll
    for (int i = 0; i < 4; ++i) {
      int dk0 = (wv * 4 + i) * 16 + q4 * 4;
      ushort4 h4, l4;
      ushort_t* hp = (ushort_t*)&h4;
      ushort_t* lp = (ushort_t*)&l4;
#pragma unroll
      for (int r = 0; r < 4; ++r) {
        float sv = Sacc[i][r] + SaccL[i][r];
        ushort_t hi = f2bf(sv);
        hp[r] = hi;
        lp[r] = f2bf(sv - bf2f(hi));
      }
      *(ushort4*)&Shi[l16][dk0] = h4;
      *(ushort4*)&Slo[l16][dk0] = l4;
    }
    wave_barrier();   // S visible; u2L reads retired
  }
}

// ------- gate_in (bf16) ----------------------------------------------------
__global__ __launch_bounds__(256) void build_gate_in_bf(
    const float* __restrict__ x, const float* __restrict__ firs,
    const float* __restrict__ firl, const float* __restrict__ delta,
    const float* __restrict__ v, ushort_t* __restrict__ gin)
{
  int mtok = blockIdx.x, t = threadIdx.x;
  int b = mtok >> 11, l = mtok & 2047;
  float4 xv = *(const float4*)(x + (size_t)mtok * 1024 + t * 4);
  ushort4 xo = make_ushort4(f2bf(xv.x), f2bf(xv.y), f2bf(xv.z), f2bf(xv.w));
  *(ushort4*)(gin + (size_t)mtok * 1056 + t * 4) = xo;
  int w = t >> 6, lane = t & 63;
  for (int br = 0; br < 4; ++br) {
    float s = 0.f, s2 = 0.f;
#pragma unroll
    for (int r = 0; r < 4; ++r) {
      int d = lane + r * 64;
      float val;
      if (br == 0)      val = firs [(size_t)mtok * 1024 + w * 256 + d];
      else if (br == 1) val = firl [(size_t)mtok * 1024 + w * 256 + d];
      else if (br == 2) val = delta[(size_t)mtok * 1024 + w * 256 + d];
      else              val = v[(((size_t)(b * NH + w)) * Ls + l) * 256 + d];
      s += val; s2 = fmaf(val, val, s2);
    }
#pragma unroll
    for (int off = 32; off; off >>= 1) {
      s += __shfl_down(s, off);
      s2 += __shfl_down(s2, off);
    }
    if (lane == 0) {
      float mean = s * (1.f / 256.f);
      float var = s2 * (1.f / 256.f) - mean * mean;
      gin[(size_t)mtok * 1056 + 1024 + br * 8 + w] = f2bf(mean);
      gin[(size_t)mtok * 1056 + 1024 + br * 8 + 4 + w] = f2bf(sqrtf(fmaxf(var, 1e-6f)));
    }
  }
}

// ------- logits -> gates (bf16 hidden input) -------------------------------
__global__ __launch_bounds__(256) void mlp2_gates(
    const ushort_t* __restrict__ mh, const float* __restrict__ W2,
    const float* __restrict__ b2, const float* __restrict__ glt,
    float* __restrict__ gates)
{
  int mtok = blockIdx.x, t = threadIdx.x;
  float p[16];
#pragma unroll
  for (int j = 0; j < 16; ++j) p[j] = 0.f;
  for (int k = t; k < 2048; k += 256) {
    float hv = bf2f(mh[(size_t)mtok * 2048 + k]);
    const float* wr = W2 + (size_t)k * 16;
#pragma unroll
    for (int j4 = 0; j4 < 4; ++j4) {
      float4 w4 = *(const float4*)(wr + j4 * 4);
      p[j4*4+0] = fmaf(hv, w4.x, p[j4*4+0]);
      p[j4*4+1] = fmaf(hv, w4.y, p[j4*4+1]);
      p[j4*4+2] = fmaf(hv, w4.z, p[j4*4+2]);
      p[j4*4+3] = fmaf(hv, w4.w, p[j4*4+3]);
    }
  }
#pragma unroll
  for (int j = 0; j < 16; ++j)
#pragma unroll
    for (int off = 32; off; off >>= 1) p[j] += __shfl_down(p[j], off);
  __shared__ float red[4][16];
  __shared__ float zl[16];
  int w = t >> 6;
  if ((t & 63) == 0) {
#pragma unroll
    for (int j = 0; j < 16; ++j) red[w][j] = p[j];
  }
  __syncthreads();
  if (t < 16) {
    float tot = red[0][t] + red[1][t] + red[2][t] + red[3][t] + b2[t];
    float tempv = log1pf(expf(glt[t >> 2])) + 1e-4f;
    zl[t] = tot / tempv;
  }
  __syncthreads();
  if (t < 4) {
    float z0 = zl[t*4], z1 = zl[t*4+1], z2 = zl[t*4+2], z3 = zl[t*4+3];
    float mx = fmaxf(fmaxf(z0, z1), fmaxf(z2, z3));
    float e0 = expf(z0 - mx), e1 = expf(z1 - mx), e2 = expf(z2 - mx), e3 = expf(z3 - mx);
    float inv = 1.f / (e0 + e1 + e2 + e3);
    gates[(size_t)mtok * 16 + t * 4 + 0] = e0 * inv;
    gates[(size_t)mtok * 16 + t * 4 + 1] = e1 * inv;
    gates[(size_t)mtok * 16 + t * 4 + 2] = e2 * inv;
    gates[(size_t)mtok * 16 + t * 4 + 3] = e3 * inv;
  }
}

// ------- o = gated mix, RMSNorm -> bf16 ------------------------------------
__global__ __launch_bounds__(256) void combine_norm_bf(
    const float* __restrict__ firs, const float* __restrict__ firl,
    const float* __restrict__ delta, const float* __restrict__ v,
    const float* __restrict__ gates, const float* __restrict__ onw,
    ushort_t* __restrict__ o)
{
  int mh = blockIdx.x;
  int mtok = mh >> 2, h = mh & 3;
  int t = threadIdx.x;
  int b = mtok >> 11, l = mtok & 2047;
  const float* g = gates + (size_t)mtok * 16 + h * 4;
  float w0 = g[0], w1 = g[1], w2 = g[2], w3 = g[3];
  size_t tb = (size_t)mtok * 1024 + h * 256 + t;
  float val = w0 * firs[tb] + w1 * firl[tb] + w2 * delta[tb]
            + w3 * v[(((size_t)(b * NH + h)) * Ls + l) * 256 + t];
  float s2 = val * val;
#pragma unroll
  for (int off = 32; off; off >>= 1) s2 += __shfl_down(s2, off);
  __shared__ float r4[4];
  if ((t & 63) == 0) r4[t >> 6] = s2;
  __syncthreads();
  float tot = r4[0] + r4[1] + r4[2] + r4[3];
  float rms = rsqrtf(tot * (1.f / 256.f) + 1e-5f);
  o[tb] = f2bf(val * rms * onw[t]);
}

// ---------------------------------------------------------------------------
extern "C" void kernel_launch(void* const* d_in, const int* in_sizes, int n_in,
                              void* d_out, int out_size, void* d_ws, size_t ws_size,
                              hipStream_t stream) {
  const float* x     = (const float*)d_in[0];
  const float* Wq    = (const float*)d_in[1];
  const float* Wk    = (const float*)d_in[2];
  const float* Wv    = (const float*)d_in[3];
  const float* Wb    = (const float*)d_in[4];
  const float* convq = (const float*)d_in[5];
  const float* convk = (const float*)d_in[6];
  const float* convv = (const float*)d_in[7];
  const float* firsw = (const float*)d_in[8];
  const float* firlw = (const float*)d_in[9];
  const float* mlpw1 = (const float*)d_in[10];
  const float* mlpb1 = (const float*)d_in[11];
  const float* mlpw2 = (const float*)d_in[12];
  const float* mlpb2 = (const float*)d_in[13];
  const float* glt   = (const float*)d_in[14];
  const float* onw   = (const float*)d_in[15];
  const float* Wo    = (const float*)d_in[16];
  float* ws = (float*)d_ws;

  ushort_t* x_bf   = (ushort_t*)(ws + off_firs);
  ushort_t* Wqkv_t = (ushort_t*)(ws + off_firl);  // 3 x [1024][1024] contiguous
  ushort_t* gin_bf = (ushort_t*)(ws + off_gin);
  ushort_t* w1_t   = (ushort_t*)(ws + off_k);     // kn dead after group_prep
  ushort_t* o_bf   = (ushort_t*)(ws + off_xv);
  ushort_t* Wo_t   = (ushort_t*)(ws + off_beta);  // spans into T_g (dead)
  ushort_t* mlph_bf= (ushort_t*)(ws + off_mlph);
  ushort_t* wn_bf  = (ushort_t*)(ws + off_firs);
  ushort_t* q_bf   = (ushort_t*)(ws + off_firs + 2097152);
  ushort_t* knT_bf = (ushort_t*)(ws + off_firl);
  ushort_t* kn_bf  = (ushort_t*)(ws + off_xq);    // x3 dead after conv_prep
  float* x3   = ws + off_xq;     // fused [4096][3072] spans xq/xk/xv
  float* kb_f = ws + off_gin;
  float* vb_f = ws + off_mlph;
  float* T_g  = ws + off_attn;   // f32 [8*64][1024]
  ushort_t* at_hi = (ushort_t*)(ws + off_at);            // [8][16][128][128]
  ushort_t* at_lo = (ushort_t*)(ws + off_at + 1048576);
  float* firs_f = ws + off_xq;   // x3/kn_bf dead after group_prep
  float* firl_f = ws + off_xk;

  dim3 blk(256);
  // fused q/k/v projection (one N=3072 GEMM) + beta
  to_bf16<<<2048, blk, 0, stream>>>(x, x_bf, 4194304);
  convT<<<dim3(32, 32), blk, 0, stream>>>(Wq, Wqkv_t, 1024, 1024);
  convT<<<dim3(32, 32), blk, 0, stream>>>(Wk, Wqkv_t + 1048576, 1024, 1024);
  convT<<<dim3(32, 32), blk, 0, stream>>>(Wv, Wqkv_t + 2097152, 1024, 1024);
  gemm_bf16<<<dim3(24, 32), blk, 0, stream>>>(x_bf, Wqkv_t, x3, 3072, 1024, nullptr, 0, 0);
  beta_sigmoid<<<4096, blk, 0, stream>>>(x, Wb, ws + off_beta);
  // fused conv4+silu + l2norm + beta products
  conv_prep<<<16384, blk, 0, stream>>>(x3, convq, convk, convv, ws + off_beta,
                                       ws + off_q, ws + off_k, kb_f, vb_f, ws + off_v);
  // per-chunk T inverse, u, bf16 {-w, q, knT, kn}, T persisted
  chunk_prep<<<512, blk, 0, stream>>>(kb_f, ws + off_k, ws + off_q, vb_f,
                                      ws + off_xv, wn_bf, q_bf, knT_bf, kn_bf, T_g);
  // T128 cascade + fold into w/u + attn128 (hi/lo)
  group_prep<<<128, blk, 0, stream>>>(T_g, kb_f, vb_f, ws + off_q, ws + off_k,
                                      kn_bf, q_bf, wn_bf, ws + off_xv,
                                      at_hi, at_lo);
  // merged 128-token serial MFMA scan (delta -> off_q) + FIR (-> x3 regions)
  delta_fir<<<2176, blk, 0, stream>>>(wn_bf, q_bf, knT_bf, at_hi, at_lo,
                                      ws + off_xv, ws + off_q,
                                      ws + off_v, firlw, firsw, firl_f, firs_f);
  // gate input (bf16), MLP1 (MFMA, gelu, bf16 out), gates
  build_gate_in_bf<<<4096, blk, 0, stream>>>(x, firs_f, firl_f, ws + off_q,
                                             ws + off_v, gin_bf);
  convT<<<dim3(64, 33), blk, 0, stream>>>(mlpw1, w1_t, 1056, 2048);
  gemm_bf16<<<dim3(16, 32), blk, 0, stream>>>(gin_bf, w1_t, (float*)mlph_bf,
                                              2048, 1056, mlpb1, 1, 1);
  mlp2_gates<<<4096, blk, 0, stream>>>(mlph_bf, mlpw2, mlpb2, glt, ws + off_gates);
  // combine + RMSNorm -> bf16, output projection (MFMA)
  combine_norm_bf<<<16384, blk, 0, stream>>>(firs_f, firl_f, ws + off_q,
                                             ws + off_v, ws + off_gates, onw, o_bf);
  convT<<<dim3(32, 32), blk, 0, stream>>>(Wo, Wo_t, 1024, 1024);
  gemm_bf16<<<dim3(8, 32), blk, 0, stream>>>(o_bf, Wo_t, (float*)d_out, 1024, 1024, nullptr, 0, 0);
}

// Round 4
// 632.222 us; speedup vs baseline: 1.1593x; 1.1593x over previous
//
#include <hip/hip_runtime.h>
#include <hip/hip_bf16.h>

// ---------------------------------------------------------------------------
// DeltaNet forward, round 11:
//  - REVERT to r8 chain structure (m=2 super-chunks, 32 iters, deep operand
//    prefetch; measured 146us/546us). r10's CHUNK=128 cut barriers but
//    removed prefetch depth -> 233us (loads exposed at 1 wave/SIMD).
//  - NEW: 2 chains per 512-thread block. Two independent (bh,g) units run in
//    disjoint LDS slices; shared s_barrier stays lockstep (identical trip
//    counts) but each SIMD now holds 2 waves -> sibling chain hides the
//    LDS/cvt/MFMA dependency stalls that dominate (~85% of chain time).
//  - FIR co-scheduled at 512 threads: two adjacent 8-row units share one
//    78-row LDS window (stride 79, odd -> conflict-free).
// ---------------------------------------------------------------------------

#define DEVI __device__ __forceinline__
typedef unsigned int u32;
typedef unsigned short ushort_t;
typedef __attribute__((ext_vector_type(8))) short short8;
typedef __attribute__((ext_vector_type(4))) float floatx4;

constexpr int Ls = 2048, NH = 4;

// workspace offsets (floats)
constexpr size_t off_xq   = 0;         // x3 [m][3072] cols 0-1023 -> kn_bf -> firs
constexpr size_t off_xk   = 4194304;   // x3 cols 1024-2047 -> firl
constexpr size_t off_xv   = 8388608;   // x3 cols 2048-3071 -> u -> o_bf
constexpr size_t off_q    = 12582912;  // qn -> delta
constexpr size_t off_k    = 16777216;  // kn -> w1_t (bf16)
constexpr size_t off_v    = 20971520;  // v (alive to the end)
constexpr size_t off_beta = 25165824;  // beta -> Wo_t (bf16, spans into attn)
constexpr size_t off_attn = 25182208;  // attn (dead after chain)
constexpr size_t off_firs = 25706496;  // x_bf -> {wn_bf, q_bf} (bf16)
constexpr size_t off_firl = 29900800;  // Wqkv_t -> knT_bf (bf16)
constexpr size_t off_gin  = 34095104;  // kb (f32) -> {X_g, Y_g} -> gin_bf
constexpr size_t off_mlph = 38420480;  // vb (f32) -> mlph_bf
constexpr size_t off_gates= 46809088;  // gates

DEVI float sigmoidf_(float x) { return 1.f / (1.f + expf(-x)); }
DEVI float siluf_(float x) { return x / (1.f + expf(-x)); }
DEVI float geluf_(float x) { return 0.5f * x * (1.f + erff(x * 0.7071067811865476f)); }
DEVI ushort_t f2bf(float f) {
  union { float f; u32 u; } c{f};
  u32 r = (c.u + 0x7fffu + ((c.u >> 16) & 1u)) >> 16;
  return (ushort_t)r;
}
DEVI float bf2f(ushort_t h) {
  union { u32 u; float f; } c; c.u = ((u32)h) << 16; return c.f;
}
DEVI void cvt8(float4 a, float4 b, short8& hi, short8& lo) {
  float f[8] = {a.x,a.y,a.z,a.w,b.x,b.y,b.z,b.w};
#pragma unroll
  for (int j = 0; j < 8; ++j) {
    ushort_t h = f2bf(f[j]);
    hi[j] = (short)h;
    lo[j] = (short)f2bf(f[j] - bf2f(h));
  }
}
DEVI void async16(const void* g, void* l) {
  __builtin_amdgcn_global_load_lds(
      (const u32 __attribute__((address_space(1)))*)g,
      (u32 __attribute__((address_space(3)))*)l, 16, 0, 0);
}
// Raw workgroup barrier: waits LDS ops only (lgkmcnt), leaves global
// loads/stores (vmcnt) in flight. All cross-wave deps in the chain loop are
// LDS-only, and global data has no in-kernel consumers.
DEVI void wave_barrier() {
  __builtin_amdgcn_sched_barrier(0);
  asm volatile("s_waitcnt lgkmcnt(0)" ::: "memory");
  __builtin_amdgcn_s_barrier();
  __builtin_amdgcn_sched_barrier(0);
}

// ---------------- f32 -> bf16 ----------------------------------------------
__global__ __launch_bounds__(256) void to_bf16(
    const float* __restrict__ in, ushort_t* __restrict__ out, int n)
{
  int i = (blockIdx.x * 256 + threadIdx.x) * 8;
  if (i >= n) return;
  float4 a = *(const float4*)(in + i);
  float4 b = *(const float4*)(in + i + 4);
  ushort_t o[8] = { f2bf(a.x), f2bf(a.y), f2bf(a.z), f2bf(a.w),
                    f2bf(b.x), f2bf(b.y), f2bf(b.z), f2bf(b.w) };
  *(uint4*)(out + i) = *(uint4*)o;
}

// ---------------- f32 [K][N] -> bf16 [N][K] --------------------------------
__global__ __launch_bounds__(256) void convT(
    const float* __restrict__ W, ushort_t* __restrict__ out, int Kq, int Nq)
{
  __shared__ ushort_t tile[32][33];
  int n0 = blockIdx.x * 32, k0 = blockIdx.y * 32;
  int tx = threadIdx.x & 31, ty = threadIdx.x >> 5;
#pragma unroll
  for (int r = 0; r < 32; r += 8)
    tile[ty + r][tx] = f2bf(W[(size_t)(k0 + ty + r) * Nq + n0 + tx]);
  __syncthreads();
#pragma unroll
  for (int r = 0; r < 32; r += 8)
    out[(size_t)(n0 + ty + r) * Kq + k0 + tx] = tile[tx][ty + r];
}

// ---------------- bf16 MFMA GEMM -------------------------------------------
__global__ __launch_bounds__(256) void gemm_bf16(
    const ushort_t* __restrict__ A, const ushort_t* __restrict__ Bt,
    float* __restrict__ C, int Nq, int Kq,
    const float* __restrict__ bias, int act, int outbf)
{
  __shared__ ushort_t As[128 * 32];
  __shared__ ushort_t Bs[128 * 32];
  int t = threadIdx.x;
  int w = t >> 6, lane = t & 63;
  int m0 = blockIdx.y * 128, n0 = blockIdx.x * 128;
  floatx4 acc[4][4];
#pragma unroll
  for (int i = 0; i < 4; ++i)
#pragma unroll
    for (int j = 0; j < 4; ++j)
#pragma unroll
      for (int r = 0; r < 4; ++r) acc[i][j][r] = 0.f;

  int lrow = lane >> 2, lk8 = (lane & 3) * 8;
  for (int kt = 0; kt < Kq; kt += 32) {
#pragma unroll
    for (int r = 0; r < 2; ++r) {
      int seg = w * 2 + r;
      int row = seg * 16 + lrow;
      async16(A  + (size_t)(m0 + row) * Kq + kt + lk8, &As[seg * 512]);
      async16(Bt + (size_t)(n0 + row) * Kq + kt + lk8, &Bs[seg * 512]);
    }
    __syncthreads();
    short8 af[4], bf[4];
#pragma unroll
    for (int i = 0; i < 4; ++i) {
      int row = (w >> 1) * 64 + i * 16 + (lane & 15);
      af[i] = *(const short8*)&As[row * 32 + (lane >> 4) * 8];
    }
#pragma unroll
    for (int j = 0; j < 4; ++j) {
      int col = (w & 1) * 64 + j * 16 + (lane & 15);
      bf[j] = *(const short8*)&Bs[col * 32 + (lane >> 4) * 8];
    }
#pragma unroll
    for (int i = 0; i < 4; ++i)
#pragma unroll
      for (int j = 0; j < 4; ++j)
        acc[i][j] = __builtin_amdgcn_mfma_f32_16x16x32_bf16(af[i], bf[j], acc[i][j], 0, 0, 0);
    __syncthreads();
  }
#pragma unroll
  for (int i = 0; i < 4; ++i) {
    int rbase = m0 + (w >> 1) * 64 + i * 16 + ((lane >> 4) << 2);
#pragma unroll
    for (int j = 0; j < 4; ++j) {
      int col = n0 + (w & 1) * 64 + j * 16 + (lane & 15);
      float bv = act ? bias[col] : 0.f;
#pragma unroll
      for (int r = 0; r < 4; ++r) {
        float v = acc[i][j][r];
        if (act) v = geluf_(v + bv);
        if (outbf) ((ushort_t*)C)[(size_t)(rbase + r) * Nq + col] = f2bf(v);
        else       C[(size_t)(rbase + r) * Nq + col] = v;
      }
    }
  }
}

// ---------------- beta = sigmoid(x @ Wb) -----------------------------------
__global__ __launch_bounds__(256) void beta_sigmoid(
    const float* __restrict__ x, const float* __restrict__ Wb,
    float* __restrict__ beta)
{
  int mtok = blockIdx.x, t = threadIdx.x;
  int b = mtok >> 11, l = mtok & 2047;
  float a0 = 0, a1 = 0, a2 = 0, a3 = 0;
  for (int k = t; k < 1024; k += 256) {
    float xv = x[(size_t)mtok * 1024 + k];
    float4 w4 = *(const float4*)(Wb + k * 4);
    a0 = fmaf(xv, w4.x, a0); a1 = fmaf(xv, w4.y, a1);
    a2 = fmaf(xv, w4.z, a2); a3 = fmaf(xv, w4.w, a3);
  }
#pragma unroll
  for (int off = 32; off; off >>= 1) {
    a0 += __shfl_down(a0, off); a1 += __shfl_down(a1, off);
    a2 += __shfl_down(a2, off); a3 += __shfl_down(a3, off);
  }
  __shared__ float red[4][4];
  int w = t >> 6;
  if ((t & 63) == 0) { red[w][0] = a0; red[w][1] = a1; red[w][2] = a2; red[w][3] = a3; }
  __syncthreads();
  if (t < 4) {
    float s = red[0][t] + red[1][t] + red[2][t] + red[3][t];
    beta[((size_t)(b * NH + t)) * Ls + l] = sigmoidf_(s);
  }
}

// ------- fused conv4+silu (from fused x3 [m][3072]) + l2norm + beta --------
__global__ __launch_bounds__(256) void conv_prep(
    const float* __restrict__ x3, const float* __restrict__ wq,
    const float* __restrict__ wk, const float* __restrict__ wv,
    const float* __restrict__ beta_g,
    float* __restrict__ qn, float* __restrict__ kn,
    float* __restrict__ kb, float* __restrict__ vb,
    float* __restrict__ v_out)
{
  int i = blockIdx.x;              // bh*Ls + l
  int t = threadIdx.x;
  int l = i & 2047, bh = i >> 11;
  int b = bh >> 2, h = bh & 3;
  int c = h * 256 + t;
  const float* p = x3 + ((size_t)b * Ls) * 3072 + c;
  float4 wq4 = *(const float4*)(wq + c * 4);
  float4 wk4 = *(const float4*)(wk + c * 4);
  float4 wv4 = *(const float4*)(wv + c * 4);
  float qw[4] = {wq4.x, wq4.y, wq4.z, wq4.w};
  float kw[4] = {wk4.x, wk4.y, wk4.z, wk4.w};
  float vw[4] = {wv4.x, wv4.y, wv4.z, wv4.w};
  float aq = 0.f, ak = 0.f, av = 0.f;
#pragma unroll
  for (int j = 0; j < 4; ++j) {
    int ls = l - 3 + j;
    if (ls >= 0) {
      size_t rb = (size_t)ls * 3072;
      aq = fmaf(qw[j], p[rb], aq);
      ak = fmaf(kw[j], p[rb + 1024], ak);
      av = fmaf(vw[j], p[rb + 2048], av);
    }
  }
  float qv = siluf_(aq), kv = siluf_(ak), vv = siluf_(av);
  float sq = qv * qv, sk = kv * kv;
#pragma unroll
  for (int off = 32; off; off >>= 1) {
    sq += __shfl_down(sq, off);
    sk += __shfl_down(sk, off);
  }
  __shared__ float rq_[4], rk_[4];
  int w = t >> 6;
  if ((t & 63) == 0) { rq_[w] = sq; rk_[w] = sk; }
  __syncthreads();
  sq = rq_[0] + rq_[1] + rq_[2] + rq_[3];
  sk = rk_[0] + rk_[1] + rk_[2] + rk_[3];
  float rq = rsqrtf(sq + 1e-6f), rk = rsqrtf(sk + 1e-6f);
  float bt = beta_g[i];
  size_t base = (size_t)i * 256 + t;
  qn[base] = qv * rq;
  kn[base] = kv * rk;
  kb[base] = kv * rk * bt;
  vb[base] = vv * bt;
  v_out[base] = vv;
}

// ------- per (b,h,chunk) MFMA: Gram, substitution, w/u applies -------------
__global__ __launch_bounds__(256) void chunk_prep(
    const float* __restrict__ kb, const float* __restrict__ kn,
    const float* __restrict__ qn, const float* __restrict__ vb,
    float* __restrict__ attn_g, float* __restrict__ u_out,
    ushort_t* __restrict__ wn_bf, ushort_t* __restrict__ q_bf,
    ushort_t* __restrict__ knT_bf, ushort_t* __restrict__ kn_bf)
{
  __shared__ float Am[32][33];
  __shared__ float Tm[32][36];
  __shared__ ushort_t KT_hi[256][40];
  __shared__ ushort_t KT_lo[256][40];
  int t = threadIdx.x;
  int cc = blockIdx.x & 63, bh = blockIdx.x >> 6;
  size_t gbase = ((size_t)bh * Ls + cc * 32) * 256;
  int wv = t >> 6, lane = t & 63;
  int l16 = lane & 15, quad = lane >> 4;
  int mi = wv >> 1, ni = wv & 1;

  floatx4 Aacc = {0.f,0.f,0.f,0.f}, Qacc = {0.f,0.f,0.f,0.f};
  {
    int mrow = mi * 16 + l16, nrow = ni * 16 + l16;
    const float* kbp = kb + gbase + (size_t)mrow * 256;
    const float* qnp = qn + gbase + (size_t)mrow * 256;
    const float* knp = kn + gbase + (size_t)nrow * 256;
#pragma unroll
    for (int ks = 0; ks < 8; ++ks) {
      int koff = ks * 32 + quad * 8;
      short8 kbh, kbl, qnh, qnl, knh, knl;
      cvt8(*(const float4*)(kbp + koff), *(const float4*)(kbp + koff + 4), kbh, kbl);
      cvt8(*(const float4*)(qnp + koff), *(const float4*)(qnp + koff + 4), qnh, qnl);
      cvt8(*(const float4*)(knp + koff), *(const float4*)(knp + koff + 4), knh, knl);
      Aacc = __builtin_amdgcn_mfma_f32_16x16x32_bf16(kbh, knh, Aacc, 0, 0, 0);
      Aacc = __builtin_amdgcn_mfma_f32_16x16x32_bf16(kbh, knl, Aacc, 0, 0, 0);
      Aacc = __builtin_amdgcn_mfma_f32_16x16x32_bf16(kbl, knh, Aacc, 0, 0, 0);
      Qacc = __builtin_amdgcn_mfma_f32_16x16x32_bf16(qnh, knh, Qacc, 0, 0, 0);
      Qacc = __builtin_amdgcn_mfma_f32_16x16x32_bf16(qnh, knl, Qacc, 0, 0, 0);
      Qacc = __builtin_amdgcn_mfma_f32_16x16x32_bf16(qnl, knh, Qacc, 0, 0, 0);
      if (ni == 0)
        *(uint4*)(q_bf + gbase + (size_t)mrow * 256 + koff) = *(uint4*)&qnh;
      if (mi == 0)
        *(uint4*)(kn_bf + gbase + (size_t)nrow * 256 + koff) = *(uint4*)&knh;
    }
  }
  float* ag = attn_g + ((size_t)bh * 64 + cc) * 1024;
#pragma unroll
  for (int r = 0; r < 4; ++r) {
    int row = mi * 16 + quad * 4 + r, col = ni * 16 + l16;
    Am[row][col] = (col < row) ? Aacc[r] : 0.f;
    ag[row * 32 + col] = (col <= row) ? Qacc[r] : 0.f;
  }
  __syncthreads();

  if (wv == 0) {
    if (t < 32) {
#pragma unroll
      for (int i = 0; i < 32; ++i) Tm[i][t] = (i == t) ? 1.f : 0.f;
      for (int i2 = 1; i2 < 32; ++i2) {
        if (t < i2) {
          float s = 0.f;
          for (int m2 = t; m2 < i2; ++m2) s = fmaf(Am[i2][m2], Tm[m2][t], s);
          Tm[i2][t] = -s;
        }
      }
    }
  } else {
    int base = t - 64;
#pragma unroll
    for (int pass = 0; pass < 2; ++pass) {
      int d = base + pass * 192;
      if (d < 256) {
        u32 hp[16], lp[16], kp2[16];
#pragma unroll
        for (int m2 = 0; m2 < 16; ++m2) {
          float f0 = kb[gbase + (size_t)(2 * m2) * 256 + d];
          float f1 = kb[gbase + (size_t)(2 * m2 + 1) * 256 + d];
          ushort_t h0 = f2bf(f0), h1 = f2bf(f1);
          hp[m2] = (u32)h0 | ((u32)h1 << 16);
          lp[m2] = (u32)f2bf(f0 - bf2f(h0)) | ((u32)f2bf(f1 - bf2f(h1)) << 16);
          float g0 = kn[gbase + (size_t)(2 * m2) * 256 + d];
          float g1 = kn[gbase + (size_t)(2 * m2 + 1) * 256 + d];
          kp2[m2] = (u32)f2bf(g0) | ((u32)f2bf(g1) << 16);
        }
#pragma unroll
        for (int q2 = 0; q2 < 4; ++q2) {
          *(uint4*)&KT_hi[d][q2 * 8] = *(uint4*)&hp[q2 * 4];
          *(uint4*)&KT_lo[d][q2 * 8] = *(uint4*)&lp[q2 * 4];
          *(uint4*)(knT_bf + gbase + (size_t)d * 32 + q2 * 8) = *(uint4*)&kp2[q2 * 4];
        }
      }
    }
  }
  __syncthreads();

  int lt = wv & 1, dgrp = wv >> 1;
  short8 Th, Tl;
  {
    int lrow = lt * 16 + l16;
    cvt8(*(const float4*)&Tm[lrow][quad * 8],
         *(const float4*)&Tm[lrow][quad * 8 + 4], Th, Tl);
  }
#pragma unroll
  for (int j = 0; j < 8; ++j) {
    int dt = dgrp * 8 + j;
    short8 Bh = *(const short8*)&KT_hi[dt * 16 + l16][quad * 8];
    short8 Bl = *(const short8*)&KT_lo[dt * 16 + l16][quad * 8];
    floatx4 acc = {0.f,0.f,0.f,0.f};
    acc = __builtin_amdgcn_mfma_f32_16x16x32_bf16(Th, Bh, acc, 0, 0, 0);
    acc = __builtin_amdgcn_mfma_f32_16x16x32_bf16(Th, Bl, acc, 0, 0, 0);
    acc = __builtin_amdgcn_mfma_f32_16x16x32_bf16(Tl, Bh, acc, 0, 0, 0);
#pragma unroll
    for (int r = 0; r < 4; ++r) {
      int row = lt * 16 + quad * 4 + r;
      wn_bf[gbase + (size_t)row * 256 + dt * 16 + l16] = f2bf(-acc[r]);
    }
  }
  __syncthreads();

  {
    int d = t;
    u32 hp[16], lp[16];
#pragma unroll
    for (int m2 = 0; m2 < 16; ++m2) {
      float f0 = vb[gbase + (size_t)(2 * m2) * 256 + d];
      float f1 = vb[gbase + (size_t)(2 * m2 + 1) * 256 + d];
      ushort_t h0 = f2bf(f0), h1 = f2bf(f1);
      hp[m2] = (u32)h0 | ((u32)h1 << 16);
      lp[m2] = (u32)f2bf(f0 - bf2f(h0)) | ((u32)f2bf(f1 - bf2f(h1)) << 16);
    }
#pragma unroll
    for (int q2 = 0; q2 < 4; ++q2) {
      *(uint4*)&KT_hi[d][q2 * 8] = *(uint4*)&hp[q2 * 4];
      *(uint4*)&KT_lo[d][q2 * 8] = *(uint4*)&lp[q2 * 4];
    }
  }
  __syncthreads();

#pragma unroll
  for (int j = 0; j < 8; ++j) {
    int dt = dgrp * 8 + j;
    short8 Bh = *(const short8*)&KT_hi[dt * 16 + l16][quad * 8];
    short8 Bl = *(const short8*)&KT_lo[dt * 16 + l16][quad * 8];
    floatx4 acc = {0.f,0.f,0.f,0.f};
    acc = __builtin_amdgcn_mfma_f32_16x16x32_bf16(Th, Bh, acc, 0, 0, 0);
    acc = __builtin_amdgcn_mfma_f32_16x16x32_bf16(Th, Bl, acc, 0, 0, 0);
    acc = __builtin_amdgcn_mfma_f32_16x16x32_bf16(Tl, Bh, acc, 0, 0, 0);
#pragma unroll
    for (int r = 0; r < 4; ++r) {
      int row = lt * 16 + quad * 4 + r;
      u_out[gbase + (size_t)row * 256 + dt * 16 + l16] = acc[r];
    }
  }
}

// ------- cross matrices per super-chunk: X = wn1 @ kn0^T, Y = q1 @ kn0^T ---
__global__ __launch_bounds__(256) void cross_prep(
    const ushort_t* __restrict__ wn_bf, const ushort_t* __restrict__ q_bf,
    const ushort_t* __restrict__ kn_bf,
    float* __restrict__ X_g, float* __restrict__ Y_g)
{
  int t = threadIdx.x;
  int sc = blockIdx.x & 31, bh = blockIdx.x >> 5;
  int wv = t >> 6, lane = t & 63;
  int l16 = lane & 15, quad = lane >> 4;
  int mi = wv >> 1, ni = wv & 1;
  size_t base = (size_t)bh * Ls * 256;
  size_t r1 = base + (size_t)(sc * 64 + 32 + mi * 16 + l16) * 256;  // chunk 2sc+1 rows
  size_t r0 = base + (size_t)(sc * 64 + ni * 16 + l16) * 256;       // chunk 2sc rows
  floatx4 Xacc = {0.f,0.f,0.f,0.f}, Yacc = {0.f,0.f,0.f,0.f};
#pragma unroll
  for (int ks = 0; ks < 8; ++ks) {
    int ko = ks * 32 + quad * 8;
    short8 aw = *(const short8*)(wn_bf + r1 + ko);
    short8 aq = *(const short8*)(q_bf  + r1 + ko);
    short8 bk = *(const short8*)(kn_bf + r0 + ko);
    Xacc = __builtin_amdgcn_mfma_f32_16x16x32_bf16(aw, bk, Xacc, 0, 0, 0);
    Yacc = __builtin_amdgcn_mfma_f32_16x16x32_bf16(aq, bk, Yacc, 0, 0, 0);
  }
  float* xo = X_g + ((size_t)bh * 32 + sc) * 1024;
  float* yo = Y_g + ((size_t)bh * 32 + sc) * 1024;
#pragma unroll
  for (int r = 0; r < 4; ++r) {
    int row = mi * 16 + quad * 4 + r, col = ni * 16 + l16;
    xo[row * 32 + col] = Xacc[r];
    yo[row * 32 + col] = Yacc[r];
  }
}

// ------- merged: MFMA serial scan x2 (blocks 0-63) + FIR conv (64+) --------
__global__ __launch_bounds__(512, 2) void delta_fir(
    const ushort_t* __restrict__ wn_bf, const ushort_t* __restrict__ q_bf,
    const ushort_t* __restrict__ knT_bf, const float* __restrict__ attn_g,
    const float* __restrict__ u_g, const float* __restrict__ X_g,
    const float* __restrict__ Y_g, float* __restrict__ delta_g,
    const float* __restrict__ v, const float* __restrict__ wlg,
    const float* __restrict__ wsg, float* __restrict__ firl,
    float* __restrict__ firs)
{
  __shared__ __attribute__((aligned(16))) char smem[81920];
  int t = threadIdx.x;

  if (blockIdx.x >= 64) {
    // -------- FIR part: 2 adjacent 8-row units share one 78-row window ----
    float (*vt)[79] = (float(*)[79])smem;           // 256 ch x 78 rows (pad 79)
    int bid = blockIdx.x - 64;                      // 0..1023
    int half = t >> 8, c = t & 255;
    int unit = bid * 2 + half;                      // 0..2047
    int lt = unit & 255;
    int bh = unit >> 8;                             // same for both halves
    int b = bh >> 2, h = bh & 3;
    int l0 = lt * 8;
    int base_l = ((bid * 2) & 255) * 8 - 62;        // shared window base row
    const float* vp = v + (size_t)bh * Ls * 256;
    for (int r = half * 39; r < half * 39 + 39 && r < 78; ++r) {
      int ls = base_l + r;
      vt[c][r] = (ls >= 0) ? vp[(size_t)ls * 256 + c] : 0.f;
    }
    float TL[63], TS3[3];
#pragma unroll
    for (int j = 0; j < 63; ++j) TL[j] = wlg[((size_t)h * 256 + c) * 63 + j];
#pragma unroll
    for (int j = 0; j < 3; ++j) TS3[j] = wsg[((size_t)h * 256 + c) * 3 + j];
    __syncthreads();
    int roff = half * 8;                            // unit's offset in window
    float aL[8] = {0,0,0,0,0,0,0,0}, aS[8] = {0,0,0,0,0,0,0,0};
#pragma unroll
    for (int r = 0; r < 70; ++r) {
      float vm = vt[c][roff + r];
#pragma unroll
      for (int p = 0; p < 8; ++p) {
        int jl = r - p;
        if (jl >= 0 && jl < 63) aL[p] = fmaf(vm, TL[jl], aL[p]);
        int jssrc = r - 60 - p;
        if (jssrc >= 0 && jssrc < 3) aS[p] = fmaf(vm, TS3[jssrc], aS[p]);
      }
    }
#pragma unroll
    for (int p = 0; p < 8; ++p) {
      int l = l0 + p;
      size_t ob = (((size_t)b * Ls + l) * NH + h) * 256 + c;
      firl[ob] = aL[p];
      firs[ob] = aS[p];
    }
    return;
  }

  // -------- chain part: 2 independent chains per block (m=2 super-chunks) --
  int half = t >> 8, tt = t & 255;
  char* cbase = smem + half * 21248;
  ushort_t (*Shi)[264] = (ushort_t(*)[264])(cbase);
  ushort_t (*Slo)[264] = (ushort_t(*)[264])(cbase + 8448);
  float (*u2L0)[17] = (float(*)[17])(cbase + 16896);
  float (*u2L1)[17] = (float(*)[17])(cbase + 19072);
  int unit = blockIdx.x * 2 + half;                 // 0..127
  int bh = unit & 7, g = unit >> 3;
  int b = bh >> 2, h = bh & 3;
  int wv = tt >> 6, lane = tt & 63;
  int lquad = lane >> 4, l16 = lane & 15;
  int j0 = g * 16;
  int Mt = wv & 1;
  bool isU = (wv < 2);
  const ushort_t* wp = wn_bf + (size_t)bh * Ls * 256;
  const ushort_t* qp = q_bf  + (size_t)bh * Ls * 256;
  const ushort_t* ap = (isU ? wp : qp) + (size_t)(Mt * 16 + l16) * 256;
  const ushort_t* kr = knT_bf + (size_t)bh * Ls * 256 + (size_t)l16 * 32 + lquad * 8;
  const float* urow = u_g + (size_t)bh * Ls * 256
                    + (size_t)(Mt * 16 + lquad * 4) * 256 + j0 + l16;
  const float* arp = attn_g + (size_t)bh * 64 * 1024
                   + (size_t)(Mt * 16 + l16) * 32 + lquad * 8;
  const float* xrp = (isU ? X_g : Y_g) + (size_t)bh * 32768
                   + (size_t)(Mt * 16 + l16) * 32 + lquad * 8;

  floatx4 Sacc[4], SaccL[4];
#pragma unroll
  for (int i = 0; i < 4; ++i)
#pragma unroll
    for (int r = 0; r < 4; ++r) { Sacc[i][r] = 0.f; SaccL[i][r] = 0.f; }
  for (int i = tt; i < 4224; i += 256) ((u32*)cbase)[i] = 0;

  // prologue: super-chunk 0, sub-chunk 0 operands
  short8 a0[8], k0[4];
  floatx4 u0 = {0.f, 0.f, 0.f, 0.f};
  float4 at0a = {0,0,0,0}, at0b = {0,0,0,0};
#pragma unroll
  for (int ks = 0; ks < 8; ++ks)
    a0[ks] = *(const short8*)(ap + ks * 32 + lquad * 8);
#pragma unroll
  for (int i = 0; i < 4; ++i)
    k0[i] = *(const short8*)(kr + (size_t)(wv * 4 + i) * 512);
  if (isU) {
#pragma unroll
    for (int r = 0; r < 4; ++r) u0[r] = urow[(size_t)r * 256];
  } else {
    at0a = *(const float4*)(arp);
    at0b = *(const float4*)(arp + 4);
  }
  wave_barrier();

  for (int sc = 0; sc < 32; ++sc) {
    size_t cb1 = (size_t)sc * 16384 + 8192;
    size_t nb0 = (size_t)(sc + 1) * 16384;
    bool hasN = (sc + 1 < 32);

    // sub-chunk1 operands + cross matrix (used mid-iteration; latency covered)
    short8 a1[8], k1[4];
    floatx4 u1 = {0.f, 0.f, 0.f, 0.f};
    float4 at1a = {0,0,0,0}, at1b = {0,0,0,0};
#pragma unroll
    for (int ks = 0; ks < 8; ++ks)
      a1[ks] = *(const short8*)(ap + cb1 + ks * 32 + lquad * 8);
#pragma unroll
    for (int i = 0; i < 4; ++i)
      k1[i] = *(const short8*)(kr + cb1 + (size_t)(wv * 4 + i) * 512);
    if (isU) {
#pragma unroll
      for (int r = 0; r < 4; ++r) u1[r] = urow[cb1 + (size_t)r * 256];
    } else {
      size_t na = (size_t)(2 * sc + 1) * 1024;
      at1a = *(const float4*)(arp + na);
      at1b = *(const float4*)(arp + na + 4);
    }
    float4 xa = *(const float4*)(xrp + (size_t)sc * 1024);
    float4 xb = *(const float4*)(xrp + (size_t)sc * 1024 + 4);

    // ---- sub-chunk 0: u2_0 (isU) / po_0 (o) against S0 ----
    floatx4 acc0;
    if (isU) {
      floatx4 A0 = u0, A1 = {0,0,0,0}, A2 = {0,0,0,0}, A3 = {0,0,0,0};
#pragma unroll
      for (int ks = 0; ks < 8; ++ks) {
        short8 sh = *(const short8*)&Shi[l16][ks * 32 + lquad * 8];
        short8 sl = *(const short8*)&Slo[l16][ks * 32 + lquad * 8];
        if (ks & 1) {
          A1 = __builtin_amdgcn_mfma_f32_16x16x32_bf16(a0[ks], sh, A1, 0, 0, 0);
          A3 = __builtin_amdgcn_mfma_f32_16x16x32_bf16(a0[ks], sl, A3, 0, 0, 0);
        } else {
          A0 = __builtin_amdgcn_mfma_f32_16x16x32_bf16(a0[ks], sh, A0, 0, 0, 0);
          A2 = __builtin_amdgcn_mfma_f32_16x16x32_bf16(a0[ks], sl, A2, 0, 0, 0);
        }
      }
#pragma unroll
      for (int r = 0; r < 4; ++r) acc0[r] = (A0[r] + A1[r]) + (A2[r] + A3[r]);
#pragma unroll
      for (int r = 0; r < 4; ++r)
        u2L0[Mt * 16 + lquad * 4 + r][l16] = acc0[r];
    } else {
      floatx4 A0 = {0,0,0,0}, A1 = {0,0,0,0};
#pragma unroll
      for (int ks = 0; ks < 8; ++ks) {
        short8 sh = *(const short8*)&Shi[l16][ks * 32 + lquad * 8];
        if (ks & 1) A1 = __builtin_amdgcn_mfma_f32_16x16x32_bf16(a0[ks], sh, A1, 0, 0, 0);
        else        A0 = __builtin_amdgcn_mfma_f32_16x16x32_bf16(a0[ks], sh, A0, 0, 0, 0);
      }
#pragma unroll
      for (int r = 0; r < 4; ++r) acc0[r] = A0[r] + A1[r];
    }
    // prefetch next-super-chunk a0 (a0 regs dead; stays in flight across
    // the raw barriers below -> ~full iteration of latency cover)
    if (hasN) {
#pragma unroll
      for (int ks = 0; ks < 8; ++ks)
        a0[ks] = *(const short8*)(ap + nb0 + ks * 32 + lquad * 8);
    }
    wave_barrier();                          // u2_0 visible

    short8 uh0, ul0;
#pragma unroll
    for (int j = 0; j < 8; ++j) {
      float f = u2L0[lquad * 8 + j][l16];
      ushort_t hi = f2bf(f);
      uh0[j] = (short)hi;
      ul0[j] = (short)f2bf(f - bf2f(hi));
    }
#pragma unroll
    for (int i = 0; i < 4; ++i) {
      Sacc[i]  = __builtin_amdgcn_mfma_f32_16x16x32_bf16(k0[i], uh0, Sacc[i], 0, 0, 0);
      SaccL[i] = __builtin_amdgcn_mfma_f32_16x16x32_bf16(k0[i], ul0, SaccL[i], 0, 0, 0);
    }
    if (hasN) {
#pragma unroll
      for (int i = 0; i < 4; ++i)
        k0[i] = *(const short8*)(kr + nb0 + (size_t)(wv * 4 + i) * 512);
    }

    // ---- sub-chunk 1: u2_1 = u1 + wn1@S0 + X@u2_0 / o path ----
    floatx4 acc1;
    if (isU) {
      floatx4 A0 = u1, A1 = {0,0,0,0}, A2 = {0,0,0,0}, A3 = {0,0,0,0};
#pragma unroll
      for (int ks = 0; ks < 8; ++ks) {
        short8 sh = *(const short8*)&Shi[l16][ks * 32 + lquad * 8];
        short8 sl = *(const short8*)&Slo[l16][ks * 32 + lquad * 8];
        if (ks & 1) {
          A1 = __builtin_amdgcn_mfma_f32_16x16x32_bf16(a1[ks], sh, A1, 0, 0, 0);
          A3 = __builtin_amdgcn_mfma_f32_16x16x32_bf16(a1[ks], sl, A3, 0, 0, 0);
        } else {
          A0 = __builtin_amdgcn_mfma_f32_16x16x32_bf16(a1[ks], sh, A0, 0, 0, 0);
          A2 = __builtin_amdgcn_mfma_f32_16x16x32_bf16(a1[ks], sl, A2, 0, 0, 0);
        }
      }
      short8 Xh, Xl;
      cvt8(xa, xb, Xh, Xl);
      A0 = __builtin_amdgcn_mfma_f32_16x16x32_bf16(Xh, uh0, A0, 0, 0, 0);
      A1 = __builtin_amdgcn_mfma_f32_16x16x32_bf16(Xh, ul0, A1, 0, 0, 0);
      A2 = __builtin_amdgcn_mfma_f32_16x16x32_bf16(Xl, uh0, A2, 0, 0, 0);
#pragma unroll
      for (int r = 0; r < 4; ++r) acc1[r] = (A0[r] + A1[r]) + (A2[r] + A3[r]);
#pragma unroll
      for (int r = 0; r < 4; ++r)
        u2L1[Mt * 16 + lquad * 4 + r][l16] = acc1[r];
      if (hasN) {
#pragma unroll
        for (int r = 0; r < 4; ++r) u0[r] = urow[nb0 + (size_t)r * 256];
      }
    } else {
      // o_0 = po_0 + attn_0 @ u2_0 -> store
      short8 ath, atl;
      cvt8(at0a, at0b, ath, atl);
      acc0 = __builtin_amdgcn_mfma_f32_16x16x32_bf16(ath, uh0, acc0, 0, 0, 0);
      acc0 = __builtin_amdgcn_mfma_f32_16x16x32_bf16(ath, ul0, acc0, 0, 0, 0);
      acc0 = __builtin_amdgcn_mfma_f32_16x16x32_bf16(atl, uh0, acc0, 0, 0, 0);
#pragma unroll
      for (int r = 0; r < 4; ++r) {
        int l = sc * 64 + Mt * 16 + lquad * 4 + r;
        delta_g[(((size_t)b * Ls + l) * NH + h) * 256 + j0 + l16] = acc0[r];
      }
      // po_1 = q1 @ Shi(S0) + Y @ u2_0
      floatx4 A0 = {0,0,0,0}, A1 = {0,0,0,0};
#pragma unroll
      for (int ks = 0; ks < 8; ++ks) {
        short8 sh = *(const short8*)&Shi[l16][ks * 32 + lquad * 8];
        if (ks & 1) A1 = __builtin_amdgcn_mfma_f32_16x16x32_bf16(a1[ks], sh, A1, 0, 0, 0);
        else        A0 = __builtin_amdgcn_mfma_f32_16x16x32_bf16(a1[ks], sh, A0, 0, 0, 0);
      }
      short8 Yh, Yl;
      cvt8(xa, xb, Yh, Yl);
      A0 = __builtin_amdgcn_mfma_f32_16x16x32_bf16(Yh, uh0, A0, 0, 0, 0);
      A1 = __builtin_amdgcn_mfma_f32_16x16x32_bf16(Yh, ul0, A1, 0, 0, 0);
      A0 = __builtin_amdgcn_mfma_f32_16x16x32_bf16(Yl, uh0, A0, 0, 0, 0);
#pragma unroll
      for (int r = 0; r < 4; ++r) acc1[r] = A0[r] + A1[r];
      if (hasN) {
        size_t na0 = (size_t)(2 * sc + 2) * 1024;
        at0a = *(const float4*)(arp + na0);
        at0b = *(const float4*)(arp + na0 + 4);
      }
    }
    wave_barrier();                          // u2_1 visible; all Shi/Slo reads done

    short8 uh1, ul1;
#pragma unroll
    for (int j = 0; j < 8; ++j) {
      float f = u2L1[lquad * 8 + j][l16];
      ushort_t hi = f2bf(f);
      uh1[j] = (short)hi;
      ul1[j] = (short)f2bf(f - bf2f(hi));
    }
#pragma unroll
    for (int i = 0; i < 4; ++i) {
      Sacc[i]  = __builtin_amdgcn_mfma_f32_16x16x32_bf16(k1[i], uh1, Sacc[i], 0, 0, 0);
      SaccL[i] = __builtin_amdgcn_mfma_f32_16x16x32_bf16(k1[i], ul1, SaccL[i], 0, 0, 0);
    }
    if (!isU) {
      short8 ath, atl;
      cvt8(at1a, at1b, ath, atl);
      acc1 = __builtin_amdgcn_mfma_f32_16x16x32_bf16(ath, uh1, acc1, 0, 0, 0);
      acc1 = __builtin_amdgcn_mfma_f32_16x16x32_bf16(ath, ul1, acc1, 0, 0, 0);
      acc1 = __builtin_amdgcn_mfma_f32_16x16x32_bf16(atl, uh1, acc1, 0, 0, 0);
#pragma unroll
      for (int r = 0; r < 4; ++r) {
        int l = sc * 64 + 32 + Mt * 16 + lquad * 4 + r;
        delta_g[(((size_t)b * Ls + l) * NH + h) * 256 + j0 + l16] = acc1[r];
      }
    }
    // S write-back (once per 64 tokens)
#pragma unroll
    for (int i = 0; i < 4; ++i) {
      int dk0 = (wv * 4 + i) * 16 + lquad * 4;
      ushort4 h4, l4;
      ushort_t* hp = (ushort_t*)&h4;
      ushort_t* lp = (ushort_t*)&l4;
#pragma unroll
      for (int r = 0; r < 4; ++r) {
        float sv = Sacc[i][r] + SaccL[i][r];
        ushort_t hi = f2bf(sv);
        hp[r] = hi;
        lp[r] = f2bf(sv - bf2f(hi));
      }
      *(ushort4*)&Shi[l16][dk0] = h4;
      *(ushort4*)&Slo[l16][dk0] = l4;
    }
    wave_barrier();                          // S visible
  }
}

// ------- gate_in (bf16) ----------------------------------------------------
__global__ __launch_bounds__(256) void build_gate_in_bf(
    const float* __restrict__ x, const float* __restrict__ firs,
    const float* __restrict__ firl, const float* __restrict__ delta,
    const float* __restrict__ v, ushort_t* __restrict__ gin)
{
  int mtok = blockIdx.x, t = threadIdx.x;
  int b = mtok >> 11, l = mtok & 2047;
  float4 xv = *(const float4*)(x + (size_t)mtok * 1024 + t * 4);
  ushort4 xo = make_ushort4(f2bf(xv.x), f2bf(xv.y), f2bf(xv.z), f2bf(xv.w));
  *(ushort4*)(gin + (size_t)mtok * 1056 + t * 4) = xo;
  int w = t >> 6, lane = t & 63;
  for (int br = 0; br < 4; ++br) {
    float s = 0.f, s2 = 0.f;
#pragma unroll
    for (int r = 0; r < 4; ++r) {
      int d = lane + r * 64;
      float val;
      if (br == 0)      val = firs [(size_t)mtok * 1024 + w * 256 + d];
      else if (br == 1) val = firl [(size_t)mtok * 1024 + w * 256 + d];
      else if (br == 2) val = delta[(size_t)mtok * 1024 + w * 256 + d];
      else              val = v[(((size_t)(b * NH + w)) * Ls + l) * 256 + d];
      s += val; s2 = fmaf(val, val, s2);
    }
#pragma unroll
    for (int off = 32; off; off >>= 1) {
      s += __shfl_down(s, off);
      s2 += __shfl_down(s2, off);
    }
    if (lane == 0) {
      float mean = s * (1.f / 256.f);
      float var = s2 * (1.f / 256.f) - mean * mean;
      gin[(size_t)mtok * 1056 + 1024 + br * 8 + w] = f2bf(mean);
      gin[(size_t)mtok * 1056 + 1024 + br * 8 + 4 + w] = f2bf(sqrtf(fmaxf(var, 1e-6f)));
    }
  }
}

// ------- logits -> gates (bf16 hidden input) -------------------------------
__global__ __launch_bounds__(256) void mlp2_gates(
    const ushort_t* __restrict__ mh, const float* __restrict__ W2,
    const float* __restrict__ b2, const float* __restrict__ glt,
    float* __restrict__ gates)
{
  int mtok = blockIdx.x, t = threadIdx.x;
  float p[16];
#pragma unroll
  for (int j = 0; j < 16; ++j) p[j] = 0.f;
  for (int k = t; k < 2048; k += 256) {
    float hv = bf2f(mh[(size_t)mtok * 2048 + k]);
    const float* wr = W2 + (size_t)k * 16;
#pragma unroll
    for (int j4 = 0; j4 < 4; ++j4) {
      float4 w4 = *(const float4*)(wr + j4 * 4);
      p[j4*4+0] = fmaf(hv, w4.x, p[j4*4+0]);
      p[j4*4+1] = fmaf(hv, w4.y, p[j4*4+1]);
      p[j4*4+2] = fmaf(hv, w4.z, p[j4*4+2]);
      p[j4*4+3] = fmaf(hv, w4.w, p[j4*4+3]);
    }
  }
#pragma unroll
  for (int j = 0; j < 16; ++j)
#pragma unroll
    for (int off = 32; off; off >>= 1) p[j] += __shfl_down(p[j], off);
  __shared__ float red[4][16];
  __shared__ float zl[16];
  int w = t >> 6;
  if ((t & 63) == 0) {
#pragma unroll
    for (int j = 0; j < 16; ++j) red[w][j] = p[j];
  }
  __syncthreads();
  if (t < 16) {
    float tot = red[0][t] + red[1][t] + red[2][t] + red[3][t] + b2[t];
    float tempv = log1pf(expf(glt[t >> 2])) + 1e-4f;
    zl[t] = tot / tempv;
  }
  __syncthreads();
  if (t < 4) {
    float z0 = zl[t*4], z1 = zl[t*4+1], z2 = zl[t*4+2], z3 = zl[t*4+3];
    float mx = fmaxf(fmaxf(z0, z1), fmaxf(z2, z3));
    float e0 = expf(z0 - mx), e1 = expf(z1 - mx), e2 = expf(z2 - mx), e3 = expf(z3 - mx);
    float inv = 1.f / (e0 + e1 + e2 + e3);
    gates[(size_t)mtok * 16 + t * 4 + 0] = e0 * inv;
    gates[(size_t)mtok * 16 + t * 4 + 1] = e1 * inv;
    gates[(size_t)mtok * 16 + t * 4 + 2] = e2 * inv;
    gates[(size_t)mtok * 16 + t * 4 + 3] = e3 * inv;
  }
}

// ------- o = gated mix, RMSNorm -> bf16 ------------------------------------
__global__ __launch_bounds__(256) void combine_norm_bf(
    const float* __restrict__ firs, const float* __restrict__ firl,
    const float* __restrict__ delta, const float* __restrict__ v,
    const float* __restrict__ gates, const float* __restrict__ onw,
    ushort_t* __restrict__ o)
{
  int mh = blockIdx.x;
  int mtok = mh >> 2, h = mh & 3;
  int t = threadIdx.x;
  int b = mtok >> 11, l = mtok & 2047;
  const float* g = gates + (size_t)mtok * 16 + h * 4;
  float w0 = g[0], w1 = g[1], w2 = g[2], w3 = g[3];
  size_t tb = (size_t)mtok * 1024 + h * 256 + t;
  float val = w0 * firs[tb] + w1 * firl[tb] + w2 * delta[tb]
            + w3 * v[(((size_t)(b * NH + h)) * Ls + l) * 256 + t];
  float s2 = val * val;
#pragma unroll
  for (int off = 32; off; off >>= 1) s2 += __shfl_down(s2, off);
  __shared__ float r4[4];
  if ((t & 63) == 0) r4[t >> 6] = s2;
  __syncthreads();
  float tot = r4[0] + r4[1] + r4[2] + r4[3];
  float rms = rsqrtf(tot * (1.f / 256.f) + 1e-5f);
  o[tb] = f2bf(val * rms * onw[t]);
}

// ---------------------------------------------------------------------------
extern "C" void kernel_launch(void* const* d_in, const int* in_sizes, int n_in,
                              void* d_out, int out_size, void* d_ws, size_t ws_size,
                              hipStream_t stream) {
  const float* x     = (const float*)d_in[0];
  const float* Wq    = (const float*)d_in[1];
  const float* Wk    = (const float*)d_in[2];
  const float* Wv    = (const float*)d_in[3];
  const float* Wb    = (const float*)d_in[4];
  const float* convq = (const float*)d_in[5];
  const float* convk = (const float*)d_in[6];
  const float* convv = (const float*)d_in[7];
  const float* firsw = (const float*)d_in[8];
  const float* firlw = (const float*)d_in[9];
  const float* mlpw1 = (const float*)d_in[10];
  const float* mlpb1 = (const float*)d_in[11];
  const float* mlpw2 = (const float*)d_in[12];
  const float* mlpb2 = (const float*)d_in[13];
  const float* glt   = (const float*)d_in[14];
  const float* onw   = (const float*)d_in[15];
  const float* Wo    = (const float*)d_in[16];
  float* ws = (float*)d_ws;

  ushort_t* x_bf   = (ushort_t*)(ws + off_firs);
  ushort_t* Wqkv_t = (ushort_t*)(ws + off_firl);  // 3 x [1024][1024] contiguous
  ushort_t* gin_bf = (ushort_t*)(ws + off_gin);
  ushort_t* w1_t   = (ushort_t*)(ws + off_k);     // kn dead after chunk_prep
  ushort_t* o_bf   = (ushort_t*)(ws + off_xv);
  ushort_t* Wo_t   = (ushort_t*)(ws + off_beta);  // spans into attn (dead)
  ushort_t* mlph_bf= (ushort_t*)(ws + off_mlph);
  ushort_t* wn_bf  = (ushort_t*)(ws + off_firs);
  ushort_t* q_bf   = (ushort_t*)(ws + off_firs + 2097152);
  ushort_t* knT_bf = (ushort_t*)(ws + off_firl);
  ushort_t* kn_bf  = (ushort_t*)(ws + off_xq);    // x3 dead after conv_prep
  float* x3   = ws + off_xq;     // fused [4096][3072] spans xq/xk/xv
  float* kb_f = ws + off_gin;
  float* vb_f = ws + off_mlph;
  float* X_g  = ws + off_gin;            // kb dead after chunk_prep; 8*32*1024 f32
  float* Y_g  = ws + off_gin + 262144;
  float* firs_f = ws + off_xq;   // x3/kn_bf dead after cross_prep
  float* firl_f = ws + off_xk;

  dim3 blk(256);
  // fused q/k/v projection (one N=3072 GEMM) + beta
  to_bf16<<<2048, blk, 0, stream>>>(x, x_bf, 4194304);
  convT<<<dim3(32, 32), blk, 0, stream>>>(Wq, Wqkv_t, 1024, 1024);
  convT<<<dim3(32, 32), blk, 0, stream>>>(Wk, Wqkv_t + 1048576, 1024, 1024);
  convT<<<dim3(32, 32), blk, 0, stream>>>(Wv, Wqkv_t + 2097152, 1024, 1024);
  gemm_bf16<<<dim3(24, 32), blk, 0, stream>>>(x_bf, Wqkv_t, x3, 3072, 1024, nullptr, 0, 0);
  beta_sigmoid<<<4096, blk, 0, stream>>>(x, Wb, ws + off_beta);
  // fused conv4+silu + l2norm + beta products
  conv_prep<<<16384, blk, 0, stream>>>(x3, convq, convk, convv, ws + off_beta,
                                       ws + off_q, ws + off_k, kb_f, vb_f, ws + off_v);
  // per-chunk T inverse, attn, u (->xv), bf16 {-w, q, knT, kn}
  chunk_prep<<<512, blk, 0, stream>>>(kb_f, ws + off_k, ws + off_q, vb_f,
                                      ws + off_attn, ws + off_xv, wn_bf, q_bf,
                                      knT_bf, kn_bf);
  // 32x32 cross matrices per super-chunk (X = wn1 kn0^T, Y = q1 kn0^T)
  cross_prep<<<256, blk, 0, stream>>>(wn_bf, q_bf, kn_bf, X_g, Y_g);
  // merged serial MFMA scan x2/block (delta -> off_q) + FIR (-> x3 regions)
  delta_fir<<<1088, dim3(512), 0, stream>>>(wn_bf, q_bf, knT_bf, ws + off_attn,
                                            ws + off_xv, X_g, Y_g, ws + off_q,
                                            ws + off_v, firlw, firsw, firl_f, firs_f);
  // gate input (bf16), MLP1 (MFMA, gelu, bf16 out), gates
  build_gate_in_bf<<<4096, blk, 0, stream>>>(x, firs_f, firl_f, ws + off_q,
                                             ws + off_v, gin_bf);
  convT<<<dim3(64, 33), blk, 0, stream>>>(mlpw1, w1_t, 1056, 2048);
  gemm_bf16<<<dim3(16, 32), blk, 0, stream>>>(gin_bf, w1_t, (float*)mlph_bf,
                                              2048, 1056, mlpb1, 1, 1);
  mlp2_gates<<<4096, blk, 0, stream>>>(mlph_bf, mlpw2, mlpb2, glt, ws + off_gates);
  // combine + RMSNorm -> bf16, output projection (MFMA)
  combine_norm_bf<<<16384, blk, 0, stream>>>(firs_f, firl_f, ws + off_q,
                                             ws + off_v, ws + off_gates, onw, o_bf);
  convT<<<dim3(32, 32), blk, 0, stream>>>(Wo, Wo_t, 1024, 1024);
  gemm_bf16<<<dim3(8, 32), blk, 0, stream>>>(o_bf, Wo_t, (float*)d_out, 1024, 1024, nullptr, 0, 0);
}

// Round 5
// 613.180 us; speedup vs baseline: 1.1953x; 1.0311x over previous
//
#include <hip/hip_runtime.h>
#include <hip/hip_bf16.h>

// ---------------------------------------------------------------------------
// DeltaNet forward, round 12:
//  - Chain/prep/epilogue kernels VERBATIM from r8 (proven 546us, delta_fir
//    146us). r10 (CHUNK=128) and r11 (2 chains/block) both regressed: the
//    scan is exposed-latency-bound and r8's deep-prefetch 128-block layout
//    is the verified optimum among tried structures.
//  - NEW: prep1 mega-kernel merges the 6 input-only launches (to_bf16,
//    convT x Wq/Wk/Wv, convT mlpw1, convT Wo, beta_sigmoid) into ONE launch
//    (16 -> 11 launches). w1_t / Wo_t relocated to the never-used upper half
//    of the off_mlph window so they can be built before conv_prep without
//    clobbering kn (off_k) or beta (off_beta).
// ---------------------------------------------------------------------------

#define DEVI __device__ __forceinline__
typedef unsigned int u32;
typedef unsigned short ushort_t;
typedef __attribute__((ext_vector_type(8))) short short8;
typedef __attribute__((ext_vector_type(4))) float floatx4;

constexpr int Ls = 2048, NH = 4;

// workspace offsets (floats)
constexpr size_t off_xq   = 0;         // x3 [m][3072] cols 0-1023 -> kn_bf -> firs
constexpr size_t off_xk   = 4194304;   // x3 cols 1024-2047 -> firl
constexpr size_t off_xv   = 8388608;   // x3 cols 2048-3071 -> u -> o_bf
constexpr size_t off_q    = 12582912;  // qn -> delta
constexpr size_t off_k    = 16777216;  // kn (dead after chunk_prep)
constexpr size_t off_v    = 20971520;  // v (alive to the end)
constexpr size_t off_beta = 25165824;  // beta (dead after conv_prep)
constexpr size_t off_attn = 25182208;  // attn (dead after chain)
constexpr size_t off_firs = 25706496;  // x_bf -> {wn_bf, q_bf} (bf16)
constexpr size_t off_firl = 29900800;  // Wqkv_t -> knT_bf (bf16)
constexpr size_t off_gin  = 34095104;  // kb (f32) -> {X_g, Y_g} -> gin_bf
constexpr size_t off_mlph = 38420480;  // vb (f32) -> mlph_bf (lower half)
constexpr size_t off_w1t  = 42614784;  // w1_t (bf16, 1.08M fl) - never-aliased
constexpr size_t off_wot  = 43696128;  // Wo_t (bf16, 0.52M fl) - never-aliased
constexpr size_t off_gates= 46809088;  // gates

DEVI float sigmoidf_(float x) { return 1.f / (1.f + expf(-x)); }
DEVI float siluf_(float x) { return x / (1.f + expf(-x)); }
DEVI float geluf_(float x) { return 0.5f * x * (1.f + erff(x * 0.7071067811865476f)); }
DEVI ushort_t f2bf(float f) {
  union { float f; u32 u; } c{f};
  u32 r = (c.u + 0x7fffu + ((c.u >> 16) & 1u)) >> 16;
  return (ushort_t)r;
}
DEVI float bf2f(ushort_t h) {
  union { u32 u; float f; } c; c.u = ((u32)h) << 16; return c.f;
}
DEVI void cvt8(float4 a, float4 b, short8& hi, short8& lo) {
  float f[8] = {a.x,a.y,a.z,a.w,b.x,b.y,b.z,b.w};
#pragma unroll
  for (int j = 0; j < 8; ++j) {
    ushort_t h = f2bf(f[j]);
    hi[j] = (short)h;
    lo[j] = (short)f2bf(f[j] - bf2f(h));
  }
}
DEVI void async16(const void* g, void* l) {
  __builtin_amdgcn_global_load_lds(
      (const u32 __attribute__((address_space(1)))*)g,
      (u32 __attribute__((address_space(3)))*)l, 16, 0, 0);
}
// Raw workgroup barrier: waits LDS ops only (lgkmcnt), leaves global
// loads/stores (vmcnt) in flight. All cross-wave deps in the chain loop are
// LDS-only, and global data has no in-kernel consumers.
DEVI void wave_barrier() {
  __builtin_amdgcn_sched_barrier(0);
  asm volatile("s_waitcnt lgkmcnt(0)" ::: "memory");
  __builtin_amdgcn_s_barrier();
  __builtin_amdgcn_sched_barrier(0);
}

// ------- prep1: to_bf16 + convT(Wq/Wk/Wv) + convT(w1) + convT(Wo) + beta ---
DEVI void convT_body(const float* __restrict__ W, ushort_t* __restrict__ out,
                     int Kq, int Nq, int n0, int k0,
                     ushort_t (*tile)[33], int t)
{
  int tx = t & 31, ty = t >> 5;
#pragma unroll
  for (int r = 0; r < 32; r += 8)
    tile[ty + r][tx] = f2bf(W[(size_t)(k0 + ty + r) * Nq + n0 + tx]);
  __syncthreads();
#pragma unroll
  for (int r = 0; r < 32; r += 8)
    out[(size_t)(n0 + ty + r) * Kq + k0 + tx] = tile[tx][ty + r];
}

__global__ __launch_bounds__(256) void prep1(
    const float* __restrict__ x, ushort_t* __restrict__ x_bf,
    const float* __restrict__ Wq, const float* __restrict__ Wk,
    const float* __restrict__ Wv, ushort_t* __restrict__ Wqkv_t,
    const float* __restrict__ mlpw1, ushort_t* __restrict__ w1_t,
    const float* __restrict__ Wo, ushort_t* __restrict__ Wo_t,
    const float* __restrict__ Wb, float* __restrict__ beta)
{
  __shared__ ushort_t tile[32][33];
  __shared__ float red[4][4];
  int bid = blockIdx.x, t = threadIdx.x;
  if (bid < 2048) {
    // to_bf16 (x -> x_bf, 4194304 elems)
    int i = (bid * 256 + t) * 8;
    float4 a = *(const float4*)(x + i);
    float4 b = *(const float4*)(x + i + 4);
    ushort_t o[8] = { f2bf(a.x), f2bf(a.y), f2bf(a.z), f2bf(a.w),
                      f2bf(b.x), f2bf(b.y), f2bf(b.z), f2bf(b.w) };
    *(uint4*)(x_bf + i) = *(uint4*)o;
    return;
  }
  if (bid < 5120) {
    // convT Wq/Wk/Wv -> Wqkv_t (each 1024x1024, grid 32x32)
    int local = bid - 2048;
    int which = local >> 10;            // 0,1,2
    int g = local & 1023;
    const float* W = which == 0 ? Wq : (which == 1 ? Wk : Wv);
    ushort_t* out = Wqkv_t + (size_t)which * 1048576;
    convT_body(W, out, 1024, 1024, (g & 31) * 32, (g >> 5) * 32, tile, t);
    return;
  }
  if (bid < 7232) {
    // convT mlpw1 [1056][2048] -> w1_t [2048][1056], grid 64x33
    int local = bid - 5120;
    convT_body(mlpw1, w1_t, 1056, 2048, (local % 64) * 32, (local / 64) * 32, tile, t);
    return;
  }
  if (bid < 8256) {
    // convT Wo [1024][1024] -> Wo_t, grid 32x32
    int local = bid - 7232;
    convT_body(Wo, Wo_t, 1024, 1024, (local & 31) * 32, (local >> 5) * 32, tile, t);
    return;
  }
  // beta = sigmoid(x @ Wb)
  int mtok = bid - 8256;
  int b = mtok >> 11, l = mtok & 2047;
  float a0 = 0, a1 = 0, a2 = 0, a3 = 0;
  for (int k = t; k < 1024; k += 256) {
    float xv = x[(size_t)mtok * 1024 + k];
    float4 w4 = *(const float4*)(Wb + k * 4);
    a0 = fmaf(xv, w4.x, a0); a1 = fmaf(xv, w4.y, a1);
    a2 = fmaf(xv, w4.z, a2); a3 = fmaf(xv, w4.w, a3);
  }
#pragma unroll
  for (int off = 32; off; off >>= 1) {
    a0 += __shfl_down(a0, off); a1 += __shfl_down(a1, off);
    a2 += __shfl_down(a2, off); a3 += __shfl_down(a3, off);
  }
  int w = t >> 6;
  if ((t & 63) == 0) { red[w][0] = a0; red[w][1] = a1; red[w][2] = a2; red[w][3] = a3; }
  __syncthreads();
  if (t < 4) {
    float s = red[0][t] + red[1][t] + red[2][t] + red[3][t];
    beta[((size_t)(b * NH + t)) * Ls + l] = sigmoidf_(s);
  }
}

// ---------------- bf16 MFMA GEMM -------------------------------------------
__global__ __launch_bounds__(256) void gemm_bf16(
    const ushort_t* __restrict__ A, const ushort_t* __restrict__ Bt,
    float* __restrict__ C, int Nq, int Kq,
    const float* __restrict__ bias, int act, int outbf)
{
  __shared__ ushort_t As[128 * 32];
  __shared__ ushort_t Bs[128 * 32];
  int t = threadIdx.x;
  int w = t >> 6, lane = t & 63;
  int m0 = blockIdx.y * 128, n0 = blockIdx.x * 128;
  floatx4 acc[4][4];
#pragma unroll
  for (int i = 0; i < 4; ++i)
#pragma unroll
    for (int j = 0; j < 4; ++j)
#pragma unroll
      for (int r = 0; r < 4; ++r) acc[i][j][r] = 0.f;

  int lrow = lane >> 2, lk8 = (lane & 3) * 8;
  for (int kt = 0; kt < Kq; kt += 32) {
#pragma unroll
    for (int r = 0; r < 2; ++r) {
      int seg = w * 2 + r;
      int row = seg * 16 + lrow;
      async16(A  + (size_t)(m0 + row) * Kq + kt + lk8, &As[seg * 512]);
      async16(Bt + (size_t)(n0 + row) * Kq + kt + lk8, &Bs[seg * 512]);
    }
    __syncthreads();
    short8 af[4], bf[4];
#pragma unroll
    for (int i = 0; i < 4; ++i) {
      int row = (w >> 1) * 64 + i * 16 + (lane & 15);
      af[i] = *(const short8*)&As[row * 32 + (lane >> 4) * 8];
    }
#pragma unroll
    for (int j = 0; j < 4; ++j) {
      int col = (w & 1) * 64 + j * 16 + (lane & 15);
      bf[j] = *(const short8*)&Bs[col * 32 + (lane >> 4) * 8];
    }
#pragma unroll
    for (int i = 0; i < 4; ++i)
#pragma unroll
      for (int j = 0; j < 4; ++j)
        acc[i][j] = __builtin_amdgcn_mfma_f32_16x16x32_bf16(af[i], bf[j], acc[i][j], 0, 0, 0);
    __syncthreads();
  }
#pragma unroll
  for (int i = 0; i < 4; ++i) {
    int rbase = m0 + (w >> 1) * 64 + i * 16 + ((lane >> 4) << 2);
#pragma unroll
    for (int j = 0; j < 4; ++j) {
      int col = n0 + (w & 1) * 64 + j * 16 + (lane & 15);
      float bv = act ? bias[col] : 0.f;
#pragma unroll
      for (int r = 0; r < 4; ++r) {
        float v = acc[i][j][r];
        if (act) v = geluf_(v + bv);
        if (outbf) ((ushort_t*)C)[(size_t)(rbase + r) * Nq + col] = f2bf(v);
        else       C[(size_t)(rbase + r) * Nq + col] = v;
      }
    }
  }
}

// ------- fused conv4+silu (from fused x3 [m][3072]) + l2norm + beta --------
__global__ __launch_bounds__(256) void conv_prep(
    const float* __restrict__ x3, const float* __restrict__ wq,
    const float* __restrict__ wk, const float* __restrict__ wv,
    const float* __restrict__ beta_g,
    float* __restrict__ qn, float* __restrict__ kn,
    float* __restrict__ kb, float* __restrict__ vb,
    float* __restrict__ v_out)
{
  int i = blockIdx.x;              // bh*Ls + l
  int t = threadIdx.x;
  int l = i & 2047, bh = i >> 11;
  int b = bh >> 2, h = bh & 3;
  int c = h * 256 + t;
  const float* p = x3 + ((size_t)b * Ls) * 3072 + c;
  float4 wq4 = *(const float4*)(wq + c * 4);
  float4 wk4 = *(const float4*)(wk + c * 4);
  float4 wv4 = *(const float4*)(wv + c * 4);
  float qw[4] = {wq4.x, wq4.y, wq4.z, wq4.w};
  float kw[4] = {wk4.x, wk4.y, wk4.z, wk4.w};
  float vw[4] = {wv4.x, wv4.y, wv4.z, wv4.w};
  float aq = 0.f, ak = 0.f, av = 0.f;
#pragma unroll
  for (int j = 0; j < 4; ++j) {
    int ls = l - 3 + j;
    if (ls >= 0) {
      size_t rb = (size_t)ls * 3072;
      aq = fmaf(qw[j], p[rb], aq);
      ak = fmaf(kw[j], p[rb + 1024], ak);
      av = fmaf(vw[j], p[rb + 2048], av);
    }
  }
  float qv = siluf_(aq), kv = siluf_(ak), vv = siluf_(av);
  float sq = qv * qv, sk = kv * kv;
#pragma unroll
  for (int off = 32; off; off >>= 1) {
    sq += __shfl_down(sq, off);
    sk += __shfl_down(sk, off);
  }
  __shared__ float rq_[4], rk_[4];
  int w = t >> 6;
  if ((t & 63) == 0) { rq_[w] = sq; rk_[w] = sk; }
  __syncthreads();
  sq = rq_[0] + rq_[1] + rq_[2] + rq_[3];
  sk = rk_[0] + rk_[1] + rk_[2] + rk_[3];
  float rq = rsqrtf(sq + 1e-6f), rk = rsqrtf(sk + 1e-6f);
  float bt = beta_g[i];
  size_t base = (size_t)i * 256 + t;
  qn[base] = qv * rq;
  kn[base] = kv * rk;
  kb[base] = kv * rk * bt;
  vb[base] = vv * bt;
  v_out[base] = vv;
}

// ------- per (b,h,chunk) MFMA: Gram, substitution, w/u applies -------------
__global__ __launch_bounds__(256) void chunk_prep(
    const float* __restrict__ kb, const float* __restrict__ kn,
    const float* __restrict__ qn, const float* __restrict__ vb,
    float* __restrict__ attn_g, float* __restrict__ u_out,
    ushort_t* __restrict__ wn_bf, ushort_t* __restrict__ q_bf,
    ushort_t* __restrict__ knT_bf, ushort_t* __restrict__ kn_bf)
{
  __shared__ float Am[32][33];
  __shared__ float Tm[32][36];
  __shared__ ushort_t KT_hi[256][40];
  __shared__ ushort_t KT_lo[256][40];
  int t = threadIdx.x;
  int cc = blockIdx.x & 63, bh = blockIdx.x >> 6;
  size_t gbase = ((size_t)bh * Ls + cc * 32) * 256;
  int wv = t >> 6, lane = t & 63;
  int l16 = lane & 15, quad = lane >> 4;
  int mi = wv >> 1, ni = wv & 1;

  floatx4 Aacc = {0.f,0.f,0.f,0.f}, Qacc = {0.f,0.f,0.f,0.f};
  {
    int mrow = mi * 16 + l16, nrow = ni * 16 + l16;
    const float* kbp = kb + gbase + (size_t)mrow * 256;
    const float* qnp = qn + gbase + (size_t)mrow * 256;
    const float* knp = kn + gbase + (size_t)nrow * 256;
#pragma unroll
    for (int ks = 0; ks < 8; ++ks) {
      int koff = ks * 32 + quad * 8;
      short8 kbh, kbl, qnh, qnl, knh, knl;
      cvt8(*(const float4*)(kbp + koff), *(const float4*)(kbp + koff + 4), kbh, kbl);
      cvt8(*(const float4*)(qnp + koff), *(const float4*)(qnp + koff + 4), qnh, qnl);
      cvt8(*(const float4*)(knp + koff), *(const float4*)(knp + koff + 4), knh, knl);
      Aacc = __builtin_amdgcn_mfma_f32_16x16x32_bf16(kbh, knh, Aacc, 0, 0, 0);
      Aacc = __builtin_amdgcn_mfma_f32_16x16x32_bf16(kbh, knl, Aacc, 0, 0, 0);
      Aacc = __builtin_amdgcn_mfma_f32_16x16x32_bf16(kbl, knh, Aacc, 0, 0, 0);
      Qacc = __builtin_amdgcn_mfma_f32_16x16x32_bf16(qnh, knh, Qacc, 0, 0, 0);
      Qacc = __builtin_amdgcn_mfma_f32_16x16x32_bf16(qnh, knl, Qacc, 0, 0, 0);
      Qacc = __builtin_amdgcn_mfma_f32_16x16x32_bf16(qnl, knh, Qacc, 0, 0, 0);
      if (ni == 0)
        *(uint4*)(q_bf + gbase + (size_t)mrow * 256 + koff) = *(uint4*)&qnh;
      if (mi == 0)
        *(uint4*)(kn_bf + gbase + (size_t)nrow * 256 + koff) = *(uint4*)&knh;
    }
  }
  float* ag = attn_g + ((size_t)bh * 64 + cc) * 1024;
#pragma unroll
  for (int r = 0; r < 4; ++r) {
    int row = mi * 16 + quad * 4 + r, col = ni * 16 + l16;
    Am[row][col] = (col < row) ? Aacc[r] : 0.f;
    ag[row * 32 + col] = (col <= row) ? Qacc[r] : 0.f;
  }
  __syncthreads();

  if (wv == 0) {
    if (t < 32) {
#pragma unroll
      for (int i = 0; i < 32; ++i) Tm[i][t] = (i == t) ? 1.f : 0.f;
      for (int i2 = 1; i2 < 32; ++i2) {
        if (t < i2) {
          float s = 0.f;
          for (int m2 = t; m2 < i2; ++m2) s = fmaf(Am[i2][m2], Tm[m2][t], s);
          Tm[i2][t] = -s;
        }
      }
    }
  } else {
    int base = t - 64;
#pragma unroll
    for (int pass = 0; pass < 2; ++pass) {
      int d = base + pass * 192;
      if (d < 256) {
        u32 hp[16], lp[16], kp2[16];
#pragma unroll
        for (int m2 = 0; m2 < 16; ++m2) {
          float f0 = kb[gbase + (size_t)(2 * m2) * 256 + d];
          float f1 = kb[gbase + (size_t)(2 * m2 + 1) * 256 + d];
          ushort_t h0 = f2bf(f0), h1 = f2bf(f1);
          hp[m2] = (u32)h0 | ((u32)h1 << 16);
          lp[m2] = (u32)f2bf(f0 - bf2f(h0)) | ((u32)f2bf(f1 - bf2f(h1)) << 16);
          float g0 = kn[gbase + (size_t)(2 * m2) * 256 + d];
          float g1 = kn[gbase + (size_t)(2 * m2 + 1) * 256 + d];
          kp2[m2] = (u32)f2bf(g0) | ((u32)f2bf(g1) << 16);
        }
#pragma unroll
        for (int q2 = 0; q2 < 4; ++q2) {
          *(uint4*)&KT_hi[d][q2 * 8] = *(uint4*)&hp[q2 * 4];
          *(uint4*)&KT_lo[d][q2 * 8] = *(uint4*)&lp[q2 * 4];
          *(uint4*)(knT_bf + gbase + (size_t)d * 32 + q2 * 8) = *(uint4*)&kp2[q2 * 4];
        }
      }
    }
  }
  __syncthreads();

  int lt = wv & 1, dgrp = wv >> 1;
  short8 Th, Tl;
  {
    int lrow = lt * 16 + l16;
    cvt8(*(const float4*)&Tm[lrow][quad * 8],
         *(const float4*)&Tm[lrow][quad * 8 + 4], Th, Tl);
  }
#pragma unroll
  for (int j = 0; j < 8; ++j) {
    int dt = dgrp * 8 + j;
    short8 Bh = *(const short8*)&KT_hi[dt * 16 + l16][quad * 8];
    short8 Bl = *(const short8*)&KT_lo[dt * 16 + l16][quad * 8];
    floatx4 acc = {0.f,0.f,0.f,0.f};
    acc = __builtin_amdgcn_mfma_f32_16x16x32_bf16(Th, Bh, acc, 0, 0, 0);
    acc = __builtin_amdgcn_mfma_f32_16x16x32_bf16(Th, Bl, acc, 0, 0, 0);
    acc = __builtin_amdgcn_mfma_f32_16x16x32_bf16(Tl, Bh, acc, 0, 0, 0);
#pragma unroll
    for (int r = 0; r < 4; ++r) {
      int row = lt * 16 + quad * 4 + r;
      wn_bf[gbase + (size_t)row * 256 + dt * 16 + l16] = f2bf(-acc[r]);
    }
  }
  __syncthreads();

  {
    int d = t;
    u32 hp[16], lp[16];
#pragma unroll
    for (int m2 = 0; m2 < 16; ++m2) {
      float f0 = vb[gbase + (size_t)(2 * m2) * 256 + d];
      float f1 = vb[gbase + (size_t)(2 * m2 + 1) * 256 + d];
      ushort_t h0 = f2bf(f0), h1 = f2bf(f1);
      hp[m2] = (u32)h0 | ((u32)h1 << 16);
      lp[m2] = (u32)f2bf(f0 - bf2f(h0)) | ((u32)f2bf(f1 - bf2f(h1)) << 16);
    }
#pragma unroll
    for (int q2 = 0; q2 < 4; ++q2) {
      *(uint4*)&KT_hi[d][q2 * 8] = *(uint4*)&hp[q2 * 4];
      *(uint4*)&KT_lo[d][q2 * 8] = *(uint4*)&lp[q2 * 4];
    }
  }
  __syncthreads();

#pragma unroll
  for (int j = 0; j < 8; ++j) {
    int dt = dgrp * 8 + j;
    short8 Bh = *(const short8*)&KT_hi[dt * 16 + l16][quad * 8];
    short8 Bl = *(const short8*)&KT_lo[dt * 16 + l16][quad * 8];
    floatx4 acc = {0.f,0.f,0.f,0.f};
    acc = __builtin_amdgcn_mfma_f32_16x16x32_bf16(Th, Bh, acc, 0, 0, 0);
    acc = __builtin_amdgcn_mfma_f32_16x16x32_bf16(Th, Bl, acc, 0, 0, 0);
    acc = __builtin_amdgcn_mfma_f32_16x16x32_bf16(Tl, Bh, acc, 0, 0, 0);
#pragma unroll
    for (int r = 0; r < 4; ++r) {
      int row = lt * 16 + quad * 4 + r;
      u_out[gbase + (size_t)row * 256 + dt * 16 + l16] = acc[r];
    }
  }
}

// ------- cross matrices per super-chunk: X = wn1 @ kn0^T, Y = q1 @ kn0^T ---
__global__ __launch_bounds__(256) void cross_prep(
    const ushort_t* __restrict__ wn_bf, const ushort_t* __restrict__ q_bf,
    const ushort_t* __restrict__ kn_bf,
    float* __restrict__ X_g, float* __restrict__ Y_g)
{
  int t = threadIdx.x;
  int sc = blockIdx.x & 31, bh = blockIdx.x >> 5;
  int wv = t >> 6, lane = t & 63;
  int l16 = lane & 15, quad = lane >> 4;
  int mi = wv >> 1, ni = wv & 1;
  size_t base = (size_t)bh * Ls * 256;
  size_t r1 = base + (size_t)(sc * 64 + 32 + mi * 16 + l16) * 256;  // chunk 2sc+1 rows
  size_t r0 = base + (size_t)(sc * 64 + ni * 16 + l16) * 256;       // chunk 2sc rows
  floatx4 Xacc = {0.f,0.f,0.f,0.f}, Yacc = {0.f,0.f,0.f,0.f};
#pragma unroll
  for (int ks = 0; ks < 8; ++ks) {
    int ko = ks * 32 + quad * 8;
    short8 aw = *(const short8*)(wn_bf + r1 + ko);
    short8 aq = *(const short8*)(q_bf  + r1 + ko);
    short8 bk = *(const short8*)(kn_bf + r0 + ko);
    Xacc = __builtin_amdgcn_mfma_f32_16x16x32_bf16(aw, bk, Xacc, 0, 0, 0);
    Yacc = __builtin_amdgcn_mfma_f32_16x16x32_bf16(aq, bk, Yacc, 0, 0, 0);
  }
  float* xo = X_g + ((size_t)bh * 32 + sc) * 1024;
  float* yo = Y_g + ((size_t)bh * 32 + sc) * 1024;
#pragma unroll
  for (int r = 0; r < 4; ++r) {
    int row = mi * 16 + quad * 4 + r, col = ni * 16 + l16;
    xo[row * 32 + col] = Xacc[r];
    yo[row * 32 + col] = Yacc[r];
  }
}

// ------- merged: MFMA serial scan (blocks 0-127) + FIR conv (blocks 128+) --
__global__ __launch_bounds__(256, 1) void delta_fir(
    const ushort_t* __restrict__ wn_bf, const ushort_t* __restrict__ q_bf,
    const ushort_t* __restrict__ knT_bf, const float* __restrict__ attn_g,
    const float* __restrict__ u_g, const float* __restrict__ X_g,
    const float* __restrict__ Y_g, float* __restrict__ delta_g,
    const float* __restrict__ v, const float* __restrict__ wlg,
    const float* __restrict__ wsg, float* __restrict__ firl,
    float* __restrict__ firs)
{
  __shared__ __attribute__((aligned(16))) char smem[72704];
  int t = threadIdx.x;

  if (blockIdx.x >= 128) {
    // ---------------- FIR part ----------------
    float (*vt)[71] = (float(*)[71])smem;
    int bid = blockIdx.x - 128;
    int lt = bid & 255;
    int bh = bid >> 8;
    int b = bh >> 2, h = bh & 3;
    int l0 = lt * 8;
    const float* vp = v + (size_t)bh * Ls * 256;
    for (int r = 0; r < 70; ++r) {
      int ls = l0 - 62 + r;
      vt[t][r] = (ls >= 0) ? vp[(size_t)ls * 256 + t] : 0.f;
    }
    float TL[63], TS3[3];
#pragma unroll
    for (int j = 0; j < 63; ++j) TL[j] = wlg[((size_t)h * 256 + t) * 63 + j];
#pragma unroll
    for (int j = 0; j < 3; ++j) TS3[j] = wsg[((size_t)h * 256 + t) * 3 + j];
    __syncthreads();
    float aL[8] = {0,0,0,0,0,0,0,0}, aS[8] = {0,0,0,0,0,0,0,0};
#pragma unroll
    for (int r = 0; r < 70; ++r) {
      float vm = vt[t][r];
#pragma unroll
      for (int p = 0; p < 8; ++p) {
        int jl = r - p;
        if (jl >= 0 && jl < 63) aL[p] = fmaf(vm, TL[jl], aL[p]);
        int jssrc = r - 60 - p;
        if (jssrc >= 0 && jssrc < 3) aS[p] = fmaf(vm, TS3[jssrc], aS[p]);
      }
    }
#pragma unroll
    for (int p = 0; p < 8; ++p) {
      int l = l0 + p;
      size_t ob = (((size_t)b * Ls + l) * NH + h) * 256 + t;
      firl[ob] = aL[p];
      firs[ob] = aS[p];
    }
    return;
  }

  // ---------------- chain part (m=2 super-chunks) ----------------
  ushort_t (*Shi)[264] = (ushort_t(*)[264])(smem);
  ushort_t (*Slo)[264] = (ushort_t(*)[264])(smem + 8448);
  float (*u2L0)[17] = (float(*)[17])(smem + 16896);
  float (*u2L1)[17] = (float(*)[17])(smem + 19072);
  int bh = blockIdx.x & 7, g = blockIdx.x >> 3;
  int b = bh >> 2, h = bh & 3;
  int wv = t >> 6, lane = t & 63;
  int lquad = lane >> 4, l16 = lane & 15;
  int j0 = g * 16;
  int Mt = wv & 1;
  bool isU = (wv < 2);
  const ushort_t* wp = wn_bf + (size_t)bh * Ls * 256;
  const ushort_t* qp = q_bf  + (size_t)bh * Ls * 256;
  const ushort_t* ap = (isU ? wp : qp) + (size_t)(Mt * 16 + l16) * 256;
  const ushort_t* kr = knT_bf + (size_t)bh * Ls * 256 + (size_t)l16 * 32 + lquad * 8;
  const float* urow = u_g + (size_t)bh * Ls * 256
                    + (size_t)(Mt * 16 + lquad * 4) * 256 + j0 + l16;
  const float* arp = attn_g + (size_t)bh * 64 * 1024
                   + (size_t)(Mt * 16 + l16) * 32 + lquad * 8;
  const float* xrp = (isU ? X_g : Y_g) + (size_t)bh * 32768
                   + (size_t)(Mt * 16 + l16) * 32 + lquad * 8;

  floatx4 Sacc[4], SaccL[4];
#pragma unroll
  for (int i = 0; i < 4; ++i)
#pragma unroll
    for (int r = 0; r < 4; ++r) { Sacc[i][r] = 0.f; SaccL[i][r] = 0.f; }
  for (int i = t; i < 4224; i += 256) ((u32*)smem)[i] = 0;

  // prologue: super-chunk 0, sub-chunk 0 operands
  short8 a0[8], k0[4];
  floatx4 u0 = {0.f, 0.f, 0.f, 0.f};
  float4 at0a = {0,0,0,0}, at0b = {0,0,0,0};
#pragma unroll
  for (int ks = 0; ks < 8; ++ks)
    a0[ks] = *(const short8*)(ap + ks * 32 + lquad * 8);
#pragma unroll
  for (int i = 0; i < 4; ++i)
    k0[i] = *(const short8*)(kr + (size_t)(wv * 4 + i) * 512);
  if (isU) {
#pragma unroll
    for (int r = 0; r < 4; ++r) u0[r] = urow[(size_t)r * 256];
  } else {
    at0a = *(const float4*)(arp);
    at0b = *(const float4*)(arp + 4);
  }
  wave_barrier();

  for (int sc = 0; sc < 32; ++sc) {
    size_t cb1 = (size_t)sc * 16384 + 8192;
    size_t nb0 = (size_t)(sc + 1) * 16384;
    bool hasN = (sc + 1 < 32);

    // sub-chunk1 operands + cross matrix (used mid-iteration; latency covered)
    short8 a1[8], k1[4];
    floatx4 u1 = {0.f, 0.f, 0.f, 0.f};
    float4 at1a = {0,0,0,0}, at1b = {0,0,0,0};
#pragma unroll
    for (int ks = 0; ks < 8; ++ks)
      a1[ks] = *(const short8*)(ap + cb1 + ks * 32 + lquad * 8);
#pragma unroll
    for (int i = 0; i < 4; ++i)
      k1[i] = *(const short8*)(kr + cb1 + (size_t)(wv * 4 + i) * 512);
    if (isU) {
#pragma unroll
      for (int r = 0; r < 4; ++r) u1[r] = urow[cb1 + (size_t)r * 256];
    } else {
      size_t na = (size_t)(2 * sc + 1) * 1024;
      at1a = *(const float4*)(arp + na);
      at1b = *(const float4*)(arp + na + 4);
    }
    float4 xa = *(const float4*)(xrp + (size_t)sc * 1024);
    float4 xb = *(const float4*)(xrp + (size_t)sc * 1024 + 4);

    // ---- sub-chunk 0: u2_0 (isU) / po_0 (o) against S0 ----
    floatx4 acc0;
    if (isU) {
      floatx4 A0 = u0, A1 = {0,0,0,0}, A2 = {0,0,0,0}, A3 = {0,0,0,0};
#pragma unroll
      for (int ks = 0; ks < 8; ++ks) {
        short8 sh = *(const short8*)&Shi[l16][ks * 32 + lquad * 8];
        short8 sl = *(const short8*)&Slo[l16][ks * 32 + lquad * 8];
        if (ks & 1) {
          A1 = __builtin_amdgcn_mfma_f32_16x16x32_bf16(a0[ks], sh, A1, 0, 0, 0);
          A3 = __builtin_amdgcn_mfma_f32_16x16x32_bf16(a0[ks], sl, A3, 0, 0, 0);
        } else {
          A0 = __builtin_amdgcn_mfma_f32_16x16x32_bf16(a0[ks], sh, A0, 0, 0, 0);
          A2 = __builtin_amdgcn_mfma_f32_16x16x32_bf16(a0[ks], sl, A2, 0, 0, 0);
        }
      }
#pragma unroll
      for (int r = 0; r < 4; ++r) acc0[r] = (A0[r] + A1[r]) + (A2[r] + A3[r]);
#pragma unroll
      for (int r = 0; r < 4; ++r)
        u2L0[Mt * 16 + lquad * 4 + r][l16] = acc0[r];
    } else {
      floatx4 A0 = {0,0,0,0}, A1 = {0,0,0,0};
#pragma unroll
      for (int ks = 0; ks < 8; ++ks) {
        short8 sh = *(const short8*)&Shi[l16][ks * 32 + lquad * 8];
        if (ks & 1) A1 = __builtin_amdgcn_mfma_f32_16x16x32_bf16(a0[ks], sh, A1, 0, 0, 0);
        else        A0 = __builtin_amdgcn_mfma_f32_16x16x32_bf16(a0[ks], sh, A0, 0, 0, 0);
      }
#pragma unroll
      for (int r = 0; r < 4; ++r) acc0[r] = A0[r] + A1[r];
    }
    // prefetch next-super-chunk a0 (a0 regs dead; stays in flight across
    // the raw barriers below -> ~full iteration of latency cover)
    if (hasN) {
#pragma unroll
      for (int ks = 0; ks < 8; ++ks)
        a0[ks] = *(const short8*)(ap + nb0 + ks * 32 + lquad * 8);
    }
    wave_barrier();                          // u2_0 visible

    short8 uh0, ul0;
#pragma unroll
    for (int j = 0; j < 8; ++j) {
      float f = u2L0[lquad * 8 + j][l16];
      ushort_t hi = f2bf(f);
      uh0[j] = (short)hi;
      ul0[j] = (short)f2bf(f - bf2f(hi));
    }
#pragma unroll
    for (int i = 0; i < 4; ++i) {
      Sacc[i]  = __builtin_amdgcn_mfma_f32_16x16x32_bf16(k0[i], uh0, Sacc[i], 0, 0, 0);
      SaccL[i] = __builtin_amdgcn_mfma_f32_16x16x32_bf16(k0[i], ul0, SaccL[i], 0, 0, 0);
    }
    if (hasN) {
#pragma unroll
      for (int i = 0; i < 4; ++i)
        k0[i] = *(const short8*)(kr + nb0 + (size_t)(wv * 4 + i) * 512);
    }

    // ---- sub-chunk 1: u2_1 = u1 + wn1@S0 + X@u2_0 / o path ----
    floatx4 acc1;
    if (isU) {
      floatx4 A0 = u1, A1 = {0,0,0,0}, A2 = {0,0,0,0}, A3 = {0,0,0,0};
#pragma unroll
      for (int ks = 0; ks < 8; ++ks) {
        short8 sh = *(const short8*)&Shi[l16][ks * 32 + lquad * 8];
        short8 sl = *(const short8*)&Slo[l16][ks * 32 + lquad * 8];
        if (ks & 1) {
          A1 = __builtin_amdgcn_mfma_f32_16x16x32_bf16(a1[ks], sh, A1, 0, 0, 0);
          A3 = __builtin_amdgcn_mfma_f32_16x16x32_bf16(a1[ks], sl, A3, 0, 0, 0);
        } else {
          A0 = __builtin_amdgcn_mfma_f32_16x16x32_bf16(a1[ks], sh, A0, 0, 0, 0);
          A2 = __builtin_amdgcn_mfma_f32_16x16x32_bf16(a1[ks], sl, A2, 0, 0, 0);
        }
      }
      short8 Xh, Xl;
      cvt8(xa, xb, Xh, Xl);
      A0 = __builtin_amdgcn_mfma_f32_16x16x32_bf16(Xh, uh0, A0, 0, 0, 0);
      A1 = __builtin_amdgcn_mfma_f32_16x16x32_bf16(Xh, ul0, A1, 0, 0, 0);
      A2 = __builtin_amdgcn_mfma_f32_16x16x32_bf16(Xl, uh0, A2, 0, 0, 0);
#pragma unroll
      for (int r = 0; r < 4; ++r) acc1[r] = (A0[r] + A1[r]) + (A2[r] + A3[r]);
#pragma unroll
      for (int r = 0; r < 4; ++r)
        u2L1[Mt * 16 + lquad * 4 + r][l16] = acc1[r];
      if (hasN) {
#pragma unroll
        for (int r = 0; r < 4; ++r) u0[r] = urow[nb0 + (size_t)r * 256];
      }
    } else {
      // o_0 = po_0 + attn_0 @ u2_0 -> store
      short8 ath, atl;
      cvt8(at0a, at0b, ath, atl);
      acc0 = __builtin_amdgcn_mfma_f32_16x16x32_bf16(ath, uh0, acc0, 0, 0, 0);
      acc0 = __builtin_amdgcn_mfma_f32_16x16x32_bf16(ath, ul0, acc0, 0, 0, 0);
      acc0 = __builtin_amdgcn_mfma_f32_16x16x32_bf16(atl, uh0, acc0, 0, 0, 0);
#pragma unroll
      for (int r = 0; r < 4; ++r) {
        int l = sc * 64 + Mt * 16 + lquad * 4 + r;
        delta_g[(((size_t)b * Ls + l) * NH + h) * 256 + j0 + l16] = acc0[r];
      }
      // po_1 = q1 @ Shi(S0) + Y @ u2_0
      floatx4 A0 = {0,0,0,0}, A1 = {0,0,0,0};
#pragma unroll
      for (int ks = 0; ks < 8; ++ks) {
        short8 sh = *(const short8*)&Shi[l16][ks * 32 + lquad * 8];
        if (ks & 1) A1 = __builtin_amdgcn_mfma_f32_16x16x32_bf16(a1[ks], sh, A1, 0, 0, 0);
        else        A0 = __builtin_amdgcn_mfma_f32_16x16x32_bf16(a1[ks], sh, A0, 0, 0, 0);
      }
      short8 Yh, Yl;
      cvt8(xa, xb, Yh, Yl);
      A0 = __builtin_amdgcn_mfma_f32_16x16x32_bf16(Yh, uh0, A0, 0, 0, 0);
      A1 = __builtin_amdgcn_mfma_f32_16x16x32_bf16(Yh, ul0, A1, 0, 0, 0);
      A0 = __builtin_amdgcn_mfma_f32_16x16x32_bf16(Yl, uh0, A0, 0, 0, 0);
#pragma unroll
      for (int r = 0; r < 4; ++r) acc1[r] = A0[r] + A1[r];
      if (hasN) {
        size_t na0 = (size_t)(2 * sc + 2) * 1024;
        at0a = *(const float4*)(arp + na0);
        at0b = *(const float4*)(arp + na0 + 4);
      }
    }
    wave_barrier();                          // u2_1 visible; all Shi/Slo reads done

    short8 uh1, ul1;
#pragma unroll
    for (int j = 0; j < 8; ++j) {
      float f = u2L1[lquad * 8 + j][l16];
      ushort_t hi = f2bf(f);
      uh1[j] = (short)hi;
      ul1[j] = (short)f2bf(f - bf2f(hi));
    }
#pragma unroll
    for (int i = 0; i < 4; ++i) {
      Sacc[i]  = __builtin_amdgcn_mfma_f32_16x16x32_bf16(k1[i], uh1, Sacc[i], 0, 0, 0);
      SaccL[i] = __builtin_amdgcn_mfma_f32_16x16x32_bf16(k1[i], ul1, SaccL[i], 0, 0, 0);
    }
    if (!isU) {
      short8 ath, atl;
      cvt8(at1a, at1b, ath, atl);
      acc1 = __builtin_amdgcn_mfma_f32_16x16x32_bf16(ath, uh1, acc1, 0, 0, 0);
      acc1 = __builtin_amdgcn_mfma_f32_16x16x32_bf16(ath, ul1, acc1, 0, 0, 0);
      acc1 = __builtin_amdgcn_mfma_f32_16x16x32_bf16(atl, uh1, acc1, 0, 0, 0);
#pragma unroll
      for (int r = 0; r < 4; ++r) {
        int l = sc * 64 + 32 + Mt * 16 + lquad * 4 + r;
        delta_g[(((size_t)b * Ls + l) * NH + h) * 256 + j0 + l16] = acc1[r];
      }
    }
    // S write-back (once per 64 tokens)
#pragma unroll
    for (int i = 0; i < 4; ++i) {
      int dk0 = (wv * 4 + i) * 16 + lquad * 4;
      ushort4 h4, l4;
      ushort_t* hp = (ushort_t*)&h4;
      ushort_t* lp = (ushort_t*)&l4;
#pragma unroll
      for (int r = 0; r < 4; ++r) {
        float sv = Sacc[i][r] + SaccL[i][r];
        ushort_t hi = f2bf(sv);
        hp[r] = hi;
        lp[r] = f2bf(sv - bf2f(hi));
      }
      *(ushort4*)&Shi[l16][dk0] = h4;
      *(ushort4*)&Slo[l16][dk0] = l4;
    }
    wave_barrier();                          // S visible
  }
}

// ------- gate_in (bf16) ----------------------------------------------------
__global__ __launch_bounds__(256) void build_gate_in_bf(
    const float* __restrict__ x, const float* __restrict__ firs,
    const float* __restrict__ firl, const float* __restrict__ delta,
    const float* __restrict__ v, ushort_t* __restrict__ gin)
{
  int mtok = blockIdx.x, t = threadIdx.x;
  int b = mtok >> 11, l = mtok & 2047;
  float4 xv = *(const float4*)(x + (size_t)mtok * 1024 + t * 4);
  ushort4 xo = make_ushort4(f2bf(xv.x), f2bf(xv.y), f2bf(xv.z), f2bf(xv.w));
  *(ushort4*)(gin + (size_t)mtok * 1056 + t * 4) = xo;
  int w = t >> 6, lane = t & 63;
  for (int br = 0; br < 4; ++br) {
    float s = 0.f, s2 = 0.f;
#pragma unroll
    for (int r = 0; r < 4; ++r) {
      int d = lane + r * 64;
      float val;
      if (br == 0)      val = firs [(size_t)mtok * 1024 + w * 256 + d];
      else if (br == 1) val = firl [(size_t)mtok * 1024 + w * 256 + d];
      else if (br == 2) val = delta[(size_t)mtok * 1024 + w * 256 + d];
      else              val = v[(((size_t)(b * NH + w)) * Ls + l) * 256 + d];
      s += val; s2 = fmaf(val, val, s2);
    }
#pragma unroll
    for (int off = 32; off; off >>= 1) {
      s += __shfl_down(s, off);
      s2 += __shfl_down(s2, off);
    }
    if (lane == 0) {
      float mean = s * (1.f / 256.f);
      float var = s2 * (1.f / 256.f) - mean * mean;
      gin[(size_t)mtok * 1056 + 1024 + br * 8 + w] = f2bf(mean);
      gin[(size_t)mtok * 1056 + 1024 + br * 8 + 4 + w] = f2bf(sqrtf(fmaxf(var, 1e-6f)));
    }
  }
}

// ------- logits -> gates (bf16 hidden input) -------------------------------
__global__ __launch_bounds__(256) void mlp2_gates(
    const ushort_t* __restrict__ mh, const float* __restrict__ W2,
    const float* __restrict__ b2, const float* __restrict__ glt,
    float* __restrict__ gates)
{
  int mtok = blockIdx.x, t = threadIdx.x;
  float p[16];
#pragma unroll
  for (int j = 0; j < 16; ++j) p[j] = 0.f;
  for (int k = t; k < 2048; k += 256) {
    float hv = bf2f(mh[(size_t)mtok * 2048 + k]);
    const float* wr = W2 + (size_t)k * 16;
#pragma unroll
    for (int j4 = 0; j4 < 4; ++j4) {
      float4 w4 = *(const float4*)(wr + j4 * 4);
      p[j4*4+0] = fmaf(hv, w4.x, p[j4*4+0]);
      p[j4*4+1] = fmaf(hv, w4.y, p[j4*4+1]);
      p[j4*4+2] = fmaf(hv, w4.z, p[j4*4+2]);
      p[j4*4+3] = fmaf(hv, w4.w, p[j4*4+3]);
    }
  }
#pragma unroll
  for (int j = 0; j < 16; ++j)
#pragma unroll
    for (int off = 32; off; off >>= 1) p[j] += __shfl_down(p[j], off);
  __shared__ float red[4][16];
  __shared__ float zl[16];
  int w = t >> 6;
  if ((t & 63) == 0) {
#pragma unroll
    for (int j = 0; j < 16; ++j) red[w][j] = p[j];
  }
  __syncthreads();
  if (t < 16) {
    float tot = red[0][t] + red[1][t] + red[2][t] + red[3][t] + b2[t];
    float tempv = log1pf(expf(glt[t >> 2])) + 1e-4f;
    zl[t] = tot / tempv;
  }
  __syncthreads();
  if (t < 4) {
    float z0 = zl[t*4], z1 = zl[t*4+1], z2 = zl[t*4+2], z3 = zl[t*4+3];
    float mx = fmaxf(fmaxf(z0, z1), fmaxf(z2, z3));
    float e0 = expf(z0 - mx), e1 = expf(z1 - mx), e2 = expf(z2 - mx), e3 = expf(z3 - mx);
    float inv = 1.f / (e0 + e1 + e2 + e3);
    gates[(size_t)mtok * 16 + t * 4 + 0] = e0 * inv;
    gates[(size_t)mtok * 16 + t * 4 + 1] = e1 * inv;
    gates[(size_t)mtok * 16 + t * 4 + 2] = e2 * inv;
    gates[(size_t)mtok * 16 + t * 4 + 3] = e3 * inv;
  }
}

// ------- o = gated mix, RMSNorm -> bf16 ------------------------------------
__global__ __launch_bounds__(256) void combine_norm_bf(
    const float* __restrict__ firs, const float* __restrict__ firl,
    const float* __restrict__ delta, const float* __restrict__ v,
    const float* __restrict__ gates, const float* __restrict__ onw,
    ushort_t* __restrict__ o)
{
  int mh = blockIdx.x;
  int mtok = mh >> 2, h = mh & 3;
  int t = threadIdx.x;
  int b = mtok >> 11, l = mtok & 2047;
  const float* g = gates + (size_t)mtok * 16 + h * 4;
  float w0 = g[0], w1 = g[1], w2 = g[2], w3 = g[3];
  size_t tb = (size_t)mtok * 1024 + h * 256 + t;
  float val = w0 * firs[tb] + w1 * firl[tb] + w2 * delta[tb]
            + w3 * v[(((size_t)(b * NH + h)) * Ls + l) * 256 + t];
  float s2 = val * val;
#pragma unroll
  for (int off = 32; off; off >>= 1) s2 += __shfl_down(s2, off);
  __shared__ float r4[4];
  if ((t & 63) == 0) r4[t >> 6] = s2;
  __syncthreads();
  float tot = r4[0] + r4[1] + r4[2] + r4[3];
  float rms = rsqrtf(tot * (1.f / 256.f) + 1e-5f);
  o[tb] = f2bf(val * rms * onw[t]);
}

// ---------------------------------------------------------------------------
extern "C" void kernel_launch(void* const* d_in, const int* in_sizes, int n_in,
                              void* d_out, int out_size, void* d_ws, size_t ws_size,
                              hipStream_t stream) {
  const float* x     = (const float*)d_in[0];
  const float* Wq    = (const float*)d_in[1];
  const float* Wk    = (const float*)d_in[2];
  const float* Wv    = (const float*)d_in[3];
  const float* Wb    = (const float*)d_in[4];
  const float* convq = (const float*)d_in[5];
  const float* convk = (const float*)d_in[6];
  const float* convv = (const float*)d_in[7];
  const float* firsw = (const float*)d_in[8];
  const float* firlw = (const float*)d_in[9];
  const float* mlpw1 = (const float*)d_in[10];
  const float* mlpb1 = (const float*)d_in[11];
  const float* mlpw2 = (const float*)d_in[12];
  const float* mlpb2 = (const float*)d_in[13];
  const float* glt   = (const float*)d_in[14];
  const float* onw   = (const float*)d_in[15];
  const float* Wo    = (const float*)d_in[16];
  float* ws = (float*)d_ws;

  ushort_t* x_bf   = (ushort_t*)(ws + off_firs);
  ushort_t* Wqkv_t = (ushort_t*)(ws + off_firl);  // 3 x [1024][1024] contiguous
  ushort_t* gin_bf = (ushort_t*)(ws + off_gin);
  ushort_t* w1_t   = (ushort_t*)(ws + off_w1t);   // never-aliased window
  ushort_t* o_bf   = (ushort_t*)(ws + off_xv);
  ushort_t* Wo_t   = (ushort_t*)(ws + off_wot);   // never-aliased window
  ushort_t* mlph_bf= (ushort_t*)(ws + off_mlph);
  ushort_t* wn_bf  = (ushort_t*)(ws + off_firs);
  ushort_t* q_bf   = (ushort_t*)(ws + off_firs + 2097152);
  ushort_t* knT_bf = (ushort_t*)(ws + off_firl);
  ushort_t* kn_bf  = (ushort_t*)(ws + off_xq);    // x3 dead after conv_prep
  float* x3   = ws + off_xq;     // fused [4096][3072] spans xq/xk/xv
  float* kb_f = ws + off_gin;
  float* vb_f = ws + off_mlph;
  float* X_g  = ws + off_gin;            // kb dead after chunk_prep; 8*32*1024 f32
  float* Y_g  = ws + off_gin + 262144;
  float* firs_f = ws + off_xq;   // x3/kn_bf dead after cross_prep
  float* firl_f = ws + off_xk;

  dim3 blk(256);
  // merged input-only prep: x->bf16, W transposes (qkv, mlp1, Wo), beta
  prep1<<<12352, blk, 0, stream>>>(x, x_bf, Wq, Wk, Wv, Wqkv_t,
                                   mlpw1, w1_t, Wo, Wo_t, Wb, ws + off_beta);
  // fused q/k/v projection (one N=3072 GEMM)
  gemm_bf16<<<dim3(24, 32), blk, 0, stream>>>(x_bf, Wqkv_t, x3, 3072, 1024, nullptr, 0, 0);
  // fused conv4+silu + l2norm + beta products
  conv_prep<<<16384, blk, 0, stream>>>(x3, convq, convk, convv, ws + off_beta,
                                       ws + off_q, ws + off_k, kb_f, vb_f, ws + off_v);
  // per-chunk T inverse, attn, u (->xv), bf16 {-w, q, knT, kn}
  chunk_prep<<<512, blk, 0, stream>>>(kb_f, ws + off_k, ws + off_q, vb_f,
                                      ws + off_attn, ws + off_xv, wn_bf, q_bf,
                                      knT_bf, kn_bf);
  // 32x32 cross matrices per super-chunk (X = wn1 kn0^T, Y = q1 kn0^T)
  cross_prep<<<256, blk, 0, stream>>>(wn_bf, q_bf, kn_bf, X_g, Y_g);
  // merged serial MFMA scan (delta -> off_q) + FIR (firs/firl -> x3 regions)
  delta_fir<<<2176, blk, 0, stream>>>(wn_bf, q_bf, knT_bf, ws + off_attn,
                                      ws + off_xv, X_g, Y_g, ws + off_q,
                                      ws + off_v, firlw, firsw, firl_f, firs_f);
  // gate input (bf16), MLP1 (MFMA, gelu, bf16 out), gates
  build_gate_in_bf<<<4096, blk, 0, stream>>>(x, firs_f, firl_f, ws + off_q,
                                             ws + off_v, gin_bf);
  gemm_bf16<<<dim3(16, 32), blk, 0, stream>>>(gin_bf, w1_t, (float*)mlph_bf,
                                              2048, 1056, mlpb1, 1, 1);
  mlp2_gates<<<4096, blk, 0, stream>>>(mlph_bf, mlpw2, mlpb2, glt, ws + off_gates);
  // combine + RMSNorm -> bf16, output projection (MFMA)
  combine_norm_bf<<<16384, blk, 0, stream>>>(firs_f, firl_f, ws + off_q,
                                             ws + off_v, ws + off_gates, onw, o_bf);
  gemm_bf16<<<dim3(8, 32), blk, 0, stream>>>(o_bf, Wo_t, (float*)d_out, 1024, 1024, nullptr, 0, 0);
}

// Round 6
// 557.569 us; speedup vs baseline: 1.3146x; 1.0997x over previous
//
#include <hip/hip_runtime.h>
#include <hip/hip_bf16.h>

// ---------------------------------------------------------------------------
// DeltaNet forward, round 13:
//  - REVERT to r8 launch structure exactly (proven 546us best; r10/r11/r12
//    structural variants all regressed or were noise-ambiguous).
//  - ONE change: conv_prep vectorized. 4096 blocks (one per (b,l)), 4
//    channels/thread via float4 loads (was 1 ch/thread, 12 scalar loads),
//    l2norm reduction is now wave-local shfl_xor (64 lanes == 1 head) --
//    no LDS, no __syncthreads. All outputs float4 stores.
// ---------------------------------------------------------------------------

#define DEVI __device__ __forceinline__
typedef unsigned int u32;
typedef unsigned short ushort_t;
typedef __attribute__((ext_vector_type(8))) short short8;
typedef __attribute__((ext_vector_type(4))) float floatx4;

constexpr int Ls = 2048, NH = 4;

// workspace offsets (floats)
constexpr size_t off_xq   = 0;         // x3 [m][3072] cols 0-1023 -> kn_bf -> firs
constexpr size_t off_xk   = 4194304;   // x3 cols 1024-2047 -> firl
constexpr size_t off_xv   = 8388608;   // x3 cols 2048-3071 -> u -> o_bf
constexpr size_t off_q    = 12582912;  // qn -> delta
constexpr size_t off_k    = 16777216;  // kn -> w1_t (bf16)
constexpr size_t off_v    = 20971520;  // v (alive to the end)
constexpr size_t off_beta = 25165824;  // beta -> Wo_t (bf16, spans into attn)
constexpr size_t off_attn = 25182208;  // attn (dead after chain)
constexpr size_t off_firs = 25706496;  // x_bf -> {wn_bf, q_bf} (bf16)
constexpr size_t off_firl = 29900800;  // Wqkv_t -> knT_bf (bf16)
constexpr size_t off_gin  = 34095104;  // kb (f32) -> {X_g, Y_g} -> gin_bf
constexpr size_t off_mlph = 38420480;  // vb (f32) -> mlph_bf
constexpr size_t off_gates= 46809088;  // gates

DEVI float sigmoidf_(float x) { return 1.f / (1.f + expf(-x)); }
DEVI float siluf_(float x) { return x / (1.f + expf(-x)); }
DEVI float geluf_(float x) { return 0.5f * x * (1.f + erff(x * 0.7071067811865476f)); }
DEVI ushort_t f2bf(float f) {
  union { float f; u32 u; } c{f};
  u32 r = (c.u + 0x7fffu + ((c.u >> 16) & 1u)) >> 16;
  return (ushort_t)r;
}
DEVI float bf2f(ushort_t h) {
  union { u32 u; float f; } c; c.u = ((u32)h) << 16; return c.f;
}
DEVI void cvt8(float4 a, float4 b, short8& hi, short8& lo) {
  float f[8] = {a.x,a.y,a.z,a.w,b.x,b.y,b.z,b.w};
#pragma unroll
  for (int j = 0; j < 8; ++j) {
    ushort_t h = f2bf(f[j]);
    hi[j] = (short)h;
    lo[j] = (short)f2bf(f[j] - bf2f(h));
  }
}
DEVI void async16(const void* g, void* l) {
  __builtin_amdgcn_global_load_lds(
      (const u32 __attribute__((address_space(1)))*)g,
      (u32 __attribute__((address_space(3)))*)l, 16, 0, 0);
}
// Raw workgroup barrier: waits LDS ops only (lgkmcnt), leaves global
// loads/stores (vmcnt) in flight. All cross-wave deps in the chain loop are
// LDS-only, and global data has no in-kernel consumers.
DEVI void wave_barrier() {
  __builtin_amdgcn_sched_barrier(0);
  asm volatile("s_waitcnt lgkmcnt(0)" ::: "memory");
  __builtin_amdgcn_s_barrier();
  __builtin_amdgcn_sched_barrier(0);
}

// ---------------- f32 -> bf16 ----------------------------------------------
__global__ __launch_bounds__(256) void to_bf16(
    const float* __restrict__ in, ushort_t* __restrict__ out, int n)
{
  int i = (blockIdx.x * 256 + threadIdx.x) * 8;
  if (i >= n) return;
  float4 a = *(const float4*)(in + i);
  float4 b = *(const float4*)(in + i + 4);
  ushort_t o[8] = { f2bf(a.x), f2bf(a.y), f2bf(a.z), f2bf(a.w),
                    f2bf(b.x), f2bf(b.y), f2bf(b.z), f2bf(b.w) };
  *(uint4*)(out + i) = *(uint4*)o;
}

// ---------------- f32 [K][N] -> bf16 [N][K] --------------------------------
__global__ __launch_bounds__(256) void convT(
    const float* __restrict__ W, ushort_t* __restrict__ out, int Kq, int Nq)
{
  __shared__ ushort_t tile[32][33];
  int n0 = blockIdx.x * 32, k0 = blockIdx.y * 32;
  int tx = threadIdx.x & 31, ty = threadIdx.x >> 5;
#pragma unroll
  for (int r = 0; r < 32; r += 8)
    tile[ty + r][tx] = f2bf(W[(size_t)(k0 + ty + r) * Nq + n0 + tx]);
  __syncthreads();
#pragma unroll
  for (int r = 0; r < 32; r += 8)
    out[(size_t)(n0 + ty + r) * Kq + k0 + tx] = tile[tx][ty + r];
}

// ---------------- bf16 MFMA GEMM -------------------------------------------
__global__ __launch_bounds__(256) void gemm_bf16(
    const ushort_t* __restrict__ A, const ushort_t* __restrict__ Bt,
    float* __restrict__ C, int Nq, int Kq,
    const float* __restrict__ bias, int act, int outbf)
{
  __shared__ ushort_t As[128 * 32];
  __shared__ ushort_t Bs[128 * 32];
  int t = threadIdx.x;
  int w = t >> 6, lane = t & 63;
  int m0 = blockIdx.y * 128, n0 = blockIdx.x * 128;
  floatx4 acc[4][4];
#pragma unroll
  for (int i = 0; i < 4; ++i)
#pragma unroll
    for (int j = 0; j < 4; ++j)
#pragma unroll
      for (int r = 0; r < 4; ++r) acc[i][j][r] = 0.f;

  int lrow = lane >> 2, lk8 = (lane & 3) * 8;
  for (int kt = 0; kt < Kq; kt += 32) {
#pragma unroll
    for (int r = 0; r < 2; ++r) {
      int seg = w * 2 + r;
      int row = seg * 16 + lrow;
      async16(A  + (size_t)(m0 + row) * Kq + kt + lk8, &As[seg * 512]);
      async16(Bt + (size_t)(n0 + row) * Kq + kt + lk8, &Bs[seg * 512]);
    }
    __syncthreads();
    short8 af[4], bf[4];
#pragma unroll
    for (int i = 0; i < 4; ++i) {
      int row = (w >> 1) * 64 + i * 16 + (lane & 15);
      af[i] = *(const short8*)&As[row * 32 + (lane >> 4) * 8];
    }
#pragma unroll
    for (int j = 0; j < 4; ++j) {
      int col = (w & 1) * 64 + j * 16 + (lane & 15);
      bf[j] = *(const short8*)&Bs[col * 32 + (lane >> 4) * 8];
    }
#pragma unroll
    for (int i = 0; i < 4; ++i)
#pragma unroll
      for (int j = 0; j < 4; ++j)
        acc[i][j] = __builtin_amdgcn_mfma_f32_16x16x32_bf16(af[i], bf[j], acc[i][j], 0, 0, 0);
    __syncthreads();
  }
#pragma unroll
  for (int i = 0; i < 4; ++i) {
    int rbase = m0 + (w >> 1) * 64 + i * 16 + ((lane >> 4) << 2);
#pragma unroll
    for (int j = 0; j < 4; ++j) {
      int col = n0 + (w & 1) * 64 + j * 16 + (lane & 15);
      float bv = act ? bias[col] : 0.f;
#pragma unroll
      for (int r = 0; r < 4; ++r) {
        float v = acc[i][j][r];
        if (act) v = geluf_(v + bv);
        if (outbf) ((ushort_t*)C)[(size_t)(rbase + r) * Nq + col] = f2bf(v);
        else       C[(size_t)(rbase + r) * Nq + col] = v;
      }
    }
  }
}

// ---------------- beta = sigmoid(x @ Wb) -----------------------------------
__global__ __launch_bounds__(256) void beta_sigmoid(
    const float* __restrict__ x, const float* __restrict__ Wb,
    float* __restrict__ beta)
{
  int mtok = blockIdx.x, t = threadIdx.x;
  int b = mtok >> 11, l = mtok & 2047;
  float a0 = 0, a1 = 0, a2 = 0, a3 = 0;
  for (int k = t; k < 1024; k += 256) {
    float xv = x[(size_t)mtok * 1024 + k];
    float4 w4 = *(const float4*)(Wb + k * 4);
    a0 = fmaf(xv, w4.x, a0); a1 = fmaf(xv, w4.y, a1);
    a2 = fmaf(xv, w4.z, a2); a3 = fmaf(xv, w4.w, a3);
  }
#pragma unroll
  for (int off = 32; off; off >>= 1) {
    a0 += __shfl_down(a0, off); a1 += __shfl_down(a1, off);
    a2 += __shfl_down(a2, off); a3 += __shfl_down(a3, off);
  }
  __shared__ float red[4][4];
  int w = t >> 6;
  if ((t & 63) == 0) { red[w][0] = a0; red[w][1] = a1; red[w][2] = a2; red[w][3] = a3; }
  __syncthreads();
  if (t < 4) {
    float s = red[0][t] + red[1][t] + red[2][t] + red[3][t];
    beta[((size_t)(b * NH + t)) * Ls + l] = sigmoidf_(s);
  }
}

// ------- fused conv4+silu + l2norm + beta, vectorized (4 ch/thread) --------
// one block per (b,l); 64 lanes x 4 ch = one head per wave -> wave-local
// l2norm reduction (shfl_xor butterfly), no LDS, no barrier.
__global__ __launch_bounds__(256) void conv_prep(
    const float* __restrict__ x3, const float* __restrict__ wq,
    const float* __restrict__ wk, const float* __restrict__ wv,
    const float* __restrict__ beta_g,
    float* __restrict__ qn, float* __restrict__ kn,
    float* __restrict__ kb, float* __restrict__ vb,
    float* __restrict__ v_out)
{
  int i = blockIdx.x;              // b*Ls + l   (4096 blocks)
  int t = threadIdx.x;
  int l = i & 2047, b = i >> 11;
  int h = t >> 6;                  // wave == head
  int c4 = t * 4;                  // global channel base (0..1020)
  const float* p = x3 + (size_t)(b * Ls) * 3072;

  float qw_[4][4], kw_[4][4], vw_[4][4];
#pragma unroll
  for (int ch = 0; ch < 4; ++ch) {
    float4 a = *(const float4*)(wq + (size_t)(c4 + ch) * 4);
    float4 c = *(const float4*)(wk + (size_t)(c4 + ch) * 4);
    float4 d = *(const float4*)(wv + (size_t)(c4 + ch) * 4);
    qw_[ch][0]=a.x; qw_[ch][1]=a.y; qw_[ch][2]=a.z; qw_[ch][3]=a.w;
    kw_[ch][0]=c.x; kw_[ch][1]=c.y; kw_[ch][2]=c.z; kw_[ch][3]=c.w;
    vw_[ch][0]=d.x; vw_[ch][1]=d.y; vw_[ch][2]=d.z; vw_[ch][3]=d.w;
  }
  float aq[4] = {0,0,0,0}, ak[4] = {0,0,0,0}, av[4] = {0,0,0,0};
#pragma unroll
  for (int j = 0; j < 4; ++j) {
    int ls = l - 3 + j;
    if (ls >= 0) {
      size_t rb = (size_t)ls * 3072;
      float4 xq = *(const float4*)(p + rb + c4);
      float4 xk = *(const float4*)(p + rb + 1024 + c4);
      float4 xv = *(const float4*)(p + rb + 2048 + c4);
      float xq_[4] = {xq.x, xq.y, xq.z, xq.w};
      float xk_[4] = {xk.x, xk.y, xk.z, xk.w};
      float xv_[4] = {xv.x, xv.y, xv.z, xv.w};
#pragma unroll
      for (int ch = 0; ch < 4; ++ch) {
        aq[ch] = fmaf(qw_[ch][j], xq_[ch], aq[ch]);
        ak[ch] = fmaf(kw_[ch][j], xk_[ch], ak[ch]);
        av[ch] = fmaf(vw_[ch][j], xv_[ch], av[ch]);
      }
    }
  }
  float qv[4], kv[4], vv[4];
  float sq = 0.f, sk = 0.f;
#pragma unroll
  for (int ch = 0; ch < 4; ++ch) {
    qv[ch] = siluf_(aq[ch]);
    kv[ch] = siluf_(ak[ch]);
    vv[ch] = siluf_(av[ch]);
    sq = fmaf(qv[ch], qv[ch], sq);
    sk = fmaf(kv[ch], kv[ch], sk);
  }
#pragma unroll
  for (int off = 32; off; off >>= 1) {
    sq += __shfl_xor(sq, off);
    sk += __shfl_xor(sk, off);
  }
  float rq = rsqrtf(sq + 1e-6f), rk = rsqrtf(sk + 1e-6f);
  float bt = beta_g[(size_t)(b * NH + h) * Ls + l];
  size_t base = ((size_t)(b * NH + h) * Ls + l) * 256 + (c4 & 255);
  float4 oq, ok, okb, ovb, ov;
  oq.x = qv[0]*rq; oq.y = qv[1]*rq; oq.z = qv[2]*rq; oq.w = qv[3]*rq;
  ok.x = kv[0]*rk; ok.y = kv[1]*rk; ok.z = kv[2]*rk; ok.w = kv[3]*rk;
  okb.x = ok.x*bt; okb.y = ok.y*bt; okb.z = ok.z*bt; okb.w = ok.w*bt;
  ovb.x = vv[0]*bt; ovb.y = vv[1]*bt; ovb.z = vv[2]*bt; ovb.w = vv[3]*bt;
  ov.x = vv[0]; ov.y = vv[1]; ov.z = vv[2]; ov.w = vv[3];
  *(float4*)(qn + base) = oq;
  *(float4*)(kn + base) = ok;
  *(float4*)(kb + base) = okb;
  *(float4*)(vb + base) = ovb;
  *(float4*)(v_out + base) = ov;
}

// ------- per (b,h,chunk) MFMA: Gram, substitution, w/u applies -------------
__global__ __launch_bounds__(256) void chunk_prep(
    const float* __restrict__ kb, const float* __restrict__ kn,
    const float* __restrict__ qn, const float* __restrict__ vb,
    float* __restrict__ attn_g, float* __restrict__ u_out,
    ushort_t* __restrict__ wn_bf, ushort_t* __restrict__ q_bf,
    ushort_t* __restrict__ knT_bf, ushort_t* __restrict__ kn_bf)
{
  __shared__ float Am[32][33];
  __shared__ float Tm[32][36];
  __shared__ ushort_t KT_hi[256][40];
  __shared__ ushort_t KT_lo[256][40];
  int t = threadIdx.x;
  int cc = blockIdx.x & 63, bh = blockIdx.x >> 6;
  size_t gbase = ((size_t)bh * Ls + cc * 32) * 256;
  int wv = t >> 6, lane = t & 63;
  int l16 = lane & 15, quad = lane >> 4;
  int mi = wv >> 1, ni = wv & 1;

  floatx4 Aacc = {0.f,0.f,0.f,0.f}, Qacc = {0.f,0.f,0.f,0.f};
  {
    int mrow = mi * 16 + l16, nrow = ni * 16 + l16;
    const float* kbp = kb + gbase + (size_t)mrow * 256;
    const float* qnp = qn + gbase + (size_t)mrow * 256;
    const float* knp = kn + gbase + (size_t)nrow * 256;
#pragma unroll
    for (int ks = 0; ks < 8; ++ks) {
      int koff = ks * 32 + quad * 8;
      short8 kbh, kbl, qnh, qnl, knh, knl;
      cvt8(*(const float4*)(kbp + koff), *(const float4*)(kbp + koff + 4), kbh, kbl);
      cvt8(*(const float4*)(qnp + koff), *(const float4*)(qnp + koff + 4), qnh, qnl);
      cvt8(*(const float4*)(knp + koff), *(const float4*)(knp + koff + 4), knh, knl);
      Aacc = __builtin_amdgcn_mfma_f32_16x16x32_bf16(kbh, knh, Aacc, 0, 0, 0);
      Aacc = __builtin_amdgcn_mfma_f32_16x16x32_bf16(kbh, knl, Aacc, 0, 0, 0);
      Aacc = __builtin_amdgcn_mfma_f32_16x16x32_bf16(kbl, knh, Aacc, 0, 0, 0);
      Qacc = __builtin_amdgcn_mfma_f32_16x16x32_bf16(qnh, knh, Qacc, 0, 0, 0);
      Qacc = __builtin_amdgcn_mfma_f32_16x16x32_bf16(qnh, knl, Qacc, 0, 0, 0);
      Qacc = __builtin_amdgcn_mfma_f32_16x16x32_bf16(qnl, knh, Qacc, 0, 0, 0);
      if (ni == 0)
        *(uint4*)(q_bf + gbase + (size_t)mrow * 256 + koff) = *(uint4*)&qnh;
      if (mi == 0)
        *(uint4*)(kn_bf + gbase + (size_t)nrow * 256 + koff) = *(uint4*)&knh;
    }
  }
  float* ag = attn_g + ((size_t)bh * 64 + cc) * 1024;
#pragma unroll
  for (int r = 0; r < 4; ++r) {
    int row = mi * 16 + quad * 4 + r, col = ni * 16 + l16;
    Am[row][col] = (col < row) ? Aacc[r] : 0.f;
    ag[row * 32 + col] = (col <= row) ? Qacc[r] : 0.f;
  }
  __syncthreads();

  if (wv == 0) {
    if (t < 32) {
#pragma unroll
      for (int i = 0; i < 32; ++i) Tm[i][t] = (i == t) ? 1.f : 0.f;
      for (int i2 = 1; i2 < 32; ++i2) {
        if (t < i2) {
          float s = 0.f;
          for (int m2 = t; m2 < i2; ++m2) s = fmaf(Am[i2][m2], Tm[m2][t], s);
          Tm[i2][t] = -s;
        }
      }
    }
  } else {
    int base = t - 64;
#pragma unroll
    for (int pass = 0; pass < 2; ++pass) {
      int d = base + pass * 192;
      if (d < 256) {
        u32 hp[16], lp[16], kp2[16];
#pragma unroll
        for (int m2 = 0; m2 < 16; ++m2) {
          float f0 = kb[gbase + (size_t)(2 * m2) * 256 + d];
          float f1 = kb[gbase + (size_t)(2 * m2 + 1) * 256 + d];
          ushort_t h0 = f2bf(f0), h1 = f2bf(f1);
          hp[m2] = (u32)h0 | ((u32)h1 << 16);
          lp[m2] = (u32)f2bf(f0 - bf2f(h0)) | ((u32)f2bf(f1 - bf2f(h1)) << 16);
          float g0 = kn[gbase + (size_t)(2 * m2) * 256 + d];
          float g1 = kn[gbase + (size_t)(2 * m2 + 1) * 256 + d];
          kp2[m2] = (u32)f2bf(g0) | ((u32)f2bf(g1) << 16);
        }
#pragma unroll
        for (int q2 = 0; q2 < 4; ++q2) {
          *(uint4*)&KT_hi[d][q2 * 8] = *(uint4*)&hp[q2 * 4];
          *(uint4*)&KT_lo[d][q2 * 8] = *(uint4*)&lp[q2 * 4];
          *(uint4*)(knT_bf + gbase + (size_t)d * 32 + q2 * 8) = *(uint4*)&kp2[q2 * 4];
        }
      }
    }
  }
  __syncthreads();

  int lt = wv & 1, dgrp = wv >> 1;
  short8 Th, Tl;
  {
    int lrow = lt * 16 + l16;
    cvt8(*(const float4*)&Tm[lrow][quad * 8],
         *(const float4*)&Tm[lrow][quad * 8 + 4], Th, Tl);
  }
#pragma unroll
  for (int j = 0; j < 8; ++j) {
    int dt = dgrp * 8 + j;
    short8 Bh = *(const short8*)&KT_hi[dt * 16 + l16][quad * 8];
    short8 Bl = *(const short8*)&KT_lo[dt * 16 + l16][quad * 8];
    floatx4 acc = {0.f,0.f,0.f,0.f};
    acc = __builtin_amdgcn_mfma_f32_16x16x32_bf16(Th, Bh, acc, 0, 0, 0);
    acc = __builtin_amdgcn_mfma_f32_16x16x32_bf16(Th, Bl, acc, 0, 0, 0);
    acc = __builtin_amdgcn_mfma_f32_16x16x32_bf16(Tl, Bh, acc, 0, 0, 0);
#pragma unroll
    for (int r = 0; r < 4; ++r) {
      int row = lt * 16 + quad * 4 + r;
      wn_bf[gbase + (size_t)row * 256 + dt * 16 + l16] = f2bf(-acc[r]);
    }
  }
  __syncthreads();

  {
    int d = t;
    u32 hp[16], lp[16];
#pragma unroll
    for (int m2 = 0; m2 < 16; ++m2) {
      float f0 = vb[gbase + (size_t)(2 * m2) * 256 + d];
      float f1 = vb[gbase + (size_t)(2 * m2 + 1) * 256 + d];
      ushort_t h0 = f2bf(f0), h1 = f2bf(f1);
      hp[m2] = (u32)h0 | ((u32)h1 << 16);
      lp[m2] = (u32)f2bf(f0 - bf2f(h0)) | ((u32)f2bf(f1 - bf2f(h1)) << 16);
    }
#pragma unroll
    for (int q2 = 0; q2 < 4; ++q2) {
      *(uint4*)&KT_hi[d][q2 * 8] = *(uint4*)&hp[q2 * 4];
      *(uint4*)&KT_lo[d][q2 * 8] = *(uint4*)&lp[q2 * 4];
    }
  }
  __syncthreads();

#pragma unroll
  for (int j = 0; j < 8; ++j) {
    int dt = dgrp * 8 + j;
    short8 Bh = *(const short8*)&KT_hi[dt * 16 + l16][quad * 8];
    short8 Bl = *(const short8*)&KT_lo[dt * 16 + l16][quad * 8];
    floatx4 acc = {0.f,0.f,0.f,0.f};
    acc = __builtin_amdgcn_mfma_f32_16x16x32_bf16(Th, Bh, acc, 0, 0, 0);
    acc = __builtin_amdgcn_mfma_f32_16x16x32_bf16(Th, Bl, acc, 0, 0, 0);
    acc = __builtin_amdgcn_mfma_f32_16x16x32_bf16(Tl, Bh, acc, 0, 0, 0);
#pragma unroll
    for (int r = 0; r < 4; ++r) {
      int row = lt * 16 + quad * 4 + r;
      u_out[gbase + (size_t)row * 256 + dt * 16 + l16] = acc[r];
    }
  }
}

// ------- cross matrices per super-chunk: X = wn1 @ kn0^T, Y = q1 @ kn0^T ---
__global__ __launch_bounds__(256) void cross_prep(
    const ushort_t* __restrict__ wn_bf, const ushort_t* __restrict__ q_bf,
    const ushort_t* __restrict__ kn_bf,
    float* __restrict__ X_g, float* __restrict__ Y_g)
{
  int t = threadIdx.x;
  int sc = blockIdx.x & 31, bh = blockIdx.x >> 5;
  int wv = t >> 6, lane = t & 63;
  int l16 = lane & 15, quad = lane >> 4;
  int mi = wv >> 1, ni = wv & 1;
  size_t base = (size_t)bh * Ls * 256;
  size_t r1 = base + (size_t)(sc * 64 + 32 + mi * 16 + l16) * 256;  // chunk 2sc+1 rows
  size_t r0 = base + (size_t)(sc * 64 + ni * 16 + l16) * 256;       // chunk 2sc rows
  floatx4 Xacc = {0.f,0.f,0.f,0.f}, Yacc = {0.f,0.f,0.f,0.f};
#pragma unroll
  for (int ks = 0; ks < 8; ++ks) {
    int ko = ks * 32 + quad * 8;
    short8 aw = *(const short8*)(wn_bf + r1 + ko);
    short8 aq = *(const short8*)(q_bf  + r1 + ko);
    short8 bk = *(const short8*)(kn_bf + r0 + ko);
    Xacc = __builtin_amdgcn_mfma_f32_16x16x32_bf16(aw, bk, Xacc, 0, 0, 0);
    Yacc = __builtin_amdgcn_mfma_f32_16x16x32_bf16(aq, bk, Yacc, 0, 0, 0);
  }
  float* xo = X_g + ((size_t)bh * 32 + sc) * 1024;
  float* yo = Y_g + ((size_t)bh * 32 + sc) * 1024;
#pragma unroll
  for (int r = 0; r < 4; ++r) {
    int row = mi * 16 + quad * 4 + r, col = ni * 16 + l16;
    xo[row * 32 + col] = Xacc[r];
    yo[row * 32 + col] = Yacc[r];
  }
}

// ------- merged: MFMA serial scan (blocks 0-127) + FIR conv (blocks 128+) --
__global__ __launch_bounds__(256, 1) void delta_fir(
    const ushort_t* __restrict__ wn_bf, const ushort_t* __restrict__ q_bf,
    const ushort_t* __restrict__ knT_bf, const float* __restrict__ attn_g,
    const float* __restrict__ u_g, const float* __restrict__ X_g,
    const float* __restrict__ Y_g, float* __restrict__ delta_g,
    const float* __restrict__ v, const float* __restrict__ wlg,
    const float* __restrict__ wsg, float* __restrict__ firl,
    float* __restrict__ firs)
{
  __shared__ __attribute__((aligned(16))) char smem[72704];
  int t = threadIdx.x;

  if (blockIdx.x >= 128) {
    // ---------------- FIR part ----------------
    float (*vt)[71] = (float(*)[71])smem;
    int bid = blockIdx.x - 128;
    int lt = bid & 255;
    int bh = bid >> 8;
    int b = bh >> 2, h = bh & 3;
    int l0 = lt * 8;
    const float* vp = v + (size_t)bh * Ls * 256;
    for (int r = 0; r < 70; ++r) {
      int ls = l0 - 62 + r;
      vt[t][r] = (ls >= 0) ? vp[(size_t)ls * 256 + t] : 0.f;
    }
    float TL[63], TS3[3];
#pragma unroll
    for (int j = 0; j < 63; ++j) TL[j] = wlg[((size_t)h * 256 + t) * 63 + j];
#pragma unroll
    for (int j = 0; j < 3; ++j) TS3[j] = wsg[((size_t)h * 256 + t) * 3 + j];
    __syncthreads();
    float aL[8] = {0,0,0,0,0,0,0,0}, aS[8] = {0,0,0,0,0,0,0,0};
#pragma unroll
    for (int r = 0; r < 70; ++r) {
      float vm = vt[t][r];
#pragma unroll
      for (int p = 0; p < 8; ++p) {
        int jl = r - p;
        if (jl >= 0 && jl < 63) aL[p] = fmaf(vm, TL[jl], aL[p]);
        int jssrc = r - 60 - p;
        if (jssrc >= 0 && jssrc < 3) aS[p] = fmaf(vm, TS3[jssrc], aS[p]);
      }
    }
#pragma unroll
    for (int p = 0; p < 8; ++p) {
      int l = l0 + p;
      size_t ob = (((size_t)b * Ls + l) * NH + h) * 256 + t;
      firl[ob] = aL[p];
      firs[ob] = aS[p];
    }
    return;
  }

  // ---------------- chain part (m=2 super-chunks) ----------------
  ushort_t (*Shi)[264] = (ushort_t(*)[264])(smem);
  ushort_t (*Slo)[264] = (ushort_t(*)[264])(smem + 8448);
  float (*u2L0)[17] = (float(*)[17])(smem + 16896);
  float (*u2L1)[17] = (float(*)[17])(smem + 19072);
  int bh = blockIdx.x & 7, g = blockIdx.x >> 3;
  int b = bh >> 2, h = bh & 3;
  int wv = t >> 6, lane = t & 63;
  int lquad = lane >> 4, l16 = lane & 15;
  int j0 = g * 16;
  int Mt = wv & 1;
  bool isU = (wv < 2);
  const ushort_t* wp = wn_bf + (size_t)bh * Ls * 256;
  const ushort_t* qp = q_bf  + (size_t)bh * Ls * 256;
  const ushort_t* ap = (isU ? wp : qp) + (size_t)(Mt * 16 + l16) * 256;
  const ushort_t* kr = knT_bf + (size_t)bh * Ls * 256 + (size_t)l16 * 32 + lquad * 8;
  const float* urow = u_g + (size_t)bh * Ls * 256
                    + (size_t)(Mt * 16 + lquad * 4) * 256 + j0 + l16;
  const float* arp = attn_g + (size_t)bh * 64 * 1024
                   + (size_t)(Mt * 16 + l16) * 32 + lquad * 8;
  const float* xrp = (isU ? X_g : Y_g) + (size_t)bh * 32768
                   + (size_t)(Mt * 16 + l16) * 32 + lquad * 8;

  floatx4 Sacc[4], SaccL[4];
#pragma unroll
  for (int i = 0; i < 4; ++i)
#pragma unroll
    for (int r = 0; r < 4; ++r) { Sacc[i][r] = 0.f; SaccL[i][r] = 0.f; }
  for (int i = t; i < 4224; i += 256) ((u32*)smem)[i] = 0;

  // prologue: super-chunk 0, sub-chunk 0 operands
  short8 a0[8], k0[4];
  floatx4 u0 = {0.f, 0.f, 0.f, 0.f};
  float4 at0a = {0,0,0,0}, at0b = {0,0,0,0};
#pragma unroll
  for (int ks = 0; ks < 8; ++ks)
    a0[ks] = *(const short8*)(ap + ks * 32 + lquad * 8);
#pragma unroll
  for (int i = 0; i < 4; ++i)
    k0[i] = *(const short8*)(kr + (size_t)(wv * 4 + i) * 512);
  if (isU) {
#pragma unroll
    for (int r = 0; r < 4; ++r) u0[r] = urow[(size_t)r * 256];
  } else {
    at0a = *(const float4*)(arp);
    at0b = *(const float4*)(arp + 4);
  }
  wave_barrier();

  for (int sc = 0; sc < 32; ++sc) {
    size_t cb1 = (size_t)sc * 16384 + 8192;
    size_t nb0 = (size_t)(sc + 1) * 16384;
    bool hasN = (sc + 1 < 32);

    // sub-chunk1 operands + cross matrix (used mid-iteration; latency covered)
    short8 a1[8], k1[4];
    floatx4 u1 = {0.f, 0.f, 0.f, 0.f};
    float4 at1a = {0,0,0,0}, at1b = {0,0,0,0};
#pragma unroll
    for (int ks = 0; ks < 8; ++ks)
      a1[ks] = *(const short8*)(ap + cb1 + ks * 32 + lquad * 8);
#pragma unroll
    for (int i = 0; i < 4; ++i)
      k1[i] = *(const short8*)(kr + cb1 + (size_t)(wv * 4 + i) * 512);
    if (isU) {
#pragma unroll
      for (int r = 0; r < 4; ++r) u1[r] = urow[cb1 + (size_t)r * 256];
    } else {
      size_t na = (size_t)(2 * sc + 1) * 1024;
      at1a = *(const float4*)(arp + na);
      at1b = *(const float4*)(arp + na + 4);
    }
    float4 xa = *(const float4*)(xrp + (size_t)sc * 1024);
    float4 xb = *(const float4*)(xrp + (size_t)sc * 1024 + 4);

    // ---- sub-chunk 0: u2_0 (isU) / po_0 (o) against S0 ----
    floatx4 acc0;
    if (isU) {
      floatx4 A0 = u0, A1 = {0,0,0,0}, A2 = {0,0,0,0}, A3 = {0,0,0,0};
#pragma unroll
      for (int ks = 0; ks < 8; ++ks) {
        short8 sh = *(const short8*)&Shi[l16][ks * 32 + lquad * 8];
        short8 sl = *(const short8*)&Slo[l16][ks * 32 + lquad * 8];
        if (ks & 1) {
          A1 = __builtin_amdgcn_mfma_f32_16x16x32_bf16(a0[ks], sh, A1, 0, 0, 0);
          A3 = __builtin_amdgcn_mfma_f32_16x16x32_bf16(a0[ks], sl, A3, 0, 0, 0);
        } else {
          A0 = __builtin_amdgcn_mfma_f32_16x16x32_bf16(a0[ks], sh, A0, 0, 0, 0);
          A2 = __builtin_amdgcn_mfma_f32_16x16x32_bf16(a0[ks], sl, A2, 0, 0, 0);
        }
      }
#pragma unroll
      for (int r = 0; r < 4; ++r) acc0[r] = (A0[r] + A1[r]) + (A2[r] + A3[r]);
#pragma unroll
      for (int r = 0; r < 4; ++r)
        u2L0[Mt * 16 + lquad * 4 + r][l16] = acc0[r];
    } else {
      floatx4 A0 = {0,0,0,0}, A1 = {0,0,0,0};
#pragma unroll
      for (int ks = 0; ks < 8; ++ks) {
        short8 sh = *(const short8*)&Shi[l16][ks * 32 + lquad * 8];
        if (ks & 1) A1 = __builtin_amdgcn_mfma_f32_16x16x32_bf16(a0[ks], sh, A1, 0, 0, 0);
        else        A0 = __builtin_amdgcn_mfma_f32_16x16x32_bf16(a0[ks], sh, A0, 0, 0, 0);
      }
#pragma unroll
      for (int r = 0; r < 4; ++r) acc0[r] = A0[r] + A1[r];
    }
    // prefetch next-super-chunk a0 (a0 regs dead; stays in flight across
    // the raw barriers below -> ~full iteration of latency cover)
    if (hasN) {
#pragma unroll
      for (int ks = 0; ks < 8; ++ks)
        a0[ks] = *(const short8*)(ap + nb0 + ks * 32 + lquad * 8);
    }
    wave_barrier();                          // u2_0 visible

    short8 uh0, ul0;
#pragma unroll
    for (int j = 0; j < 8; ++j) {
      float f = u2L0[lquad * 8 + j][l16];
      ushort_t hi = f2bf(f);
      uh0[j] = (short)hi;
      ul0[j] = (short)f2bf(f - bf2f(hi));
    }
#pragma unroll
    for (int i = 0; i < 4; ++i) {
      Sacc[i]  = __builtin_amdgcn_mfma_f32_16x16x32_bf16(k0[i], uh0, Sacc[i], 0, 0, 0);
      SaccL[i] = __builtin_amdgcn_mfma_f32_16x16x32_bf16(k0[i], ul0, SaccL[i], 0, 0, 0);
    }
    if (hasN) {
#pragma unroll
      for (int i = 0; i < 4; ++i)
        k0[i] = *(const short8*)(kr + nb0 + (size_t)(wv * 4 + i) * 512);
    }

    // ---- sub-chunk 1: u2_1 = u1 + wn1@S0 + X@u2_0 / o path ----
    floatx4 acc1;
    if (isU) {
      floatx4 A0 = u1, A1 = {0,0,0,0}, A2 = {0,0,0,0}, A3 = {0,0,0,0};
#pragma unroll
      for (int ks = 0; ks < 8; ++ks) {
        short8 sh = *(const short8*)&Shi[l16][ks * 32 + lquad * 8];
        short8 sl = *(const short8*)&Slo[l16][ks * 32 + lquad * 8];
        if (ks & 1) {
          A1 = __builtin_amdgcn_mfma_f32_16x16x32_bf16(a1[ks], sh, A1, 0, 0, 0);
          A3 = __builtin_amdgcn_mfma_f32_16x16x32_bf16(a1[ks], sl, A3, 0, 0, 0);
        } else {
          A0 = __builtin_amdgcn_mfma_f32_16x16x32_bf16(a1[ks], sh, A0, 0, 0, 0);
          A2 = __builtin_amdgcn_mfma_f32_16x16x32_bf16(a1[ks], sl, A2, 0, 0, 0);
        }
      }
      short8 Xh, Xl;
      cvt8(xa, xb, Xh, Xl);
      A0 = __builtin_amdgcn_mfma_f32_16x16x32_bf16(Xh, uh0, A0, 0, 0, 0);
      A1 = __builtin_amdgcn_mfma_f32_16x16x32_bf16(Xh, ul0, A1, 0, 0, 0);
      A2 = __builtin_amdgcn_mfma_f32_16x16x32_bf16(Xl, uh0, A2, 0, 0, 0);
#pragma unroll
      for (int r = 0; r < 4; ++r) acc1[r] = (A0[r] + A1[r]) + (A2[r] + A3[r]);
#pragma unroll
      for (int r = 0; r < 4; ++r)
        u2L1[Mt * 16 + lquad * 4 + r][l16] = acc1[r];
      if (hasN) {
#pragma unroll
        for (int r = 0; r < 4; ++r) u0[r] = urow[nb0 + (size_t)r * 256];
      }
    } else {
      // o_0 = po_0 + attn_0 @ u2_0 -> store
      short8 ath, atl;
      cvt8(at0a, at0b, ath, atl);
      acc0 = __builtin_amdgcn_mfma_f32_16x16x32_bf16(ath, uh0, acc0, 0, 0, 0);
      acc0 = __builtin_amdgcn_mfma_f32_16x16x32_bf16(ath, ul0, acc0, 0, 0, 0);
      acc0 = __builtin_amdgcn_mfma_f32_16x16x32_bf16(atl, uh0, acc0, 0, 0, 0);
#pragma unroll
      for (int r = 0; r < 4; ++r) {
        int l = sc * 64 + Mt * 16 + lquad * 4 + r;
        delta_g[(((size_t)b * Ls + l) * NH + h) * 256 + j0 + l16] = acc0[r];
      }
      // po_1 = q1 @ Shi(S0) + Y @ u2_0
      floatx4 A0 = {0,0,0,0}, A1 = {0,0,0,0};
#pragma unroll
      for (int ks = 0; ks < 8; ++ks) {
        short8 sh = *(const short8*)&Shi[l16][ks * 32 + lquad * 8];
        if (ks & 1) A1 = __builtin_amdgcn_mfma_f32_16x16x32_bf16(a1[ks], sh, A1, 0, 0, 0);
        else        A0 = __builtin_amdgcn_mfma_f32_16x16x32_bf16(a1[ks], sh, A0, 0, 0, 0);
      }
      short8 Yh, Yl;
      cvt8(xa, xb, Yh, Yl);
      A0 = __builtin_amdgcn_mfma_f32_16x16x32_bf16(Yh, uh0, A0, 0, 0, 0);
      A1 = __builtin_amdgcn_mfma_f32_16x16x32_bf16(Yh, ul0, A1, 0, 0, 0);
      A0 = __builtin_amdgcn_mfma_f32_16x16x32_bf16(Yl, uh0, A0, 0, 0, 0);
#pragma unroll
      for (int r = 0; r < 4; ++r) acc1[r] = A0[r] + A1[r];
      if (hasN) {
        size_t na0 = (size_t)(2 * sc + 2) * 1024;
        at0a = *(const float4*)(arp + na0);
        at0b = *(const float4*)(arp + na0 + 4);
      }
    }
    wave_barrier();                          // u2_1 visible; all Shi/Slo reads done

    short8 uh1, ul1;
#pragma unroll
    for (int j = 0; j < 8; ++j) {
      float f = u2L1[lquad * 8 + j][l16];
      ushort_t hi = f2bf(f);
      uh1[j] = (short)hi;
      ul1[j] = (short)f2bf(f - bf2f(hi));
    }
#pragma unroll
    for (int i = 0; i < 4; ++i) {
      Sacc[i]  = __builtin_amdgcn_mfma_f32_16x16x32_bf16(k1[i], uh1, Sacc[i], 0, 0, 0);
      SaccL[i] = __builtin_amdgcn_mfma_f32_16x16x32_bf16(k1[i], ul1, SaccL[i], 0, 0, 0);
    }
    if (!isU) {
      short8 ath, atl;
      cvt8(at1a, at1b, ath, atl);
      acc1 = __builtin_amdgcn_mfma_f32_16x16x32_bf16(ath, uh1, acc1, 0, 0, 0);
      acc1 = __builtin_amdgcn_mfma_f32_16x16x32_bf16(ath, ul1, acc1, 0, 0, 0);
      acc1 = __builtin_amdgcn_mfma_f32_16x16x32_bf16(atl, uh1, acc1, 0, 0, 0);
#pragma unroll
      for (int r = 0; r < 4; ++r) {
        int l = sc * 64 + 32 + Mt * 16 + lquad * 4 + r;
        delta_g[(((size_t)b * Ls + l) * NH + h) * 256 + j0 + l16] = acc1[r];
      }
    }
    // S write-back (once per 64 tokens)
#pragma unroll
    for (int i = 0; i < 4; ++i) {
      int dk0 = (wv * 4 + i) * 16 + lquad * 4;
      ushort4 h4, l4;
      ushort_t* hp = (ushort_t*)&h4;
      ushort_t* lp = (ushort_t*)&l4;
#pragma unroll
      for (int r = 0; r < 4; ++r) {
        float sv = Sacc[i][r] + SaccL[i][r];
        ushort_t hi = f2bf(sv);
        hp[r] = hi;
        lp[r] = f2bf(sv - bf2f(hi));
      }
      *(ushort4*)&Shi[l16][dk0] = h4;
      *(ushort4*)&Slo[l16][dk0] = l4;
    }
    wave_barrier();                          // S visible
  }
}

// ------- gate_in (bf16) ----------------------------------------------------
__global__ __launch_bounds__(256) void build_gate_in_bf(
    const float* __restrict__ x, const float* __restrict__ firs,
    const float* __restrict__ firl, const float* __restrict__ delta,
    const float* __restrict__ v, ushort_t* __restrict__ gin)
{
  int mtok = blockIdx.x, t = threadIdx.x;
  int b = mtok >> 11, l = mtok & 2047;
  float4 xv = *(const float4*)(x + (size_t)mtok * 1024 + t * 4);
  ushort4 xo = make_ushort4(f2bf(xv.x), f2bf(xv.y), f2bf(xv.z), f2bf(xv.w));
  *(ushort4*)(gin + (size_t)mtok * 1056 + t * 4) = xo;
  int w = t >> 6, lane = t & 63;
  for (int br = 0; br < 4; ++br) {
    float s = 0.f, s2 = 0.f;
#pragma unroll
    for (int r = 0; r < 4; ++r) {
      int d = lane + r * 64;
      float val;
      if (br == 0)      val = firs [(size_t)mtok * 1024 + w * 256 + d];
      else if (br == 1) val = firl [(size_t)mtok * 1024 + w * 256 + d];
      else if (br == 2) val = delta[(size_t)mtok * 1024 + w * 256 + d];
      else              val = v[(((size_t)(b * NH + w)) * Ls + l) * 256 + d];
      s += val; s2 = fmaf(val, val, s2);
    }
#pragma unroll
    for (int off = 32; off; off >>= 1) {
      s += __shfl_down(s, off);
      s2 += __shfl_down(s2, off);
    }
    if (lane == 0) {
      float mean = s * (1.f / 256.f);
      float var = s2 * (1.f / 256.f) - mean * mean;
      gin[(size_t)mtok * 1056 + 1024 + br * 8 + w] = f2bf(mean);
      gin[(size_t)mtok * 1056 + 1024 + br * 8 + 4 + w] = f2bf(sqrtf(fmaxf(var, 1e-6f)));
    }
  }
}

// ------- logits -> gates (bf16 hidden input) -------------------------------
__global__ __launch_bounds__(256) void mlp2_gates(
    const ushort_t* __restrict__ mh, const float* __restrict__ W2,
    const float* __restrict__ b2, const float* __restrict__ glt,
    float* __restrict__ gates)
{
  int mtok = blockIdx.x, t = threadIdx.x;
  float p[16];
#pragma unroll
  for (int j = 0; j < 16; ++j) p[j] = 0.f;
  for (int k = t; k < 2048; k += 256) {
    float hv = bf2f(mh[(size_t)mtok * 2048 + k]);
    const float* wr = W2 + (size_t)k * 16;
#pragma unroll
    for (int j4 = 0; j4 < 4; ++j4) {
      float4 w4 = *(const float4*)(wr + j4 * 4);
      p[j4*4+0] = fmaf(hv, w4.x, p[j4*4+0]);
      p[j4*4+1] = fmaf(hv, w4.y, p[j4*4+1]);
      p[j4*4+2] = fmaf(hv, w4.z, p[j4*4+2]);
      p[j4*4+3] = fmaf(hv, w4.w, p[j4*4+3]);
    }
  }
#pragma unroll
  for (int j = 0; j < 16; ++j)
#pragma unroll
    for (int off = 32; off; off >>= 1) p[j] += __shfl_down(p[j], off);
  __shared__ float red[4][16];
  __shared__ float zl[16];
  int w = t >> 6;
  if ((t & 63) == 0) {
#pragma unroll
    for (int j = 0; j < 16; ++j) red[w][j] = p[j];
  }
  __syncthreads();
  if (t < 16) {
    float tot = red[0][t] + red[1][t] + red[2][t] + red[3][t] + b2[t];
    float tempv = log1pf(expf(glt[t >> 2])) + 1e-4f;
    zl[t] = tot / tempv;
  }
  __syncthreads();
  if (t < 4) {
    float z0 = zl[t*4], z1 = zl[t*4+1], z2 = zl[t*4+2], z3 = zl[t*4+3];
    float mx = fmaxf(fmaxf(z0, z1), fmaxf(z2, z3));
    float e0 = expf(z0 - mx), e1 = expf(z1 - mx), e2 = expf(z2 - mx), e3 = expf(z3 - mx);
    float inv = 1.f / (e0 + e1 + e2 + e3);
    gates[(size_t)mtok * 16 + t * 4 + 0] = e0 * inv;
    gates[(size_t)mtok * 16 + t * 4 + 1] = e1 * inv;
    gates[(size_t)mtok * 16 + t * 4 + 2] = e2 * inv;
    gates[(size_t)mtok * 16 + t * 4 + 3] = e3 * inv;
  }
}

// ------- o = gated mix, RMSNorm -> bf16 ------------------------------------
__global__ __launch_bounds__(256) void combine_norm_bf(
    const float* __restrict__ firs, const float* __restrict__ firl,
    const float* __restrict__ delta, const float* __restrict__ v,
    const float* __restrict__ gates, const float* __restrict__ onw,
    ushort_t* __restrict__ o)
{
  int mh = blockIdx.x;
  int mtok = mh >> 2, h = mh & 3;
  int t = threadIdx.x;
  int b = mtok >> 11, l = mtok & 2047;
  const float* g = gates + (size_t)mtok * 16 + h * 4;
  float w0 = g[0], w1 = g[1], w2 = g[2], w3 = g[3];
  size_t tb = (size_t)mtok * 1024 + h * 256 + t;
  float val = w0 * firs[tb] + w1 * firl[tb] + w2 * delta[tb]
            + w3 * v[(((size_t)(b * NH + h)) * Ls + l) * 256 + t];
  float s2 = val * val;
#pragma unroll
  for (int off = 32; off; off >>= 1) s2 += __shfl_down(s2, off);
  __shared__ float r4[4];
  if ((t & 63) == 0) r4[t >> 6] = s2;
  __syncthreads();
  float tot = r4[0] + r4[1] + r4[2] + r4[3];
  float rms = rsqrtf(tot * (1.f / 256.f) + 1e-5f);
  o[tb] = f2bf(val * rms * onw[t]);
}

// ---------------------------------------------------------------------------
extern "C" void kernel_launch(void* const* d_in, const int* in_sizes, int n_in,
                              void* d_out, int out_size, void* d_ws, size_t ws_size,
                              hipStream_t stream) {
  const float* x     = (const float*)d_in[0];
  const float* Wq    = (const float*)d_in[1];
  const float* Wk    = (const float*)d_in[2];
  const float* Wv    = (const float*)d_in[3];
  const float* Wb    = (const float*)d_in[4];
  const float* convq = (const float*)d_in[5];
  const float* convk = (const float*)d_in[6];
  const float* convv = (const float*)d_in[7];
  const float* firsw = (const float*)d_in[8];
  const float* firlw = (const float*)d_in[9];
  const float* mlpw1 = (const float*)d_in[10];
  const float* mlpb1 = (const float*)d_in[11];
  const float* mlpw2 = (const float*)d_in[12];
  const float* mlpb2 = (const float*)d_in[13];
  const float* glt   = (const float*)d_in[14];
  const float* onw   = (const float*)d_in[15];
  const float* Wo    = (const float*)d_in[16];
  float* ws = (float*)d_ws;

  ushort_t* x_bf   = (ushort_t*)(ws + off_firs);
  ushort_t* Wqkv_t = (ushort_t*)(ws + off_firl);  // 3 x [1024][1024] contiguous
  ushort_t* gin_bf = (ushort_t*)(ws + off_gin);
  ushort_t* w1_t   = (ushort_t*)(ws + off_k);     // kn dead after chunk_prep
  ushort_t* o_bf   = (ushort_t*)(ws + off_xv);
  ushort_t* Wo_t   = (ushort_t*)(ws + off_beta);  // spans into attn (dead)
  ushort_t* mlph_bf= (ushort_t*)(ws + off_mlph);
  ushort_t* wn_bf  = (ushort_t*)(ws + off_firs);
  ushort_t* q_bf   = (ushort_t*)(ws + off_firs + 2097152);
  ushort_t* knT_bf = (ushort_t*)(ws + off_firl);
  ushort_t* kn_bf  = (ushort_t*)(ws + off_xq);    // x3 dead after conv_prep
  float* x3   = ws + off_xq;     // fused [4096][3072] spans xq/xk/xv
  float* kb_f = ws + off_gin;
  float* vb_f = ws + off_mlph;
  float* X_g  = ws + off_gin;            // kb dead after chunk_prep; 8*32*1024 f32
  float* Y_g  = ws + off_gin + 262144;
  float* firs_f = ws + off_xq;   // x3/kn_bf dead after cross_prep
  float* firl_f = ws + off_xk;

  dim3 blk(256);
  // fused q/k/v projection (one N=3072 GEMM) + beta
  to_bf16<<<2048, blk, 0, stream>>>(x, x_bf, 4194304);
  convT<<<dim3(32, 32), blk, 0, stream>>>(Wq, Wqkv_t, 1024, 1024);
  convT<<<dim3(32, 32), blk, 0, stream>>>(Wk, Wqkv_t + 1048576, 1024, 1024);
  convT<<<dim3(32, 32), blk, 0, stream>>>(Wv, Wqkv_t + 2097152, 1024, 1024);
  gemm_bf16<<<dim3(24, 32), blk, 0, stream>>>(x_bf, Wqkv_t, x3, 3072, 1024, nullptr, 0, 0);
  beta_sigmoid<<<4096, blk, 0, stream>>>(x, Wb, ws + off_beta);
  // fused conv4+silu + l2norm + beta products (vectorized, 1 block/token)
  conv_prep<<<4096, blk, 0, stream>>>(x3, convq, convk, convv, ws + off_beta,
                                      ws + off_q, ws + off_k, kb_f, vb_f, ws + off_v);
  // per-chunk T inverse, attn, u (->xv), bf16 {-w, q, knT, kn}
  chunk_prep<<<512, blk, 0, stream>>>(kb_f, ws + off_k, ws + off_q, vb_f,
                                      ws + off_attn, ws + off_xv, wn_bf, q_bf,
                                      knT_bf, kn_bf);
  // 32x32 cross matrices per super-chunk (X = wn1 kn0^T, Y = q1 kn0^T)
  cross_prep<<<256, blk, 0, stream>>>(wn_bf, q_bf, kn_bf, X_g, Y_g);
  // merged serial MFMA scan (delta -> off_q) + FIR (firs/firl -> x3 regions)
  delta_fir<<<2176, blk, 0, stream>>>(wn_bf, q_bf, knT_bf, ws + off_attn,
                                      ws + off_xv, X_g, Y_g, ws + off_q,
                                      ws + off_v, firlw, firsw, firl_f, firs_f);
  // gate input (bf16), MLP1 (MFMA, gelu, bf16 out), gates
  build_gate_in_bf<<<4096, blk, 0, stream>>>(x, firs_f, firl_f, ws + off_q,
                                             ws + off_v, gin_bf);
  convT<<<dim3(64, 33), blk, 0, stream>>>(mlpw1, w1_t, 1056, 2048);
  gemm_bf16<<<dim3(16, 32), blk, 0, stream>>>(gin_bf, w1_t, (float*)mlph_bf,
                                              2048, 1056, mlpb1, 1, 1);
  mlp2_gates<<<4096, blk, 0, stream>>>(mlph_bf, mlpw2, mlpb2, glt, ws + off_gates);
  // combine + RMSNorm -> bf16, output projection (MFMA)
  combine_norm_bf<<<16384, blk, 0, stream>>>(firs_f, firl_f, ws + off_q,
                                             ws + off_v, ws + off_gates, onw, o_bf);
  convT<<<dim3(32, 32), blk, 0, stream>>>(Wo, Wo_t, 1024, 1024);
  gemm_bf16<<<dim3(8, 32), blk, 0, stream>>>(o_bf, Wo_t, (float*)d_out, 1024, 1024, nullptr, 0, 0);
}

// Round 7
// 553.659 us; speedup vs baseline: 1.3238x; 1.0071x over previous
//
#include <hip/hip_runtime.h>
#include <hip/hip_bf16.h>

// ---------------------------------------------------------------------------
// DeltaNet forward, round 14:
//  - Base: r8 structure exactly (proven 546us; chain locked at 146us).
//    conv_prep reverted to r8 original (r13's vectorized version correlated
//    with +12us in a same-speed session -> reverted per discipline).
//  - ONE change: gemm_bf16 K-step 32 -> 64 (BK=64). Halves the
//    stage+vmcnt(0)+barrier events per FLOP (the 2-phase GEMM critical path
//    per m233); K-accumulation order preserved bit-identically (64-step =
//    two ordered 32-sub-steps). K=1056 handled by a 32-wide tail that
//    reuses the old staging/read code. LDS 16->32KB (still >=4 blocks/CU).
// ---------------------------------------------------------------------------

#define DEVI __device__ __forceinline__
typedef unsigned int u32;
typedef unsigned short ushort_t;
typedef __attribute__((ext_vector_type(8))) short short8;
typedef __attribute__((ext_vector_type(4))) float floatx4;

constexpr int Ls = 2048, NH = 4;

// workspace offsets (floats)
constexpr size_t off_xq   = 0;         // x3 [m][3072] cols 0-1023 -> kn_bf -> firs
constexpr size_t off_xk   = 4194304;   // x3 cols 1024-2047 -> firl
constexpr size_t off_xv   = 8388608;   // x3 cols 2048-3071 -> u -> o_bf
constexpr size_t off_q    = 12582912;  // qn -> delta
constexpr size_t off_k    = 16777216;  // kn -> w1_t (bf16)
constexpr size_t off_v    = 20971520;  // v (alive to the end)
constexpr size_t off_beta = 25165824;  // beta -> Wo_t (bf16, spans into attn)
constexpr size_t off_attn = 25182208;  // attn (dead after chain)
constexpr size_t off_firs = 25706496;  // x_bf -> {wn_bf, q_bf} (bf16)
constexpr size_t off_firl = 29900800;  // Wqkv_t -> knT_bf (bf16)
constexpr size_t off_gin  = 34095104;  // kb (f32) -> {X_g, Y_g} -> gin_bf
constexpr size_t off_mlph = 38420480;  // vb (f32) -> mlph_bf
constexpr size_t off_gates= 46809088;  // gates

DEVI float sigmoidf_(float x) { return 1.f / (1.f + expf(-x)); }
DEVI float siluf_(float x) { return x / (1.f + expf(-x)); }
DEVI float geluf_(float x) { return 0.5f * x * (1.f + erff(x * 0.7071067811865476f)); }
DEVI ushort_t f2bf(float f) {
  union { float f; u32 u; } c{f};
  u32 r = (c.u + 0x7fffu + ((c.u >> 16) & 1u)) >> 16;
  return (ushort_t)r;
}
DEVI float bf2f(ushort_t h) {
  union { u32 u; float f; } c; c.u = ((u32)h) << 16; return c.f;
}
DEVI void cvt8(float4 a, float4 b, short8& hi, short8& lo) {
  float f[8] = {a.x,a.y,a.z,a.w,b.x,b.y,b.z,b.w};
#pragma unroll
  for (int j = 0; j < 8; ++j) {
    ushort_t h = f2bf(f[j]);
    hi[j] = (short)h;
    lo[j] = (short)f2bf(f[j] - bf2f(h));
  }
}
DEVI void async16(const void* g, void* l) {
  __builtin_amdgcn_global_load_lds(
      (const u32 __attribute__((address_space(1)))*)g,
      (u32 __attribute__((address_space(3)))*)l, 16, 0, 0);
}
// Raw workgroup barrier: waits LDS ops only (lgkmcnt), leaves global
// loads/stores (vmcnt) in flight. All cross-wave deps in the chain loop are
// LDS-only, and global data has no in-kernel consumers.
DEVI void wave_barrier() {
  __builtin_amdgcn_sched_barrier(0);
  asm volatile("s_waitcnt lgkmcnt(0)" ::: "memory");
  __builtin_amdgcn_s_barrier();
  __builtin_amdgcn_sched_barrier(0);
}

// ---------------- f32 -> bf16 ----------------------------------------------
__global__ __launch_bounds__(256) void to_bf16(
    const float* __restrict__ in, ushort_t* __restrict__ out, int n)
{
  int i = (blockIdx.x * 256 + threadIdx.x) * 8;
  if (i >= n) return;
  float4 a = *(const float4*)(in + i);
  float4 b = *(const float4*)(in + i + 4);
  ushort_t o[8] = { f2bf(a.x), f2bf(a.y), f2bf(a.z), f2bf(a.w),
                    f2bf(b.x), f2bf(b.y), f2bf(b.z), f2bf(b.w) };
  *(uint4*)(out + i) = *(uint4*)o;
}

// ---------------- f32 [K][N] -> bf16 [N][K] --------------------------------
__global__ __launch_bounds__(256) void convT(
    const float* __restrict__ W, ushort_t* __restrict__ out, int Kq, int Nq)
{
  __shared__ ushort_t tile[32][33];
  int n0 = blockIdx.x * 32, k0 = blockIdx.y * 32;
  int tx = threadIdx.x & 31, ty = threadIdx.x >> 5;
#pragma unroll
  for (int r = 0; r < 32; r += 8)
    tile[ty + r][tx] = f2bf(W[(size_t)(k0 + ty + r) * Nq + n0 + tx]);
  __syncthreads();
#pragma unroll
  for (int r = 0; r < 32; r += 8)
    out[(size_t)(n0 + ty + r) * Kq + k0 + tx] = tile[tx][ty + r];
}

// ---------------- bf16 MFMA GEMM (BK=64 + 32-tail) -------------------------
__global__ __launch_bounds__(256) void gemm_bf16(
    const ushort_t* __restrict__ A, const ushort_t* __restrict__ Bt,
    float* __restrict__ C, int Nq, int Kq,
    const float* __restrict__ bias, int act, int outbf)
{
  __shared__ ushort_t As[128 * 64];
  __shared__ ushort_t Bs[128 * 64];
  int t = threadIdx.x;
  int w = t >> 6, lane = t & 63;
  int m0 = blockIdx.y * 128, n0 = blockIdx.x * 128;
  floatx4 acc[4][4];
#pragma unroll
  for (int i = 0; i < 4; ++i)
#pragma unroll
    for (int j = 0; j < 4; ++j)
#pragma unroll
      for (int r = 0; r < 4; ++r) acc[i][j][r] = 0.f;

  int lrow8 = lane >> 3, lcol8 = (lane & 7) * 8;   // BK=64 staging map
  int lrow16 = lane >> 2, lcol4 = (lane & 3) * 8;  // BK=32 tail staging map

  int kt = 0;
  for (; kt + 64 <= Kq; kt += 64) {
#pragma unroll
    for (int r = 0; r < 4; ++r) {
      int seg = w * 4 + r;                 // 16 segs x 8 rows x 64 cols
      int row = seg * 8 + lrow8;
      async16(A  + (size_t)(m0 + row) * Kq + kt + lcol8, &As[seg * 512]);
      async16(Bt + (size_t)(n0 + row) * Kq + kt + lcol8, &Bs[seg * 512]);
    }
    __syncthreads();
#pragma unroll
    for (int ks = 0; ks < 2; ++ks) {
      short8 af[4], bf[4];
#pragma unroll
      for (int i = 0; i < 4; ++i) {
        int row = (w >> 1) * 64 + i * 16 + (lane & 15);
        af[i] = *(const short8*)&As[row * 64 + ks * 32 + (lane >> 4) * 8];
      }
#pragma unroll
      for (int j = 0; j < 4; ++j) {
        int col = (w & 1) * 64 + j * 16 + (lane & 15);
        bf[j] = *(const short8*)&Bs[col * 64 + ks * 32 + (lane >> 4) * 8];
      }
#pragma unroll
      for (int i = 0; i < 4; ++i)
#pragma unroll
        for (int j = 0; j < 4; ++j)
          acc[i][j] = __builtin_amdgcn_mfma_f32_16x16x32_bf16(af[i], bf[j], acc[i][j], 0, 0, 0);
    }
    __syncthreads();
  }
  if (kt < Kq) {   // 32-wide tail (old layout, dense 32-stride region)
#pragma unroll
    for (int r = 0; r < 2; ++r) {
      int seg = w * 2 + r;
      int row = seg * 16 + lrow16;
      async16(A  + (size_t)(m0 + row) * Kq + kt + lcol4, &As[seg * 512]);
      async16(Bt + (size_t)(n0 + row) * Kq + kt + lcol4, &Bs[seg * 512]);
    }
    __syncthreads();
    short8 af[4], bf[4];
#pragma unroll
    for (int i = 0; i < 4; ++i) {
      int row = (w >> 1) * 64 + i * 16 + (lane & 15);
      af[i] = *(const short8*)&As[row * 32 + (lane >> 4) * 8];
    }
#pragma unroll
    for (int j = 0; j < 4; ++j) {
      int col = (w & 1) * 64 + j * 16 + (lane & 15);
      bf[j] = *(const short8*)&Bs[col * 32 + (lane >> 4) * 8];
    }
#pragma unroll
    for (int i = 0; i < 4; ++i)
#pragma unroll
      for (int j = 0; j < 4; ++j)
        acc[i][j] = __builtin_amdgcn_mfma_f32_16x16x32_bf16(af[i], bf[j], acc[i][j], 0, 0, 0);
    __syncthreads();
  }
#pragma unroll
  for (int i = 0; i < 4; ++i) {
    int rbase = m0 + (w >> 1) * 64 + i * 16 + ((lane >> 4) << 2);
#pragma unroll
    for (int j = 0; j < 4; ++j) {
      int col = n0 + (w & 1) * 64 + j * 16 + (lane & 15);
      float bv = act ? bias[col] : 0.f;
#pragma unroll
      for (int r = 0; r < 4; ++r) {
        float v = acc[i][j][r];
        if (act) v = geluf_(v + bv);
        if (outbf) ((ushort_t*)C)[(size_t)(rbase + r) * Nq + col] = f2bf(v);
        else       C[(size_t)(rbase + r) * Nq + col] = v;
      }
    }
  }
}

// ---------------- beta = sigmoid(x @ Wb) -----------------------------------
__global__ __launch_bounds__(256) void beta_sigmoid(
    const float* __restrict__ x, const float* __restrict__ Wb,
    float* __restrict__ beta)
{
  int mtok = blockIdx.x, t = threadIdx.x;
  int b = mtok >> 11, l = mtok & 2047;
  float a0 = 0, a1 = 0, a2 = 0, a3 = 0;
  for (int k = t; k < 1024; k += 256) {
    float xv = x[(size_t)mtok * 1024 + k];
    float4 w4 = *(const float4*)(Wb + k * 4);
    a0 = fmaf(xv, w4.x, a0); a1 = fmaf(xv, w4.y, a1);
    a2 = fmaf(xv, w4.z, a2); a3 = fmaf(xv, w4.w, a3);
  }
#pragma unroll
  for (int off = 32; off; off >>= 1) {
    a0 += __shfl_down(a0, off); a1 += __shfl_down(a1, off);
    a2 += __shfl_down(a2, off); a3 += __shfl_down(a3, off);
  }
  __shared__ float red[4][4];
  int w = t >> 6;
  if ((t & 63) == 0) { red[w][0] = a0; red[w][1] = a1; red[w][2] = a2; red[w][3] = a3; }
  __syncthreads();
  if (t < 4) {
    float s = red[0][t] + red[1][t] + red[2][t] + red[3][t];
    beta[((size_t)(b * NH + t)) * Ls + l] = sigmoidf_(s);
  }
}

// ------- fused conv4+silu (from fused x3 [m][3072]) + l2norm + beta --------
__global__ __launch_bounds__(256) void conv_prep(
    const float* __restrict__ x3, const float* __restrict__ wq,
    const float* __restrict__ wk, const float* __restrict__ wv,
    const float* __restrict__ beta_g,
    float* __restrict__ qn, float* __restrict__ kn,
    float* __restrict__ kb, float* __restrict__ vb,
    float* __restrict__ v_out)
{
  int i = blockIdx.x;              // bh*Ls + l
  int t = threadIdx.x;
  int l = i & 2047, bh = i >> 11;
  int b = bh >> 2, h = bh & 3;
  int c = h * 256 + t;
  const float* p = x3 + ((size_t)b * Ls) * 3072 + c;
  float4 wq4 = *(const float4*)(wq + c * 4);
  float4 wk4 = *(const float4*)(wk + c * 4);
  float4 wv4 = *(const float4*)(wv + c * 4);
  float qw[4] = {wq4.x, wq4.y, wq4.z, wq4.w};
  float kw[4] = {wk4.x, wk4.y, wk4.z, wk4.w};
  float vw[4] = {wv4.x, wv4.y, wv4.z, wv4.w};
  float aq = 0.f, ak = 0.f, av = 0.f;
#pragma unroll
  for (int j = 0; j < 4; ++j) {
    int ls = l - 3 + j;
    if (ls >= 0) {
      size_t rb = (size_t)ls * 3072;
      aq = fmaf(qw[j], p[rb], aq);
      ak = fmaf(kw[j], p[rb + 1024], ak);
      av = fmaf(vw[j], p[rb + 2048], av);
    }
  }
  float qv = siluf_(aq), kv = siluf_(ak), vv = siluf_(av);
  float sq = qv * qv, sk = kv * kv;
#pragma unroll
  for (int off = 32; off; off >>= 1) {
    sq += __shfl_down(sq, off);
    sk += __shfl_down(sk, off);
  }
  __shared__ float rq_[4], rk_[4];
  int w = t >> 6;
  if ((t & 63) == 0) { rq_[w] = sq; rk_[w] = sk; }
  __syncthreads();
  sq = rq_[0] + rq_[1] + rq_[2] + rq_[3];
  sk = rk_[0] + rk_[1] + rk_[2] + rk_[3];
  float rq = rsqrtf(sq + 1e-6f), rk = rsqrtf(sk + 1e-6f);
  float bt = beta_g[i];
  size_t base = (size_t)i * 256 + t;
  qn[base] = qv * rq;
  kn[base] = kv * rk;
  kb[base] = kv * rk * bt;
  vb[base] = vv * bt;
  v_out[base] = vv;
}

// ------- per (b,h,chunk) MFMA: Gram, substitution, w/u applies -------------
__global__ __launch_bounds__(256) void chunk_prep(
    const float* __restrict__ kb, const float* __restrict__ kn,
    const float* __restrict__ qn, const float* __restrict__ vb,
    float* __restrict__ attn_g, float* __restrict__ u_out,
    ushort_t* __restrict__ wn_bf, ushort_t* __restrict__ q_bf,
    ushort_t* __restrict__ knT_bf, ushort_t* __restrict__ kn_bf)
{
  __shared__ float Am[32][33];
  __shared__ float Tm[32][36];
  __shared__ ushort_t KT_hi[256][40];
  __shared__ ushort_t KT_lo[256][40];
  int t = threadIdx.x;
  int cc = blockIdx.x & 63, bh = blockIdx.x >> 6;
  size_t gbase = ((size_t)bh * Ls + cc * 32) * 256;
  int wv = t >> 6, lane = t & 63;
  int l16 = lane & 15, quad = lane >> 4;
  int mi = wv >> 1, ni = wv & 1;

  floatx4 Aacc = {0.f,0.f,0.f,0.f}, Qacc = {0.f,0.f,0.f,0.f};
  {
    int mrow = mi * 16 + l16, nrow = ni * 16 + l16;
    const float* kbp = kb + gbase + (size_t)mrow * 256;
    const float* qnp = qn + gbase + (size_t)mrow * 256;
    const float* knp = kn + gbase + (size_t)nrow * 256;
#pragma unroll
    for (int ks = 0; ks < 8; ++ks) {
      int koff = ks * 32 + quad * 8;
      short8 kbh, kbl, qnh, qnl, knh, knl;
      cvt8(*(const float4*)(kbp + koff), *(const float4*)(kbp + koff + 4), kbh, kbl);
      cvt8(*(const float4*)(qnp + koff), *(const float4*)(qnp + koff + 4), qnh, qnl);
      cvt8(*(const float4*)(knp + koff), *(const float4*)(knp + koff + 4), knh, knl);
      Aacc = __builtin_amdgcn_mfma_f32_16x16x32_bf16(kbh, knh, Aacc, 0, 0, 0);
      Aacc = __builtin_amdgcn_mfma_f32_16x16x32_bf16(kbh, knl, Aacc, 0, 0, 0);
      Aacc = __builtin_amdgcn_mfma_f32_16x16x32_bf16(kbl, knh, Aacc, 0, 0, 0);
      Qacc = __builtin_amdgcn_mfma_f32_16x16x32_bf16(qnh, knh, Qacc, 0, 0, 0);
      Qacc = __builtin_amdgcn_mfma_f32_16x16x32_bf16(qnh, knl, Qacc, 0, 0, 0);
      Qacc = __builtin_amdgcn_mfma_f32_16x16x32_bf16(qnl, knh, Qacc, 0, 0, 0);
      if (ni == 0)
        *(uint4*)(q_bf + gbase + (size_t)mrow * 256 + koff) = *(uint4*)&qnh;
      if (mi == 0)
        *(uint4*)(kn_bf + gbase + (size_t)nrow * 256 + koff) = *(uint4*)&knh;
    }
  }
  float* ag = attn_g + ((size_t)bh * 64 + cc) * 1024;
#pragma unroll
  for (int r = 0; r < 4; ++r) {
    int row = mi * 16 + quad * 4 + r, col = ni * 16 + l16;
    Am[row][col] = (col < row) ? Aacc[r] : 0.f;
    ag[row * 32 + col] = (col <= row) ? Qacc[r] : 0.f;
  }
  __syncthreads();

  if (wv == 0) {
    if (t < 32) {
#pragma unroll
      for (int i = 0; i < 32; ++i) Tm[i][t] = (i == t) ? 1.f : 0.f;
      for (int i2 = 1; i2 < 32; ++i2) {
        if (t < i2) {
          float s = 0.f;
          for (int m2 = t; m2 < i2; ++m2) s = fmaf(Am[i2][m2], Tm[m2][t], s);
          Tm[i2][t] = -s;
        }
      }
    }
  } else {
    int base = t - 64;
#pragma unroll
    for (int pass = 0; pass < 2; ++pass) {
      int d = base + pass * 192;
      if (d < 256) {
        u32 hp[16], lp[16], kp2[16];
#pragma unroll
        for (int m2 = 0; m2 < 16; ++m2) {
          float f0 = kb[gbase + (size_t)(2 * m2) * 256 + d];
          float f1 = kb[gbase + (size_t)(2 * m2 + 1) * 256 + d];
          ushort_t h0 = f2bf(f0), h1 = f2bf(f1);
          hp[m2] = (u32)h0 | ((u32)h1 << 16);
          lp[m2] = (u32)f2bf(f0 - bf2f(h0)) | ((u32)f2bf(f1 - bf2f(h1)) << 16);
          float g0 = kn[gbase + (size_t)(2 * m2) * 256 + d];
          float g1 = kn[gbase + (size_t)(2 * m2 + 1) * 256 + d];
          kp2[m2] = (u32)f2bf(g0) | ((u32)f2bf(g1) << 16);
        }
#pragma unroll
        for (int q2 = 0; q2 < 4; ++q2) {
          *(uint4*)&KT_hi[d][q2 * 8] = *(uint4*)&hp[q2 * 4];
          *(uint4*)&KT_lo[d][q2 * 8] = *(uint4*)&lp[q2 * 4];
          *(uint4*)(knT_bf + gbase + (size_t)d * 32 + q2 * 8) = *(uint4*)&kp2[q2 * 4];
        }
      }
    }
  }
  __syncthreads();

  int lt = wv & 1, dgrp = wv >> 1;
  short8 Th, Tl;
  {
    int lrow = lt * 16 + l16;
    cvt8(*(const float4*)&Tm[lrow][quad * 8],
         *(const float4*)&Tm[lrow][quad * 8 + 4], Th, Tl);
  }
#pragma unroll
  for (int j = 0; j < 8; ++j) {
    int dt = dgrp * 8 + j;
    short8 Bh = *(const short8*)&KT_hi[dt * 16 + l16][quad * 8];
    short8 Bl = *(const short8*)&KT_lo[dt * 16 + l16][quad * 8];
    floatx4 acc = {0.f,0.f,0.f,0.f};
    acc = __builtin_amdgcn_mfma_f32_16x16x32_bf16(Th, Bh, acc, 0, 0, 0);
    acc = __builtin_amdgcn_mfma_f32_16x16x32_bf16(Th, Bl, acc, 0, 0, 0);
    acc = __builtin_amdgcn_mfma_f32_16x16x32_bf16(Tl, Bh, acc, 0, 0, 0);
#pragma unroll
    for (int r = 0; r < 4; ++r) {
      int row = lt * 16 + quad * 4 + r;
      wn_bf[gbase + (size_t)row * 256 + dt * 16 + l16] = f2bf(-acc[r]);
    }
  }
  __syncthreads();

  {
    int d = t;
    u32 hp[16], lp[16];
#pragma unroll
    for (int m2 = 0; m2 < 16; ++m2) {
      float f0 = vb[gbase + (size_t)(2 * m2) * 256 + d];
      float f1 = vb[gbase + (size_t)(2 * m2 + 1) * 256 + d];
      ushort_t h0 = f2bf(f0), h1 = f2bf(f1);
      hp[m2] = (u32)h0 | ((u32)h1 << 16);
      lp[m2] = (u32)f2bf(f0 - bf2f(h0)) | ((u32)f2bf(f1 - bf2f(h1)) << 16);
    }
#pragma unroll
    for (int q2 = 0; q2 < 4; ++q2) {
      *(uint4*)&KT_hi[d][q2 * 8] = *(uint4*)&hp[q2 * 4];
      *(uint4*)&KT_lo[d][q2 * 8] = *(uint4*)&lp[q2 * 4];
    }
  }
  __syncthreads();

#pragma unroll
  for (int j = 0; j < 8; ++j) {
    int dt = dgrp * 8 + j;
    short8 Bh = *(const short8*)&KT_hi[dt * 16 + l16][quad * 8];
    short8 Bl = *(const short8*)&KT_lo[dt * 16 + l16][quad * 8];
    floatx4 acc = {0.f,0.f,0.f,0.f};
    acc = __builtin_amdgcn_mfma_f32_16x16x32_bf16(Th, Bh, acc, 0, 0, 0);
    acc = __builtin_amdgcn_mfma_f32_16x16x32_bf16(Th, Bl, acc, 0, 0, 0);
    acc = __builtin_amdgcn_mfma_f32_16x16x32_bf16(Tl, Bh, acc, 0, 0, 0);
#pragma unroll
    for (int r = 0; r < 4; ++r) {
      int row = lt * 16 + quad * 4 + r;
      u_out[gbase + (size_t)row * 256 + dt * 16 + l16] = acc[r];
    }
  }
}

// ------- cross matrices per super-chunk: X = wn1 @ kn0^T, Y = q1 @ kn0^T ---
__global__ __launch_bounds__(256) void cross_prep(
    const ushort_t* __restrict__ wn_bf, const ushort_t* __restrict__ q_bf,
    const ushort_t* __restrict__ kn_bf,
    float* __restrict__ X_g, float* __restrict__ Y_g)
{
  int t = threadIdx.x;
  int sc = blockIdx.x & 31, bh = blockIdx.x >> 5;
  int wv = t >> 6, lane = t & 63;
  int l16 = lane & 15, quad = lane >> 4;
  int mi = wv >> 1, ni = wv & 1;
  size_t base = (size_t)bh * Ls * 256;
  size_t r1 = base + (size_t)(sc * 64 + 32 + mi * 16 + l16) * 256;  // chunk 2sc+1 rows
  size_t r0 = base + (size_t)(sc * 64 + ni * 16 + l16) * 256;       // chunk 2sc rows
  floatx4 Xacc = {0.f,0.f,0.f,0.f}, Yacc = {0.f,0.f,0.f,0.f};
#pragma unroll
  for (int ks = 0; ks < 8; ++ks) {
    int ko = ks * 32 + quad * 8;
    short8 aw = *(const short8*)(wn_bf + r1 + ko);
    short8 aq = *(const short8*)(q_bf  + r1 + ko);
    short8 bk = *(const short8*)(kn_bf + r0 + ko);
    Xacc = __builtin_amdgcn_mfma_f32_16x16x32_bf16(aw, bk, Xacc, 0, 0, 0);
    Yacc = __builtin_amdgcn_mfma_f32_16x16x32_bf16(aq, bk, Yacc, 0, 0, 0);
  }
  float* xo = X_g + ((size_t)bh * 32 + sc) * 1024;
  float* yo = Y_g + ((size_t)bh * 32 + sc) * 1024;
#pragma unroll
  for (int r = 0; r < 4; ++r) {
    int row = mi * 16 + quad * 4 + r, col = ni * 16 + l16;
    xo[row * 32 + col] = Xacc[r];
    yo[row * 32 + col] = Yacc[r];
  }
}

// ------- merged: MFMA serial scan (blocks 0-127) + FIR conv (blocks 128+) --
__global__ __launch_bounds__(256, 1) void delta_fir(
    const ushort_t* __restrict__ wn_bf, const ushort_t* __restrict__ q_bf,
    const ushort_t* __restrict__ knT_bf, const float* __restrict__ attn_g,
    const float* __restrict__ u_g, const float* __restrict__ X_g,
    const float* __restrict__ Y_g, float* __restrict__ delta_g,
    const float* __restrict__ v, const float* __restrict__ wlg,
    const float* __restrict__ wsg, float* __restrict__ firl,
    float* __restrict__ firs)
{
  __shared__ __attribute__((aligned(16))) char smem[72704];
  int t = threadIdx.x;

  if (blockIdx.x >= 128) {
    // ---------------- FIR part ----------------
    float (*vt)[71] = (float(*)[71])smem;
    int bid = blockIdx.x - 128;
    int lt = bid & 255;
    int bh = bid >> 8;
    int b = bh >> 2, h = bh & 3;
    int l0 = lt * 8;
    const float* vp = v + (size_t)bh * Ls * 256;
    for (int r = 0; r < 70; ++r) {
      int ls = l0 - 62 + r;
      vt[t][r] = (ls >= 0) ? vp[(size_t)ls * 256 + t] : 0.f;
    }
    float TL[63], TS3[3];
#pragma unroll
    for (int j = 0; j < 63; ++j) TL[j] = wlg[((size_t)h * 256 + t) * 63 + j];
#pragma unroll
    for (int j = 0; j < 3; ++j) TS3[j] = wsg[((size_t)h * 256 + t) * 3 + j];
    __syncthreads();
    float aL[8] = {0,0,0,0,0,0,0,0}, aS[8] = {0,0,0,0,0,0,0,0};
#pragma unroll
    for (int r = 0; r < 70; ++r) {
      float vm = vt[t][r];
#pragma unroll
      for (int p = 0; p < 8; ++p) {
        int jl = r - p;
        if (jl >= 0 && jl < 63) aL[p] = fmaf(vm, TL[jl], aL[p]);
        int jssrc = r - 60 - p;
        if (jssrc >= 0 && jssrc < 3) aS[p] = fmaf(vm, TS3[jssrc], aS[p]);
      }
    }
#pragma unroll
    for (int p = 0; p < 8; ++p) {
      int l = l0 + p;
      size_t ob = (((size_t)b * Ls + l) * NH + h) * 256 + t;
      firl[ob] = aL[p];
      firs[ob] = aS[p];
    }
    return;
  }

  // ---------------- chain part (m=2 super-chunks) ----------------
  ushort_t (*Shi)[264] = (ushort_t(*)[264])(smem);
  ushort_t (*Slo)[264] = (ushort_t(*)[264])(smem + 8448);
  float (*u2L0)[17] = (float(*)[17])(smem + 16896);
  float (*u2L1)[17] = (float(*)[17])(smem + 19072);
  int bh = blockIdx.x & 7, g = blockIdx.x >> 3;
  int b = bh >> 2, h = bh & 3;
  int wv = t >> 6, lane = t & 63;
  int lquad = lane >> 4, l16 = lane & 15;
  int j0 = g * 16;
  int Mt = wv & 1;
  bool isU = (wv < 2);
  const ushort_t* wp = wn_bf + (size_t)bh * Ls * 256;
  const ushort_t* qp = q_bf  + (size_t)bh * Ls * 256;
  const ushort_t* ap = (isU ? wp : qp) + (size_t)(Mt * 16 + l16) * 256;
  const ushort_t* kr = knT_bf + (size_t)bh * Ls * 256 + (size_t)l16 * 32 + lquad * 8;
  const float* urow = u_g + (size_t)bh * Ls * 256
                    + (size_t)(Mt * 16 + lquad * 4) * 256 + j0 + l16;
  const float* arp = attn_g + (size_t)bh * 64 * 1024
                   + (size_t)(Mt * 16 + l16) * 32 + lquad * 8;
  const float* xrp = (isU ? X_g : Y_g) + (size_t)bh * 32768
                   + (size_t)(Mt * 16 + l16) * 32 + lquad * 8;

  floatx4 Sacc[4], SaccL[4];
#pragma unroll
  for (int i = 0; i < 4; ++i)
#pragma unroll
    for (int r = 0; r < 4; ++r) { Sacc[i][r] = 0.f; SaccL[i][r] = 0.f; }
  for (int i = t; i < 4224; i += 256) ((u32*)smem)[i] = 0;

  // prologue: super-chunk 0, sub-chunk 0 operands
  short8 a0[8], k0[4];
  floatx4 u0 = {0.f, 0.f, 0.f, 0.f};
  float4 at0a = {0,0,0,0}, at0b = {0,0,0,0};
#pragma unroll
  for (int ks = 0; ks < 8; ++ks)
    a0[ks] = *(const short8*)(ap + ks * 32 + lquad * 8);
#pragma unroll
  for (int i = 0; i < 4; ++i)
    k0[i] = *(const short8*)(kr + (size_t)(wv * 4 + i) * 512);
  if (isU) {
#pragma unroll
    for (int r = 0; r < 4; ++r) u0[r] = urow[(size_t)r * 256];
  } else {
    at0a = *(const float4*)(arp);
    at0b = *(const float4*)(arp + 4);
  }
  wave_barrier();

  for (int sc = 0; sc < 32; ++sc) {
    size_t cb1 = (size_t)sc * 16384 + 8192;
    size_t nb0 = (size_t)(sc + 1) * 16384;
    bool hasN = (sc + 1 < 32);

    // sub-chunk1 operands + cross matrix (used mid-iteration; latency covered)
    short8 a1[8], k1[4];
    floatx4 u1 = {0.f, 0.f, 0.f, 0.f};
    float4 at1a = {0,0,0,0}, at1b = {0,0,0,0};
#pragma unroll
    for (int ks = 0; ks < 8; ++ks)
      a1[ks] = *(const short8*)(ap + cb1 + ks * 32 + lquad * 8);
#pragma unroll
    for (int i = 0; i < 4; ++i)
      k1[i] = *(const short8*)(kr + cb1 + (size_t)(wv * 4 + i) * 512);
    if (isU) {
#pragma unroll
      for (int r = 0; r < 4; ++r) u1[r] = urow[cb1 + (size_t)r * 256];
    } else {
      size_t na = (size_t)(2 * sc + 1) * 1024;
      at1a = *(const float4*)(arp + na);
      at1b = *(const float4*)(arp + na + 4);
    }
    float4 xa = *(const float4*)(xrp + (size_t)sc * 1024);
    float4 xb = *(const float4*)(xrp + (size_t)sc * 1024 + 4);

    // ---- sub-chunk 0: u2_0 (isU) / po_0 (o) against S0 ----
    floatx4 acc0;
    if (isU) {
      floatx4 A0 = u0, A1 = {0,0,0,0}, A2 = {0,0,0,0}, A3 = {0,0,0,0};
#pragma unroll
      for (int ks = 0; ks < 8; ++ks) {
        short8 sh = *(const short8*)&Shi[l16][ks * 32 + lquad * 8];
        short8 sl = *(const short8*)&Slo[l16][ks * 32 + lquad * 8];
        if (ks & 1) {
          A1 = __builtin_amdgcn_mfma_f32_16x16x32_bf16(a0[ks], sh, A1, 0, 0, 0);
          A3 = __builtin_amdgcn_mfma_f32_16x16x32_bf16(a0[ks], sl, A3, 0, 0, 0);
        } else {
          A0 = __builtin_amdgcn_mfma_f32_16x16x32_bf16(a0[ks], sh, A0, 0, 0, 0);
          A2 = __builtin_amdgcn_mfma_f32_16x16x32_bf16(a0[ks], sl, A2, 0, 0, 0);
        }
      }
#pragma unroll
      for (int r = 0; r < 4; ++r) acc0[r] = (A0[r] + A1[r]) + (A2[r] + A3[r]);
#pragma unroll
      for (int r = 0; r < 4; ++r)
        u2L0[Mt * 16 + lquad * 4 + r][l16] = acc0[r];
    } else {
      floatx4 A0 = {0,0,0,0}, A1 = {0,0,0,0};
#pragma unroll
      for (int ks = 0; ks < 8; ++ks) {
        short8 sh = *(const short8*)&Shi[l16][ks * 32 + lquad * 8];
        if (ks & 1) A1 = __builtin_amdgcn_mfma_f32_16x16x32_bf16(a0[ks], sh, A1, 0, 0, 0);
        else        A0 = __builtin_amdgcn_mfma_f32_16x16x32_bf16(a0[ks], sh, A0, 0, 0, 0);
      }
#pragma unroll
      for (int r = 0; r < 4; ++r) acc0[r] = A0[r] + A1[r];
    }
    // prefetch next-super-chunk a0 (a0 regs dead; stays in flight across
    // the raw barriers below -> ~full iteration of latency cover)
    if (hasN) {
#pragma unroll
      for (int ks = 0; ks < 8; ++ks)
        a0[ks] = *(const short8*)(ap + nb0 + ks * 32 + lquad * 8);
    }
    wave_barrier();                          // u2_0 visible

    short8 uh0, ul0;
#pragma unroll
    for (int j = 0; j < 8; ++j) {
      float f = u2L0[lquad * 8 + j][l16];
      ushort_t hi = f2bf(f);
      uh0[j] = (short)hi;
      ul0[j] = (short)f2bf(f - bf2f(hi));
    }
#pragma unroll
    for (int i = 0; i < 4; ++i) {
      Sacc[i]  = __builtin_amdgcn_mfma_f32_16x16x32_bf16(k0[i], uh0, Sacc[i], 0, 0, 0);
      SaccL[i] = __builtin_amdgcn_mfma_f32_16x16x32_bf16(k0[i], ul0, SaccL[i], 0, 0, 0);
    }
    if (hasN) {
#pragma unroll
      for (int i = 0; i < 4; ++i)
        k0[i] = *(const short8*)(kr + nb0 + (size_t)(wv * 4 + i) * 512);
    }

    // ---- sub-chunk 1: u2_1 = u1 + wn1@S0 + X@u2_0 / o path ----
    floatx4 acc1;
    if (isU) {
      floatx4 A0 = u1, A1 = {0,0,0,0}, A2 = {0,0,0,0}, A3 = {0,0,0,0};
#pragma unroll
      for (int ks = 0; ks < 8; ++ks) {
        short8 sh = *(const short8*)&Shi[l16][ks * 32 + lquad * 8];
        short8 sl = *(const short8*)&Slo[l16][ks * 32 + lquad * 8];
        if (ks & 1) {
          A1 = __builtin_amdgcn_mfma_f32_16x16x32_bf16(a1[ks], sh, A1, 0, 0, 0);
          A3 = __builtin_amdgcn_mfma_f32_16x16x32_bf16(a1[ks], sl, A3, 0, 0, 0);
        } else {
          A0 = __builtin_amdgcn_mfma_f32_16x16x32_bf16(a1[ks], sh, A0, 0, 0, 0);
          A2 = __builtin_amdgcn_mfma_f32_16x16x32_bf16(a1[ks], sl, A2, 0, 0, 0);
        }
      }
      short8 Xh, Xl;
      cvt8(xa, xb, Xh, Xl);
      A0 = __builtin_amdgcn_mfma_f32_16x16x32_bf16(Xh, uh0, A0, 0, 0, 0);
      A1 = __builtin_amdgcn_mfma_f32_16x16x32_bf16(Xh, ul0, A1, 0, 0, 0);
      A2 = __builtin_amdgcn_mfma_f32_16x16x32_bf16(Xl, uh0, A2, 0, 0, 0);
#pragma unroll
      for (int r = 0; r < 4; ++r) acc1[r] = (A0[r] + A1[r]) + (A2[r] + A3[r]);
#pragma unroll
      for (int r = 0; r < 4; ++r)
        u2L1[Mt * 16 + lquad * 4 + r][l16] = acc1[r];
      if (hasN) {
#pragma unroll
        for (int r = 0; r < 4; ++r) u0[r] = urow[nb0 + (size_t)r * 256];
      }
    } else {
      // o_0 = po_0 + attn_0 @ u2_0 -> store
      short8 ath, atl;
      cvt8(at0a, at0b, ath, atl);
      acc0 = __builtin_amdgcn_mfma_f32_16x16x32_bf16(ath, uh0, acc0, 0, 0, 0);
      acc0 = __builtin_amdgcn_mfma_f32_16x16x32_bf16(ath, ul0, acc0, 0, 0, 0);
      acc0 = __builtin_amdgcn_mfma_f32_16x16x32_bf16(atl, uh0, acc0, 0, 0, 0);
#pragma unroll
      for (int r = 0; r < 4; ++r) {
        int l = sc * 64 + Mt * 16 + lquad * 4 + r;
        delta_g[(((size_t)b * Ls + l) * NH + h) * 256 + j0 + l16] = acc0[r];
      }
      // po_1 = q1 @ Shi(S0) + Y @ u2_0
      floatx4 A0 = {0,0,0,0}, A1 = {0,0,0,0};
#pragma unroll
      for (int ks = 0; ks < 8; ++ks) {
        short8 sh = *(const short8*)&Shi[l16][ks * 32 + lquad * 8];
        if (ks & 1) A1 = __builtin_amdgcn_mfma_f32_16x16x32_bf16(a1[ks], sh, A1, 0, 0, 0);
        else        A0 = __builtin_amdgcn_mfma_f32_16x16x32_bf16(a1[ks], sh, A0, 0, 0, 0);
      }
      short8 Yh, Yl;
      cvt8(xa, xb, Yh, Yl);
      A0 = __builtin_amdgcn_mfma_f32_16x16x32_bf16(Yh, uh0, A0, 0, 0, 0);
      A1 = __builtin_amdgcn_mfma_f32_16x16x32_bf16(Yh, ul0, A1, 0, 0, 0);
      A0 = __builtin_amdgcn_mfma_f32_16x16x32_bf16(Yl, uh0, A0, 0, 0, 0);
#pragma unroll
      for (int r = 0; r < 4; ++r) acc1[r] = A0[r] + A1[r];
      if (hasN) {
        size_t na0 = (size_t)(2 * sc + 2) * 1024;
        at0a = *(const float4*)(arp + na0);
        at0b = *(const float4*)(arp + na0 + 4);
      }
    }
    wave_barrier();                          // u2_1 visible; all Shi/Slo reads done

    short8 uh1, ul1;
#pragma unroll
    for (int j = 0; j < 8; ++j) {
      float f = u2L1[lquad * 8 + j][l16];
      ushort_t hi = f2bf(f);
      uh1[j] = (short)hi;
      ul1[j] = (short)f2bf(f - bf2f(hi));
    }
#pragma unroll
    for (int i = 0; i < 4; ++i) {
      Sacc[i]  = __builtin_amdgcn_mfma_f32_16x16x32_bf16(k1[i], uh1, Sacc[i], 0, 0, 0);
      SaccL[i] = __builtin_amdgcn_mfma_f32_16x16x32_bf16(k1[i], ul1, SaccL[i], 0, 0, 0);
    }
    if (!isU) {
      short8 ath, atl;
      cvt8(at1a, at1b, ath, atl);
      acc1 = __builtin_amdgcn_mfma_f32_16x16x32_bf16(ath, uh1, acc1, 0, 0, 0);
      acc1 = __builtin_amdgcn_mfma_f32_16x16x32_bf16(ath, ul1, acc1, 0, 0, 0);
      acc1 = __builtin_amdgcn_mfma_f32_16x16x32_bf16(atl, uh1, acc1, 0, 0, 0);
#pragma unroll
      for (int r = 0; r < 4; ++r) {
        int l = sc * 64 + 32 + Mt * 16 + lquad * 4 + r;
        delta_g[(((size_t)b * Ls + l) * NH + h) * 256 + j0 + l16] = acc1[r];
      }
    }
    // S write-back (once per 64 tokens)
#pragma unroll
    for (int i = 0; i < 4; ++i) {
      int dk0 = (wv * 4 + i) * 16 + lquad * 4;
      ushort4 h4, l4;
      ushort_t* hp = (ushort_t*)&h4;
      ushort_t* lp = (ushort_t*)&l4;
#pragma unroll
      for (int r = 0; r < 4; ++r) {
        float sv = Sacc[i][r] + SaccL[i][r];
        ushort_t hi = f2bf(sv);
        hp[r] = hi;
        lp[r] = f2bf(sv - bf2f(hi));
      }
      *(ushort4*)&Shi[l16][dk0] = h4;
      *(ushort4*)&Slo[l16][dk0] = l4;
    }
    wave_barrier();                          // S visible
  }
}

// ------- gate_in (bf16) ----------------------------------------------------
__global__ __launch_bounds__(256) void build_gate_in_bf(
    const float* __restrict__ x, const float* __restrict__ firs,
    const float* __restrict__ firl, const float* __restrict__ delta,
    const float* __restrict__ v, ushort_t* __restrict__ gin)
{
  int mtok = blockIdx.x, t = threadIdx.x;
  int b = mtok >> 11, l = mtok & 2047;
  float4 xv = *(const float4*)(x + (size_t)mtok * 1024 + t * 4);
  ushort4 xo = make_ushort4(f2bf(xv.x), f2bf(xv.y), f2bf(xv.z), f2bf(xv.w));
  *(ushort4*)(gin + (size_t)mtok * 1056 + t * 4) = xo;
  int w = t >> 6, lane = t & 63;
  for (int br = 0; br < 4; ++br) {
    float s = 0.f, s2 = 0.f;
#pragma unroll
    for (int r = 0; r < 4; ++r) {
      int d = lane + r * 64;
      float val;
      if (br == 0)      val = firs [(size_t)mtok * 1024 + w * 256 + d];
      else if (br == 1) val = firl [(size_t)mtok * 1024 + w * 256 + d];
      else if (br == 2) val = delta[(size_t)mtok * 1024 + w * 256 + d];
      else              val = v[(((size_t)(b * NH + w)) * Ls + l) * 256 + d];
      s += val; s2 = fmaf(val, val, s2);
    }
#pragma unroll
    for (int off = 32; off; off >>= 1) {
      s += __shfl_down(s, off);
      s2 += __shfl_down(s2, off);
    }
    if (lane == 0) {
      float mean = s * (1.f / 256.f);
      float var = s2 * (1.f / 256.f) - mean * mean;
      gin[(size_t)mtok * 1056 + 1024 + br * 8 + w] = f2bf(mean);
      gin[(size_t)mtok * 1056 + 1024 + br * 8 + 4 + w] = f2bf(sqrtf(fmaxf(var, 1e-6f)));
    }
  }
}

// ------- logits -> gates (bf16 hidden input) -------------------------------
__global__ __launch_bounds__(256) void mlp2_gates(
    const ushort_t* __restrict__ mh, const float* __restrict__ W2,
    const float* __restrict__ b2, const float* __restrict__ glt,
    float* __restrict__ gates)
{
  int mtok = blockIdx.x, t = threadIdx.x;
  float p[16];
#pragma unroll
  for (int j = 0; j < 16; ++j) p[j] = 0.f;
  for (int k = t; k < 2048; k += 256) {
    float hv = bf2f(mh[(size_t)mtok * 2048 + k]);
    const float* wr = W2 + (size_t)k * 16;
#pragma unroll
    for (int j4 = 0; j4 < 4; ++j4) {
      float4 w4 = *(const float4*)(wr + j4 * 4);
      p[j4*4+0] = fmaf(hv, w4.x, p[j4*4+0]);
      p[j4*4+1] = fmaf(hv, w4.y, p[j4*4+1]);
      p[j4*4+2] = fmaf(hv, w4.z, p[j4*4+2]);
      p[j4*4+3] = fmaf(hv, w4.w, p[j4*4+3]);
    }
  }
#pragma unroll
  for (int j = 0; j < 16; ++j)
#pragma unroll
    for (int off = 32; off; off >>= 1) p[j] += __shfl_down(p[j], off);
  __shared__ float red[4][16];
  __shared__ float zl[16];
  int w = t >> 6;
  if ((t & 63) == 0) {
#pragma unroll
    for (int j = 0; j < 16; ++j) red[w][j] = p[j];
  }
  __syncthreads();
  if (t < 16) {
    float tot = red[0][t] + red[1][t] + red[2][t] + red[3][t] + b2[t];
    float tempv = log1pf(expf(glt[t >> 2])) + 1e-4f;
    zl[t] = tot / tempv;
  }
  __syncthreads();
  if (t < 4) {
    float z0 = zl[t*4], z1 = zl[t*4+1], z2 = zl[t*4+2], z3 = zl[t*4+3];
    float mx = fmaxf(fmaxf(z0, z1), fmaxf(z2, z3));
    float e0 = expf(z0 - mx), e1 = expf(z1 - mx), e2 = expf(z2 - mx), e3 = expf(z3 - mx);
    float inv = 1.f / (e0 + e1 + e2 + e3);
    gates[(size_t)mtok * 16 + t * 4 + 0] = e0 * inv;
    gates[(size_t)mtok * 16 + t * 4 + 1] = e1 * inv;
    gates[(size_t)mtok * 16 + t * 4 + 2] = e2 * inv;
    gates[(size_t)mtok * 16 + t * 4 + 3] = e3 * inv;
  }
}

// ------- o = gated mix, RMSNorm -> bf16 ------------------------------------
__global__ __launch_bounds__(256) void combine_norm_bf(
    const float* __restrict__ firs, const float* __restrict__ firl,
    const float* __restrict__ delta, const float* __restrict__ v,
    const float* __restrict__ gates, const float* __restrict__ onw,
    ushort_t* __restrict__ o)
{
  int mh = blockIdx.x;
  int mtok = mh >> 2, h = mh & 3;
  int t = threadIdx.x;
  int b = mtok >> 11, l = mtok & 2047;
  const float* g = gates + (size_t)mtok * 16 + h * 4;
  float w0 = g[0], w1 = g[1], w2 = g[2], w3 = g[3];
  size_t tb = (size_t)mtok * 1024 + h * 256 + t;
  float val = w0 * firs[tb] + w1 * firl[tb] + w2 * delta[tb]
            + w3 * v[(((size_t)(b * NH + h)) * Ls + l) * 256 + t];
  float s2 = val * val;
#pragma unroll
  for (int off = 32; off; off >>= 1) s2 += __shfl_down(s2, off);
  __shared__ float r4[4];
  if ((t & 63) == 0) r4[t >> 6] = s2;
  __syncthreads();
  float tot = r4[0] + r4[1] + r4[2] + r4[3];
  float rms = rsqrtf(tot * (1.f / 256.f) + 1e-5f);
  o[tb] = f2bf(val * rms * onw[t]);
}

// ---------------------------------------------------------------------------
extern "C" void kernel_launch(void* const* d_in, const int* in_sizes, int n_in,
                              void* d_out, int out_size, void* d_ws, size_t ws_size,
                              hipStream_t stream) {
  const float* x     = (const float*)d_in[0];
  const float* Wq    = (const float*)d_in[1];
  const float* Wk    = (const float*)d_in[2];
  const float* Wv    = (const float*)d_in[3];
  const float* Wb    = (const float*)d_in[4];
  const float* convq = (const float*)d_in[5];
  const float* convk = (const float*)d_in[6];
  const float* convv = (const float*)d_in[7];
  const float* firsw = (const float*)d_in[8];
  const float* firlw = (const float*)d_in[9];
  const float* mlpw1 = (const float*)d_in[10];
  const float* mlpb1 = (const float*)d_in[11];
  const float* mlpw2 = (const float*)d_in[12];
  const float* mlpb2 = (const float*)d_in[13];
  const float* glt   = (const float*)d_in[14];
  const float* onw   = (const float*)d_in[15];
  const float* Wo    = (const float*)d_in[16];
  float* ws = (float*)d_ws;

  ushort_t* x_bf   = (ushort_t*)(ws + off_firs);
  ushort_t* Wqkv_t = (ushort_t*)(ws + off_firl);  // 3 x [1024][1024] contiguous
  ushort_t* gin_bf = (ushort_t*)(ws + off_gin);
  ushort_t* w1_t   = (ushort_t*)(ws + off_k);     // kn dead after chunk_prep
  ushort_t* o_bf   = (ushort_t*)(ws + off_xv);
  ushort_t* Wo_t   = (ushort_t*)(ws + off_beta);  // spans into attn (dead)
  ushort_t* mlph_bf= (ushort_t*)(ws + off_mlph);
  ushort_t* wn_bf  = (ushort_t*)(ws + off_firs);
  ushort_t* q_bf   = (ushort_t*)(ws + off_firs + 2097152);
  ushort_t* knT_bf = (ushort_t*)(ws + off_firl);
  ushort_t* kn_bf  = (ushort_t*)(ws + off_xq);    // x3 dead after conv_prep
  float* x3   = ws + off_xq;     // fused [4096][3072] spans xq/xk/xv
  float* kb_f = ws + off_gin;
  float* vb_f = ws + off_mlph;
  float* X_g  = ws + off_gin;            // kb dead after chunk_prep; 8*32*1024 f32
  float* Y_g  = ws + off_gin + 262144;
  float* firs_f = ws + off_xq;   // x3/kn_bf dead after cross_prep
  float* firl_f = ws + off_xk;

  dim3 blk(256);
  // fused q/k/v projection (one N=3072 GEMM) + beta
  to_bf16<<<2048, blk, 0, stream>>>(x, x_bf, 4194304);
  convT<<<dim3(32, 32), blk, 0, stream>>>(Wq, Wqkv_t, 1024, 1024);
  convT<<<dim3(32, 32), blk, 0, stream>>>(Wk, Wqkv_t + 1048576, 1024, 1024);
  convT<<<dim3(32, 32), blk, 0, stream>>>(Wv, Wqkv_t + 2097152, 1024, 1024);
  gemm_bf16<<<dim3(24, 32), blk, 0, stream>>>(x_bf, Wqkv_t, x3, 3072, 1024, nullptr, 0, 0);
  beta_sigmoid<<<4096, blk, 0, stream>>>(x, Wb, ws + off_beta);
  // fused conv4+silu + l2norm + beta products
  conv_prep<<<16384, blk, 0, stream>>>(x3, convq, convk, convv, ws + off_beta,
                                       ws + off_q, ws + off_k, kb_f, vb_f, ws + off_v);
  // per-chunk T inverse, attn, u (->xv), bf16 {-w, q, knT, kn}
  chunk_prep<<<512, blk, 0, stream>>>(kb_f, ws + off_k, ws + off_q, vb_f,
                                      ws + off_attn, ws + off_xv, wn_bf, q_bf,
                                      knT_bf, kn_bf);
  // 32x32 cross matrices per super-chunk (X = wn1 kn0^T, Y = q1 kn0^T)
  cross_prep<<<256, blk, 0, stream>>>(wn_bf, q_bf, kn_bf, X_g, Y_g);
  // merged serial MFMA scan (delta -> off_q) + FIR (firs/firl -> x3 regions)
  delta_fir<<<2176, blk, 0, stream>>>(wn_bf, q_bf, knT_bf, ws + off_attn,
                                      ws + off_xv, X_g, Y_g, ws + off_q,
                                      ws + off_v, firlw, firsw, firl_f, firs_f);
  // gate input (bf16), MLP1 (MFMA, gelu, bf16 out), gates
  build_gate_in_bf<<<4096, blk, 0, stream>>>(x, firs_f, firl_f, ws + off_q,
                                             ws + off_v, gin_bf);
  convT<<<dim3(64, 33), blk, 0, stream>>>(mlpw1, w1_t, 1056, 2048);
  gemm_bf16<<<dim3(16, 32), blk, 0, stream>>>(gin_bf, w1_t, (float*)mlph_bf,
                                              2048, 1056, mlpb1, 1, 1);
  mlp2_gates<<<4096, blk, 0, stream>>>(mlph_bf, mlpw2, mlpb2, glt, ws + off_gates);
  // combine + RMSNorm -> bf16, output projection (MFMA)
  combine_norm_bf<<<16384, blk, 0, stream>>>(firs_f, firl_f, ws + off_q,
                                             ws + off_v, ws + off_gates, onw, o_bf);
  convT<<<dim3(32, 32), blk, 0, stream>>>(Wo, Wo_t, 1024, 1024);
  gemm_bf16<<<dim3(8, 32), blk, 0, stream>>>(o_bf, Wo_t, (float*)d_out, 1024, 1024, nullptr, 0, 0);
}

// Round 8
// 543.186 us; speedup vs baseline: 1.3494x; 1.0193x over previous
//
#include <hip/hip_runtime.h>
#include <hip/hip_bf16.h>

// ---------------------------------------------------------------------------
// DeltaNet forward, round 15:
//  - Base: r8 exactly (proven 546us best; gemm reverted to BK=32 after r14's
//    BK=64 came back neutral-to-worse).
//  - ONE change: the two input-only weight transposes (mlpw1 -> w1_t,
//    Wo -> Wo_t) are folded into delta_fir's grid as blocks 2176+ so they
//    run on the ~128 CUs that idle after the FIR blocks drain (the chain
//    occupies the other 128 CUs for ~146us). Zero math change.
//    Wo_t relocated from off_beta (overlaps live attn during the chain) to
//    the never-used [42614784,..) window; w1_t stays at off_k (kn dead).
// ---------------------------------------------------------------------------

#define DEVI __device__ __forceinline__
typedef unsigned int u32;
typedef unsigned short ushort_t;
typedef __attribute__((ext_vector_type(8))) short short8;
typedef __attribute__((ext_vector_type(4))) float floatx4;

constexpr int Ls = 2048, NH = 4;

// workspace offsets (floats)
constexpr size_t off_xq   = 0;         // x3 [m][3072] cols 0-1023 -> kn_bf -> firs
constexpr size_t off_xk   = 4194304;   // x3 cols 1024-2047 -> firl
constexpr size_t off_xv   = 8388608;   // x3 cols 2048-3071 -> u -> o_bf
constexpr size_t off_q    = 12582912;  // qn -> delta
constexpr size_t off_k    = 16777216;  // kn (dead after chunk_prep) -> w1_t
constexpr size_t off_v    = 20971520;  // v (alive to the end)
constexpr size_t off_beta = 25165824;  // beta (dead after conv_prep)
constexpr size_t off_attn = 25182208;  // attn (read by chain)
constexpr size_t off_firs = 25706496;  // x_bf -> {wn_bf, q_bf} (bf16)
constexpr size_t off_firl = 29900800;  // Wqkv_t -> knT_bf (bf16)
constexpr size_t off_gin  = 34095104;  // kb (f32) -> {X_g, Y_g} -> gin_bf
constexpr size_t off_mlph = 38420480;  // vb (f32) -> mlph_bf
constexpr size_t off_wot  = 42614784;  // Wo_t (bf16, 0.52M fl) - never-aliased
constexpr size_t off_gates= 46809088;  // gates

DEVI float sigmoidf_(float x) { return 1.f / (1.f + expf(-x)); }
DEVI float siluf_(float x) { return x / (1.f + expf(-x)); }
DEVI float geluf_(float x) { return 0.5f * x * (1.f + erff(x * 0.7071067811865476f)); }
DEVI ushort_t f2bf(float f) {
  union { float f; u32 u; } c{f};
  u32 r = (c.u + 0x7fffu + ((c.u >> 16) & 1u)) >> 16;
  return (ushort_t)r;
}
DEVI float bf2f(ushort_t h) {
  union { u32 u; float f; } c; c.u = ((u32)h) << 16; return c.f;
}
DEVI void cvt8(float4 a, float4 b, short8& hi, short8& lo) {
  float f[8] = {a.x,a.y,a.z,a.w,b.x,b.y,b.z,b.w};
#pragma unroll
  for (int j = 0; j < 8; ++j) {
    ushort_t h = f2bf(f[j]);
    hi[j] = (short)h;
    lo[j] = (short)f2bf(f[j] - bf2f(h));
  }
}
DEVI void async16(const void* g, void* l) {
  __builtin_amdgcn_global_load_lds(
      (const u32 __attribute__((address_space(1)))*)g,
      (u32 __attribute__((address_space(3)))*)l, 16, 0, 0);
}
// Raw workgroup barrier: waits LDS ops only (lgkmcnt), leaves global
// loads/stores (vmcnt) in flight. All cross-wave deps in the chain loop are
// LDS-only, and global data has no in-kernel consumers.
DEVI void wave_barrier() {
  __builtin_amdgcn_sched_barrier(0);
  asm volatile("s_waitcnt lgkmcnt(0)" ::: "memory");
  __builtin_amdgcn_s_barrier();
  __builtin_amdgcn_sched_barrier(0);
}

// ---------------- f32 -> bf16 ----------------------------------------------
__global__ __launch_bounds__(256) void to_bf16(
    const float* __restrict__ in, ushort_t* __restrict__ out, int n)
{
  int i = (blockIdx.x * 256 + threadIdx.x) * 8;
  if (i >= n) return;
  float4 a = *(const float4*)(in + i);
  float4 b = *(const float4*)(in + i + 4);
  ushort_t o[8] = { f2bf(a.x), f2bf(a.y), f2bf(a.z), f2bf(a.w),
                    f2bf(b.x), f2bf(b.y), f2bf(b.z), f2bf(b.w) };
  *(uint4*)(out + i) = *(uint4*)o;
}

// ---------------- f32 [K][N] -> bf16 [N][K] --------------------------------
__global__ __launch_bounds__(256) void convT(
    const float* __restrict__ W, ushort_t* __restrict__ out, int Kq, int Nq)
{
  __shared__ ushort_t tile[32][33];
  int n0 = blockIdx.x * 32, k0 = blockIdx.y * 32;
  int tx = threadIdx.x & 31, ty = threadIdx.x >> 5;
#pragma unroll
  for (int r = 0; r < 32; r += 8)
    tile[ty + r][tx] = f2bf(W[(size_t)(k0 + ty + r) * Nq + n0 + tx]);
  __syncthreads();
#pragma unroll
  for (int r = 0; r < 32; r += 8)
    out[(size_t)(n0 + ty + r) * Kq + k0 + tx] = tile[tx][ty + r];
}

// ---------------- bf16 MFMA GEMM -------------------------------------------
__global__ __launch_bounds__(256) void gemm_bf16(
    const ushort_t* __restrict__ A, const ushort_t* __restrict__ Bt,
    float* __restrict__ C, int Nq, int Kq,
    const float* __restrict__ bias, int act, int outbf)
{
  __shared__ ushort_t As[128 * 32];
  __shared__ ushort_t Bs[128 * 32];
  int t = threadIdx.x;
  int w = t >> 6, lane = t & 63;
  int m0 = blockIdx.y * 128, n0 = blockIdx.x * 128;
  floatx4 acc[4][4];
#pragma unroll
  for (int i = 0; i < 4; ++i)
#pragma unroll
    for (int j = 0; j < 4; ++j)
#pragma unroll
      for (int r = 0; r < 4; ++r) acc[i][j][r] = 0.f;

  int lrow = lane >> 2, lk8 = (lane & 3) * 8;
  for (int kt = 0; kt < Kq; kt += 32) {
#pragma unroll
    for (int r = 0; r < 2; ++r) {
      int seg = w * 2 + r;
      int row = seg * 16 + lrow;
      async16(A  + (size_t)(m0 + row) * Kq + kt + lk8, &As[seg * 512]);
      async16(Bt + (size_t)(n0 + row) * Kq + kt + lk8, &Bs[seg * 512]);
    }
    __syncthreads();
    short8 af[4], bf[4];
#pragma unroll
    for (int i = 0; i < 4; ++i) {
      int row = (w >> 1) * 64 + i * 16 + (lane & 15);
      af[i] = *(const short8*)&As[row * 32 + (lane >> 4) * 8];
    }
#pragma unroll
    for (int j = 0; j < 4; ++j) {
      int col = (w & 1) * 64 + j * 16 + (lane & 15);
      bf[j] = *(const short8*)&Bs[col * 32 + (lane >> 4) * 8];
    }
#pragma unroll
    for (int i = 0; i < 4; ++i)
#pragma unroll
      for (int j = 0; j < 4; ++j)
        acc[i][j] = __builtin_amdgcn_mfma_f32_16x16x32_bf16(af[i], bf[j], acc[i][j], 0, 0, 0);
    __syncthreads();
  }
#pragma unroll
  for (int i = 0; i < 4; ++i) {
    int rbase = m0 + (w >> 1) * 64 + i * 16 + ((lane >> 4) << 2);
#pragma unroll
    for (int j = 0; j < 4; ++j) {
      int col = n0 + (w & 1) * 64 + j * 16 + (lane & 15);
      float bv = act ? bias[col] : 0.f;
#pragma unroll
      for (int r = 0; r < 4; ++r) {
        float v = acc[i][j][r];
        if (act) v = geluf_(v + bv);
        if (outbf) ((ushort_t*)C)[(size_t)(rbase + r) * Nq + col] = f2bf(v);
        else       C[(size_t)(rbase + r) * Nq + col] = v;
      }
    }
  }
}

// ---------------- beta = sigmoid(x @ Wb) -----------------------------------
__global__ __launch_bounds__(256) void beta_sigmoid(
    const float* __restrict__ x, const float* __restrict__ Wb,
    float* __restrict__ beta)
{
  int mtok = blockIdx.x, t = threadIdx.x;
  int b = mtok >> 11, l = mtok & 2047;
  float a0 = 0, a1 = 0, a2 = 0, a3 = 0;
  for (int k = t; k < 1024; k += 256) {
    float xv = x[(size_t)mtok * 1024 + k];
    float4 w4 = *(const float4*)(Wb + k * 4);
    a0 = fmaf(xv, w4.x, a0); a1 = fmaf(xv, w4.y, a1);
    a2 = fmaf(xv, w4.z, a2); a3 = fmaf(xv, w4.w, a3);
  }
#pragma unroll
  for (int off = 32; off; off >>= 1) {
    a0 += __shfl_down(a0, off); a1 += __shfl_down(a1, off);
    a2 += __shfl_down(a2, off); a3 += __shfl_down(a3, off);
  }
  __shared__ float red[4][4];
  int w = t >> 6;
  if ((t & 63) == 0) { red[w][0] = a0; red[w][1] = a1; red[w][2] = a2; red[w][3] = a3; }
  __syncthreads();
  if (t < 4) {
    float s = red[0][t] + red[1][t] + red[2][t] + red[3][t];
    beta[((size_t)(b * NH + t)) * Ls + l] = sigmoidf_(s);
  }
}

// ------- fused conv4+silu (from fused x3 [m][3072]) + l2norm + beta --------
__global__ __launch_bounds__(256) void conv_prep(
    const float* __restrict__ x3, const float* __restrict__ wq,
    const float* __restrict__ wk, const float* __restrict__ wv,
    const float* __restrict__ beta_g,
    float* __restrict__ qn, float* __restrict__ kn,
    float* __restrict__ kb, float* __restrict__ vb,
    float* __restrict__ v_out)
{
  int i = blockIdx.x;              // bh*Ls + l
  int t = threadIdx.x;
  int l = i & 2047, bh = i >> 11;
  int b = bh >> 2, h = bh & 3;
  int c = h * 256 + t;
  const float* p = x3 + ((size_t)b * Ls) * 3072 + c;
  float4 wq4 = *(const float4*)(wq + c * 4);
  float4 wk4 = *(const float4*)(wk + c * 4);
  float4 wv4 = *(const float4*)(wv + c * 4);
  float qw[4] = {wq4.x, wq4.y, wq4.z, wq4.w};
  float kw[4] = {wk4.x, wk4.y, wk4.z, wk4.w};
  float vw[4] = {wv4.x, wv4.y, wv4.z, wv4.w};
  float aq = 0.f, ak = 0.f, av = 0.f;
#pragma unroll
  for (int j = 0; j < 4; ++j) {
    int ls = l - 3 + j;
    if (ls >= 0) {
      size_t rb = (size_t)ls * 3072;
      aq = fmaf(qw[j], p[rb], aq);
      ak = fmaf(kw[j], p[rb + 1024], ak);
      av = fmaf(vw[j], p[rb + 2048], av);
    }
  }
  float qv = siluf_(aq), kv = siluf_(ak), vv = siluf_(av);
  float sq = qv * qv, sk = kv * kv;
#pragma unroll
  for (int off = 32; off; off >>= 1) {
    sq += __shfl_down(sq, off);
    sk += __shfl_down(sk, off);
  }
  __shared__ float rq_[4], rk_[4];
  int w = t >> 6;
  if ((t & 63) == 0) { rq_[w] = sq; rk_[w] = sk; }
  __syncthreads();
  sq = rq_[0] + rq_[1] + rq_[2] + rq_[3];
  sk = rk_[0] + rk_[1] + rk_[2] + rk_[3];
  float rq = rsqrtf(sq + 1e-6f), rk = rsqrtf(sk + 1e-6f);
  float bt = beta_g[i];
  size_t base = (size_t)i * 256 + t;
  qn[base] = qv * rq;
  kn[base] = kv * rk;
  kb[base] = kv * rk * bt;
  vb[base] = vv * bt;
  v_out[base] = vv;
}

// ------- per (b,h,chunk) MFMA: Gram, substitution, w/u applies -------------
__global__ __launch_bounds__(256) void chunk_prep(
    const float* __restrict__ kb, const float* __restrict__ kn,
    const float* __restrict__ qn, const float* __restrict__ vb,
    float* __restrict__ attn_g, float* __restrict__ u_out,
    ushort_t* __restrict__ wn_bf, ushort_t* __restrict__ q_bf,
    ushort_t* __restrict__ knT_bf, ushort_t* __restrict__ kn_bf)
{
  __shared__ float Am[32][33];
  __shared__ float Tm[32][36];
  __shared__ ushort_t KT_hi[256][40];
  __shared__ ushort_t KT_lo[256][40];
  int t = threadIdx.x;
  int cc = blockIdx.x & 63, bh = blockIdx.x >> 6;
  size_t gbase = ((size_t)bh * Ls + cc * 32) * 256;
  int wv = t >> 6, lane = t & 63;
  int l16 = lane & 15, quad = lane >> 4;
  int mi = wv >> 1, ni = wv & 1;

  floatx4 Aacc = {0.f,0.f,0.f,0.f}, Qacc = {0.f,0.f,0.f,0.f};
  {
    int mrow = mi * 16 + l16, nrow = ni * 16 + l16;
    const float* kbp = kb + gbase + (size_t)mrow * 256;
    const float* qnp = qn + gbase + (size_t)mrow * 256;
    const float* knp = kn + gbase + (size_t)nrow * 256;
#pragma unroll
    for (int ks = 0; ks < 8; ++ks) {
      int koff = ks * 32 + quad * 8;
      short8 kbh, kbl, qnh, qnl, knh, knl;
      cvt8(*(const float4*)(kbp + koff), *(const float4*)(kbp + koff + 4), kbh, kbl);
      cvt8(*(const float4*)(qnp + koff), *(const float4*)(qnp + koff + 4), qnh, qnl);
      cvt8(*(const float4*)(knp + koff), *(const float4*)(knp + koff + 4), knh, knl);
      Aacc = __builtin_amdgcn_mfma_f32_16x16x32_bf16(kbh, knh, Aacc, 0, 0, 0);
      Aacc = __builtin_amdgcn_mfma_f32_16x16x32_bf16(kbh, knl, Aacc, 0, 0, 0);
      Aacc = __builtin_amdgcn_mfma_f32_16x16x32_bf16(kbl, knh, Aacc, 0, 0, 0);
      Qacc = __builtin_amdgcn_mfma_f32_16x16x32_bf16(qnh, knh, Qacc, 0, 0, 0);
      Qacc = __builtin_amdgcn_mfma_f32_16x16x32_bf16(qnh, knl, Qacc, 0, 0, 0);
      Qacc = __builtin_amdgcn_mfma_f32_16x16x32_bf16(qnl, knh, Qacc, 0, 0, 0);
      if (ni == 0)
        *(uint4*)(q_bf + gbase + (size_t)mrow * 256 + koff) = *(uint4*)&qnh;
      if (mi == 0)
        *(uint4*)(kn_bf + gbase + (size_t)nrow * 256 + koff) = *(uint4*)&knh;
    }
  }
  float* ag = attn_g + ((size_t)bh * 64 + cc) * 1024;
#pragma unroll
  for (int r = 0; r < 4; ++r) {
    int row = mi * 16 + quad * 4 + r, col = ni * 16 + l16;
    Am[row][col] = (col < row) ? Aacc[r] : 0.f;
    ag[row * 32 + col] = (col <= row) ? Qacc[r] : 0.f;
  }
  __syncthreads();

  if (wv == 0) {
    if (t < 32) {
#pragma unroll
      for (int i = 0; i < 32; ++i) Tm[i][t] = (i == t) ? 1.f : 0.f;
      for (int i2 = 1; i2 < 32; ++i2) {
        if (t < i2) {
          float s = 0.f;
          for (int m2 = t; m2 < i2; ++m2) s = fmaf(Am[i2][m2], Tm[m2][t], s);
          Tm[i2][t] = -s;
        }
      }
    }
  } else {
    int base = t - 64;
#pragma unroll
    for (int pass = 0; pass < 2; ++pass) {
      int d = base + pass * 192;
      if (d < 256) {
        u32 hp[16], lp[16], kp2[16];
#pragma unroll
        for (int m2 = 0; m2 < 16; ++m2) {
          float f0 = kb[gbase + (size_t)(2 * m2) * 256 + d];
          float f1 = kb[gbase + (size_t)(2 * m2 + 1) * 256 + d];
          ushort_t h0 = f2bf(f0), h1 = f2bf(f1);
          hp[m2] = (u32)h0 | ((u32)h1 << 16);
          lp[m2] = (u32)f2bf(f0 - bf2f(h0)) | ((u32)f2bf(f1 - bf2f(h1)) << 16);
          float g0 = kn[gbase + (size_t)(2 * m2) * 256 + d];
          float g1 = kn[gbase + (size_t)(2 * m2 + 1) * 256 + d];
          kp2[m2] = (u32)f2bf(g0) | ((u32)f2bf(g1) << 16);
        }
#pragma unroll
        for (int q2 = 0; q2 < 4; ++q2) {
          *(uint4*)&KT_hi[d][q2 * 8] = *(uint4*)&hp[q2 * 4];
          *(uint4*)&KT_lo[d][q2 * 8] = *(uint4*)&lp[q2 * 4];
          *(uint4*)(knT_bf + gbase + (size_t)d * 32 + q2 * 8) = *(uint4*)&kp2[q2 * 4];
        }
      }
    }
  }
  __syncthreads();

  int lt = wv & 1, dgrp = wv >> 1;
  short8 Th, Tl;
  {
    int lrow = lt * 16 + l16;
    cvt8(*(const float4*)&Tm[lrow][quad * 8],
         *(const float4*)&Tm[lrow][quad * 8 + 4], Th, Tl);
  }
#pragma unroll
  for (int j = 0; j < 8; ++j) {
    int dt = dgrp * 8 + j;
    short8 Bh = *(const short8*)&KT_hi[dt * 16 + l16][quad * 8];
    short8 Bl = *(const short8*)&KT_lo[dt * 16 + l16][quad * 8];
    floatx4 acc = {0.f,0.f,0.f,0.f};
    acc = __builtin_amdgcn_mfma_f32_16x16x32_bf16(Th, Bh, acc, 0, 0, 0);
    acc = __builtin_amdgcn_mfma_f32_16x16x32_bf16(Th, Bl, acc, 0, 0, 0);
    acc = __builtin_amdgcn_mfma_f32_16x16x32_bf16(Tl, Bh, acc, 0, 0, 0);
#pragma unroll
    for (int r = 0; r < 4; ++r) {
      int row = lt * 16 + quad * 4 + r;
      wn_bf[gbase + (size_t)row * 256 + dt * 16 + l16] = f2bf(-acc[r]);
    }
  }
  __syncthreads();

  {
    int d = t;
    u32 hp[16], lp[16];
#pragma unroll
    for (int m2 = 0; m2 < 16; ++m2) {
      float f0 = vb[gbase + (size_t)(2 * m2) * 256 + d];
      float f1 = vb[gbase + (size_t)(2 * m2 + 1) * 256 + d];
      ushort_t h0 = f2bf(f0), h1 = f2bf(f1);
      hp[m2] = (u32)h0 | ((u32)h1 << 16);
      lp[m2] = (u32)f2bf(f0 - bf2f(h0)) | ((u32)f2bf(f1 - bf2f(h1)) << 16);
    }
#pragma unroll
    for (int q2 = 0; q2 < 4; ++q2) {
      *(uint4*)&KT_hi[d][q2 * 8] = *(uint4*)&hp[q2 * 4];
      *(uint4*)&KT_lo[d][q2 * 8] = *(uint4*)&lp[q2 * 4];
    }
  }
  __syncthreads();

#pragma unroll
  for (int j = 0; j < 8; ++j) {
    int dt = dgrp * 8 + j;
    short8 Bh = *(const short8*)&KT_hi[dt * 16 + l16][quad * 8];
    short8 Bl = *(const short8*)&KT_lo[dt * 16 + l16][quad * 8];
    floatx4 acc = {0.f,0.f,0.f,0.f};
    acc = __builtin_amdgcn_mfma_f32_16x16x32_bf16(Th, Bh, acc, 0, 0, 0);
    acc = __builtin_amdgcn_mfma_f32_16x16x32_bf16(Th, Bl, acc, 0, 0, 0);
    acc = __builtin_amdgcn_mfma_f32_16x16x32_bf16(Tl, Bh, acc, 0, 0, 0);
#pragma unroll
    for (int r = 0; r < 4; ++r) {
      int row = lt * 16 + quad * 4 + r;
      u_out[gbase + (size_t)row * 256 + dt * 16 + l16] = acc[r];
    }
  }
}

// ------- cross matrices per super-chunk: X = wn1 @ kn0^T, Y = q1 @ kn0^T ---
__global__ __launch_bounds__(256) void cross_prep(
    const ushort_t* __restrict__ wn_bf, const ushort_t* __restrict__ q_bf,
    const ushort_t* __restrict__ kn_bf,
    float* __restrict__ X_g, float* __restrict__ Y_g)
{
  int t = threadIdx.x;
  int sc = blockIdx.x & 31, bh = blockIdx.x >> 5;
  int wv = t >> 6, lane = t & 63;
  int l16 = lane & 15, quad = lane >> 4;
  int mi = wv >> 1, ni = wv & 1;
  size_t base = (size_t)bh * Ls * 256;
  size_t r1 = base + (size_t)(sc * 64 + 32 + mi * 16 + l16) * 256;  // chunk 2sc+1 rows
  size_t r0 = base + (size_t)(sc * 64 + ni * 16 + l16) * 256;       // chunk 2sc rows
  floatx4 Xacc = {0.f,0.f,0.f,0.f}, Yacc = {0.f,0.f,0.f,0.f};
#pragma unroll
  for (int ks = 0; ks < 8; ++ks) {
    int ko = ks * 32 + quad * 8;
    short8 aw = *(const short8*)(wn_bf + r1 + ko);
    short8 aq = *(const short8*)(q_bf  + r1 + ko);
    short8 bk = *(const short8*)(kn_bf + r0 + ko);
    Xacc = __builtin_amdgcn_mfma_f32_16x16x32_bf16(aw, bk, Xacc, 0, 0, 0);
    Yacc = __builtin_amdgcn_mfma_f32_16x16x32_bf16(aq, bk, Yacc, 0, 0, 0);
  }
  float* xo = X_g + ((size_t)bh * 32 + sc) * 1024;
  float* yo = Y_g + ((size_t)bh * 32 + sc) * 1024;
#pragma unroll
  for (int r = 0; r < 4; ++r) {
    int row = mi * 16 + quad * 4 + r, col = ni * 16 + l16;
    xo[row * 32 + col] = Xacc[r];
    yo[row * 32 + col] = Yacc[r];
  }
}

// ------- merged: chain (0-127) + FIR (128-2175) + weight convT (2176+) -----
__global__ __launch_bounds__(256, 1) void delta_fir(
    const ushort_t* __restrict__ wn_bf, const ushort_t* __restrict__ q_bf,
    const ushort_t* __restrict__ knT_bf, const float* __restrict__ attn_g,
    const float* __restrict__ u_g, const float* __restrict__ X_g,
    const float* __restrict__ Y_g, float* __restrict__ delta_g,
    const float* __restrict__ v, const float* __restrict__ wlg,
    const float* __restrict__ wsg, float* __restrict__ firl,
    float* __restrict__ firs,
    const float* __restrict__ mlpw1, ushort_t* __restrict__ w1_t,
    const float* __restrict__ Wo, ushort_t* __restrict__ wo_t)
{
  __shared__ __attribute__((aligned(16))) char smem[72704];
  int t = threadIdx.x;

  if (blockIdx.x >= 2176) {
    // -------- input-only weight transposes on idle CUs --------
    ushort_t (*tile)[33] = (ushort_t(*)[33])smem;
    const float* W; ushort_t* out; int Kq, Nq, n0, k0;
    if (blockIdx.x < 4288) {          // mlpw1 [1056][2048] -> w1_t [2048][1056]
      int local = blockIdx.x - 2176;  // 64 x 33
      W = mlpw1; out = w1_t; Kq = 1056; Nq = 2048;
      n0 = (local & 63) * 32; k0 = (local >> 6) * 32;
    } else {                          // Wo [1024][1024] -> wo_t [1024][1024]
      int local = blockIdx.x - 4288;  // 32 x 32
      W = Wo; out = wo_t; Kq = 1024; Nq = 1024;
      n0 = (local & 31) * 32; k0 = (local >> 5) * 32;
    }
    int tx = t & 31, ty = t >> 5;
#pragma unroll
    for (int r = 0; r < 32; r += 8)
      tile[ty + r][tx] = f2bf(W[(size_t)(k0 + ty + r) * Nq + n0 + tx]);
    __syncthreads();
#pragma unroll
    for (int r = 0; r < 32; r += 8)
      out[(size_t)(n0 + ty + r) * Kq + k0 + tx] = tile[tx][ty + r];
    return;
  }

  if (blockIdx.x >= 128) {
    // ---------------- FIR part ----------------
    float (*vt)[71] = (float(*)[71])smem;
    int bid = blockIdx.x - 128;
    int lt = bid & 255;
    int bh = bid >> 8;
    int b = bh >> 2, h = bh & 3;
    int l0 = lt * 8;
    const float* vp = v + (size_t)bh * Ls * 256;
    for (int r = 0; r < 70; ++r) {
      int ls = l0 - 62 + r;
      vt[t][r] = (ls >= 0) ? vp[(size_t)ls * 256 + t] : 0.f;
    }
    float TL[63], TS3[3];
#pragma unroll
    for (int j = 0; j < 63; ++j) TL[j] = wlg[((size_t)h * 256 + t) * 63 + j];
#pragma unroll
    for (int j = 0; j < 3; ++j) TS3[j] = wsg[((size_t)h * 256 + t) * 3 + j];
    __syncthreads();
    float aL[8] = {0,0,0,0,0,0,0,0}, aS[8] = {0,0,0,0,0,0,0,0};
#pragma unroll
    for (int r = 0; r < 70; ++r) {
      float vm = vt[t][r];
#pragma unroll
      for (int p = 0; p < 8; ++p) {
        int jl = r - p;
        if (jl >= 0 && jl < 63) aL[p] = fmaf(vm, TL[jl], aL[p]);
        int jssrc = r - 60 - p;
        if (jssrc >= 0 && jssrc < 3) aS[p] = fmaf(vm, TS3[jssrc], aS[p]);
      }
    }
#pragma unroll
    for (int p = 0; p < 8; ++p) {
      int l = l0 + p;
      size_t ob = (((size_t)b * Ls + l) * NH + h) * 256 + t;
      firl[ob] = aL[p];
      firs[ob] = aS[p];
    }
    return;
  }

  // ---------------- chain part (m=2 super-chunks) ----------------
  ushort_t (*Shi)[264] = (ushort_t(*)[264])(smem);
  ushort_t (*Slo)[264] = (ushort_t(*)[264])(smem + 8448);
  float (*u2L0)[17] = (float(*)[17])(smem + 16896);
  float (*u2L1)[17] = (float(*)[17])(smem + 19072);
  int bh = blockIdx.x & 7, g = blockIdx.x >> 3;
  int b = bh >> 2, h = bh & 3;
  int wv = t >> 6, lane = t & 63;
  int lquad = lane >> 4, l16 = lane & 15;
  int j0 = g * 16;
  int Mt = wv & 1;
  bool isU = (wv < 2);
  const ushort_t* wp = wn_bf + (size_t)bh * Ls * 256;
  const ushort_t* qp = q_bf  + (size_t)bh * Ls * 256;
  const ushort_t* ap = (isU ? wp : qp) + (size_t)(Mt * 16 + l16) * 256;
  const ushort_t* kr = knT_bf + (size_t)bh * Ls * 256 + (size_t)l16 * 32 + lquad * 8;
  const float* urow = u_g + (size_t)bh * Ls * 256
                    + (size_t)(Mt * 16 + lquad * 4) * 256 + j0 + l16;
  const float* arp = attn_g + (size_t)bh * 64 * 1024
                   + (size_t)(Mt * 16 + l16) * 32 + lquad * 8;
  const float* xrp = (isU ? X_g : Y_g) + (size_t)bh * 32768
                   + (size_t)(Mt * 16 + l16) * 32 + lquad * 8;

  floatx4 Sacc[4], SaccL[4];
#pragma unroll
  for (int i = 0; i < 4; ++i)
#pragma unroll
    for (int r = 0; r < 4; ++r) { Sacc[i][r] = 0.f; SaccL[i][r] = 0.f; }
  for (int i = t; i < 4224; i += 256) ((u32*)smem)[i] = 0;

  // prologue: super-chunk 0, sub-chunk 0 operands
  short8 a0[8], k0[4];
  floatx4 u0 = {0.f, 0.f, 0.f, 0.f};
  float4 at0a = {0,0,0,0}, at0b = {0,0,0,0};
#pragma unroll
  for (int ks = 0; ks < 8; ++ks)
    a0[ks] = *(const short8*)(ap + ks * 32 + lquad * 8);
#pragma unroll
  for (int i = 0; i < 4; ++i)
    k0[i] = *(const short8*)(kr + (size_t)(wv * 4 + i) * 512);
  if (isU) {
#pragma unroll
    for (int r = 0; r < 4; ++r) u0[r] = urow[(size_t)r * 256];
  } else {
    at0a = *(const float4*)(arp);
    at0b = *(const float4*)(arp + 4);
  }
  wave_barrier();

  for (int sc = 0; sc < 32; ++sc) {
    size_t cb1 = (size_t)sc * 16384 + 8192;
    size_t nb0 = (size_t)(sc + 1) * 16384;
    bool hasN = (sc + 1 < 32);

    // sub-chunk1 operands + cross matrix (used mid-iteration; latency covered)
    short8 a1[8], k1[4];
    floatx4 u1 = {0.f, 0.f, 0.f, 0.f};
    float4 at1a = {0,0,0,0}, at1b = {0,0,0,0};
#pragma unroll
    for (int ks = 0; ks < 8; ++ks)
      a1[ks] = *(const short8*)(ap + cb1 + ks * 32 + lquad * 8);
#pragma unroll
    for (int i = 0; i < 4; ++i)
      k1[i] = *(const short8*)(kr + cb1 + (size_t)(wv * 4 + i) * 512);
    if (isU) {
#pragma unroll
      for (int r = 0; r < 4; ++r) u1[r] = urow[cb1 + (size_t)r * 256];
    } else {
      size_t na = (size_t)(2 * sc + 1) * 1024;
      at1a = *(const float4*)(arp + na);
      at1b = *(const float4*)(arp + na + 4);
    }
    float4 xa = *(const float4*)(xrp + (size_t)sc * 1024);
    float4 xb = *(const float4*)(xrp + (size_t)sc * 1024 + 4);

    // ---- sub-chunk 0: u2_0 (isU) / po_0 (o) against S0 ----
    floatx4 acc0;
    if (isU) {
      floatx4 A0 = u0, A1 = {0,0,0,0}, A2 = {0,0,0,0}, A3 = {0,0,0,0};
#pragma unroll
      for (int ks = 0; ks < 8; ++ks) {
        short8 sh = *(const short8*)&Shi[l16][ks * 32 + lquad * 8];
        short8 sl = *(const short8*)&Slo[l16][ks * 32 + lquad * 8];
        if (ks & 1) {
          A1 = __builtin_amdgcn_mfma_f32_16x16x32_bf16(a0[ks], sh, A1, 0, 0, 0);
          A3 = __builtin_amdgcn_mfma_f32_16x16x32_bf16(a0[ks], sl, A3, 0, 0, 0);
        } else {
          A0 = __builtin_amdgcn_mfma_f32_16x16x32_bf16(a0[ks], sh, A0, 0, 0, 0);
          A2 = __builtin_amdgcn_mfma_f32_16x16x32_bf16(a0[ks], sl, A2, 0, 0, 0);
        }
      }
#pragma unroll
      for (int r = 0; r < 4; ++r) acc0[r] = (A0[r] + A1[r]) + (A2[r] + A3[r]);
#pragma unroll
      for (int r = 0; r < 4; ++r)
        u2L0[Mt * 16 + lquad * 4 + r][l16] = acc0[r];
    } else {
      floatx4 A0 = {0,0,0,0}, A1 = {0,0,0,0};
#pragma unroll
      for (int ks = 0; ks < 8; ++ks) {
        short8 sh = *(const short8*)&Shi[l16][ks * 32 + lquad * 8];
        if (ks & 1) A1 = __builtin_amdgcn_mfma_f32_16x16x32_bf16(a0[ks], sh, A1, 0, 0, 0);
        else        A0 = __builtin_amdgcn_mfma_f32_16x16x32_bf16(a0[ks], sh, A0, 0, 0, 0);
      }
#pragma unroll
      for (int r = 0; r < 4; ++r) acc0[r] = A0[r] + A1[r];
    }
    // prefetch next-super-chunk a0 (a0 regs dead; stays in flight across
    // the raw barriers below -> ~full iteration of latency cover)
    if (hasN) {
#pragma unroll
      for (int ks = 0; ks < 8; ++ks)
        a0[ks] = *(const short8*)(ap + nb0 + ks * 32 + lquad * 8);
    }
    wave_barrier();                          // u2_0 visible

    short8 uh0, ul0;
#pragma unroll
    for (int j = 0; j < 8; ++j) {
      float f = u2L0[lquad * 8 + j][l16];
      ushort_t hi = f2bf(f);
      uh0[j] = (short)hi;
      ul0[j] = (short)f2bf(f - bf2f(hi));
    }
#pragma unroll
    for (int i = 0; i < 4; ++i) {
      Sacc[i]  = __builtin_amdgcn_mfma_f32_16x16x32_bf16(k0[i], uh0, Sacc[i], 0, 0, 0);
      SaccL[i] = __builtin_amdgcn_mfma_f32_16x16x32_bf16(k0[i], ul0, SaccL[i], 0, 0, 0);
    }
    if (hasN) {
#pragma unroll
      for (int i = 0; i < 4; ++i)
        k0[i] = *(const short8*)(kr + nb0 + (size_t)(wv * 4 + i) * 512);
    }

    // ---- sub-chunk 1: u2_1 = u1 + wn1@S0 + X@u2_0 / o path ----
    floatx4 acc1;
    if (isU) {
      floatx4 A0 = u1, A1 = {0,0,0,0}, A2 = {0,0,0,0}, A3 = {0,0,0,0};
#pragma unroll
      for (int ks = 0; ks < 8; ++ks) {
        short8 sh = *(const short8*)&Shi[l16][ks * 32 + lquad * 8];
        short8 sl = *(const short8*)&Slo[l16][ks * 32 + lquad * 8];
        if (ks & 1) {
          A1 = __builtin_amdgcn_mfma_f32_16x16x32_bf16(a1[ks], sh, A1, 0, 0, 0);
          A3 = __builtin_amdgcn_mfma_f32_16x16x32_bf16(a1[ks], sl, A3, 0, 0, 0);
        } else {
          A0 = __builtin_amdgcn_mfma_f32_16x16x32_bf16(a1[ks], sh, A0, 0, 0, 0);
          A2 = __builtin_amdgcn_mfma_f32_16x16x32_bf16(a1[ks], sl, A2, 0, 0, 0);
        }
      }
      short8 Xh, Xl;
      cvt8(xa, xb, Xh, Xl);
      A0 = __builtin_amdgcn_mfma_f32_16x16x32_bf16(Xh, uh0, A0, 0, 0, 0);
      A1 = __builtin_amdgcn_mfma_f32_16x16x32_bf16(Xh, ul0, A1, 0, 0, 0);
      A2 = __builtin_amdgcn_mfma_f32_16x16x32_bf16(Xl, uh0, A2, 0, 0, 0);
#pragma unroll
      for (int r = 0; r < 4; ++r) acc1[r] = (A0[r] + A1[r]) + (A2[r] + A3[r]);
#pragma unroll
      for (int r = 0; r < 4; ++r)
        u2L1[Mt * 16 + lquad * 4 + r][l16] = acc1[r];
      if (hasN) {
#pragma unroll
        for (int r = 0; r < 4; ++r) u0[r] = urow[nb0 + (size_t)r * 256];
      }
    } else {
      // o_0 = po_0 + attn_0 @ u2_0 -> store
      short8 ath, atl;
      cvt8(at0a, at0b, ath, atl);
      acc0 = __builtin_amdgcn_mfma_f32_16x16x32_bf16(ath, uh0, acc0, 0, 0, 0);
      acc0 = __builtin_amdgcn_mfma_f32_16x16x32_bf16(ath, ul0, acc0, 0, 0, 0);
      acc0 = __builtin_amdgcn_mfma_f32_16x16x32_bf16(atl, uh0, acc0, 0, 0, 0);
#pragma unroll
      for (int r = 0; r < 4; ++r) {
        int l = sc * 64 + Mt * 16 + lquad * 4 + r;
        delta_g[(((size_t)b * Ls + l) * NH + h) * 256 + j0 + l16] = acc0[r];
      }
      // po_1 = q1 @ Shi(S0) + Y @ u2_0
      floatx4 A0 = {0,0,0,0}, A1 = {0,0,0,0};
#pragma unroll
      for (int ks = 0; ks < 8; ++ks) {
        short8 sh = *(const short8*)&Shi[l16][ks * 32 + lquad * 8];
        if (ks & 1) A1 = __builtin_amdgcn_mfma_f32_16x16x32_bf16(a1[ks], sh, A1, 0, 0, 0);
        else        A0 = __builtin_amdgcn_mfma_f32_16x16x32_bf16(a1[ks], sh, A0, 0, 0, 0);
      }
      short8 Yh, Yl;
      cvt8(xa, xb, Yh, Yl);
      A0 = __builtin_amdgcn_mfma_f32_16x16x32_bf16(Yh, uh0, A0, 0, 0, 0);
      A1 = __builtin_amdgcn_mfma_f32_16x16x32_bf16(Yh, ul0, A1, 0, 0, 0);
      A0 = __builtin_amdgcn_mfma_f32_16x16x32_bf16(Yl, uh0, A0, 0, 0, 0);
#pragma unroll
      for (int r = 0; r < 4; ++r) acc1[r] = A0[r] + A1[r];
      if (hasN) {
        size_t na0 = (size_t)(2 * sc + 2) * 1024;
        at0a = *(const float4*)(arp + na0);
        at0b = *(const float4*)(arp + na0 + 4);
      }
    }
    wave_barrier();                          // u2_1 visible; all Shi/Slo reads done

    short8 uh1, ul1;
#pragma unroll
    for (int j = 0; j < 8; ++j) {
      float f = u2L1[lquad * 8 + j][l16];
      ushort_t hi = f2bf(f);
      uh1[j] = (short)hi;
      ul1[j] = (short)f2bf(f - bf2f(hi));
    }
#pragma unroll
    for (int i = 0; i < 4; ++i) {
      Sacc[i]  = __builtin_amdgcn_mfma_f32_16x16x32_bf16(k1[i], uh1, Sacc[i], 0, 0, 0);
      SaccL[i] = __builtin_amdgcn_mfma_f32_16x16x32_bf16(k1[i], ul1, SaccL[i], 0, 0, 0);
    }
    if (!isU) {
      short8 ath, atl;
      cvt8(at1a, at1b, ath, atl);
      acc1 = __builtin_amdgcn_mfma_f32_16x16x32_bf16(ath, uh1, acc1, 0, 0, 0);
      acc1 = __builtin_amdgcn_mfma_f32_16x16x32_bf16(ath, ul1, acc1, 0, 0, 0);
      acc1 = __builtin_amdgcn_mfma_f32_16x16x32_bf16(atl, uh1, acc1, 0, 0, 0);
#pragma unroll
      for (int r = 0; r < 4; ++r) {
        int l = sc * 64 + 32 + Mt * 16 + lquad * 4 + r;
        delta_g[(((size_t)b * Ls + l) * NH + h) * 256 + j0 + l16] = acc1[r];
      }
    }
    // S write-back (once per 64 tokens)
#pragma unroll
    for (int i = 0; i < 4; ++i) {
      int dk0 = (wv * 4 + i) * 16 + lquad * 4;
      ushort4 h4, l4;
      ushort_t* hp = (ushort_t*)&h4;
      ushort_t* lp = (ushort_t*)&l4;
#pragma unroll
      for (int r = 0; r < 4; ++r) {
        float sv = Sacc[i][r] + SaccL[i][r];
        ushort_t hi = f2bf(sv);
        hp[r] = hi;
        lp[r] = f2bf(sv - bf2f(hi));
      }
      *(ushort4*)&Shi[l16][dk0] = h4;
      *(ushort4*)&Slo[l16][dk0] = l4;
    }
    wave_barrier();                          // S visible
  }
}

// ------- gate_in (bf16) ----------------------------------------------------
__global__ __launch_bounds__(256) void build_gate_in_bf(
    const float* __restrict__ x, const float* __restrict__ firs,
    const float* __restrict__ firl, const float* __restrict__ delta,
    const float* __restrict__ v, ushort_t* __restrict__ gin)
{
  int mtok = blockIdx.x, t = threadIdx.x;
  int b = mtok >> 11, l = mtok & 2047;
  float4 xv = *(const float4*)(x + (size_t)mtok * 1024 + t * 4);
  ushort4 xo = make_ushort4(f2bf(xv.x), f2bf(xv.y), f2bf(xv.z), f2bf(xv.w));
  *(ushort4*)(gin + (size_t)mtok * 1056 + t * 4) = xo;
  int w = t >> 6, lane = t & 63;
  for (int br = 0; br < 4; ++br) {
    float s = 0.f, s2 = 0.f;
#pragma unroll
    for (int r = 0; r < 4; ++r) {
      int d = lane + r * 64;
      float val;
      if (br == 0)      val = firs [(size_t)mtok * 1024 + w * 256 + d];
      else if (br == 1) val = firl [(size_t)mtok * 1024 + w * 256 + d];
      else if (br == 2) val = delta[(size_t)mtok * 1024 + w * 256 + d];
      else              val = v[(((size_t)(b * NH + w)) * Ls + l) * 256 + d];
      s += val; s2 = fmaf(val, val, s2);
    }
#pragma unroll
    for (int off = 32; off; off >>= 1) {
      s += __shfl_down(s, off);
      s2 += __shfl_down(s2, off);
    }
    if (lane == 0) {
      float mean = s * (1.f / 256.f);
      float var = s2 * (1.f / 256.f) - mean * mean;
      gin[(size_t)mtok * 1056 + 1024 + br * 8 + w] = f2bf(mean);
      gin[(size_t)mtok * 1056 + 1024 + br * 8 + 4 + w] = f2bf(sqrtf(fmaxf(var, 1e-6f)));
    }
  }
}

// ------- logits -> gates (bf16 hidden input) -------------------------------
__global__ __launch_bounds__(256) void mlp2_gates(
    const ushort_t* __restrict__ mh, const float* __restrict__ W2,
    const float* __restrict__ b2, const float* __restrict__ glt,
    float* __restrict__ gates)
{
  int mtok = blockIdx.x, t = threadIdx.x;
  float p[16];
#pragma unroll
  for (int j = 0; j < 16; ++j) p[j] = 0.f;
  for (int k = t; k < 2048; k += 256) {
    float hv = bf2f(mh[(size_t)mtok * 2048 + k]);
    const float* wr = W2 + (size_t)k * 16;
#pragma unroll
    for (int j4 = 0; j4 < 4; ++j4) {
      float4 w4 = *(const float4*)(wr + j4 * 4);
      p[j4*4+0] = fmaf(hv, w4.x, p[j4*4+0]);
      p[j4*4+1] = fmaf(hv, w4.y, p[j4*4+1]);
      p[j4*4+2] = fmaf(hv, w4.z, p[j4*4+2]);
      p[j4*4+3] = fmaf(hv, w4.w, p[j4*4+3]);
    }
  }
#pragma unroll
  for (int j = 0; j < 16; ++j)
#pragma unroll
    for (int off = 32; off; off >>= 1) p[j] += __shfl_down(p[j], off);
  __shared__ float red[4][16];
  __shared__ float zl[16];
  int w = t >> 6;
  if ((t & 63) == 0) {
#pragma unroll
    for (int j = 0; j < 16; ++j) red[w][j] = p[j];
  }
  __syncthreads();
  if (t < 16) {
    float tot = red[0][t] + red[1][t] + red[2][t] + red[3][t] + b2[t];
    float tempv = log1pf(expf(glt[t >> 2])) + 1e-4f;
    zl[t] = tot / tempv;
  }
  __syncthreads();
  if (t < 4) {
    float z0 = zl[t*4], z1 = zl[t*4+1], z2 = zl[t*4+2], z3 = zl[t*4+3];
    float mx = fmaxf(fmaxf(z0, z1), fmaxf(z2, z3));
    float e0 = expf(z0 - mx), e1 = expf(z1 - mx), e2 = expf(z2 - mx), e3 = expf(z3 - mx);
    float inv = 1.f / (e0 + e1 + e2 + e3);
    gates[(size_t)mtok * 16 + t * 4 + 0] = e0 * inv;
    gates[(size_t)mtok * 16 + t * 4 + 1] = e1 * inv;
    gates[(size_t)mtok * 16 + t * 4 + 2] = e2 * inv;
    gates[(size_t)mtok * 16 + t * 4 + 3] = e3 * inv;
  }
}

// ------- o = gated mix, RMSNorm -> bf16 ------------------------------------
__global__ __launch_bounds__(256) void combine_norm_bf(
    const float* __restrict__ firs, const float* __restrict__ firl,
    const float* __restrict__ delta, const float* __restrict__ v,
    const float* __restrict__ gates, const float* __restrict__ onw,
    ushort_t* __restrict__ o)
{
  int mh = blockIdx.x;
  int mtok = mh >> 2, h = mh & 3;
  int t = threadIdx.x;
  int b = mtok >> 11, l = mtok & 2047;
  const float* g = gates + (size_t)mtok * 16 + h * 4;
  float w0 = g[0], w1 = g[1], w2 = g[2], w3 = g[3];
  size_t tb = (size_t)mtok * 1024 + h * 256 + t;
  float val = w0 * firs[tb] + w1 * firl[tb] + w2 * delta[tb]
            + w3 * v[(((size_t)(b * NH + h)) * Ls + l) * 256 + t];
  float s2 = val * val;
#pragma unroll
  for (int off = 32; off; off >>= 1) s2 += __shfl_down(s2, off);
  __shared__ float r4[4];
  if ((t & 63) == 0) r4[t >> 6] = s2;
  __syncthreads();
  float tot = r4[0] + r4[1] + r4[2] + r4[3];
  float rms = rsqrtf(tot * (1.f / 256.f) + 1e-5f);
  o[tb] = f2bf(val * rms * onw[t]);
}

// ---------------------------------------------------------------------------
extern "C" void kernel_launch(void* const* d_in, const int* in_sizes, int n_in,
                              void* d_out, int out_size, void* d_ws, size_t ws_size,
                              hipStream_t stream) {
  const float* x     = (const float*)d_in[0];
  const float* Wq    = (const float*)d_in[1];
  const float* Wk    = (const float*)d_in[2];
  const float* Wv    = (const float*)d_in[3];
  const float* Wb    = (const float*)d_in[4];
  const float* convq = (const float*)d_in[5];
  const float* convk = (const float*)d_in[6];
  const float* convv = (const float*)d_in[7];
  const float* firsw = (const float*)d_in[8];
  const float* firlw = (const float*)d_in[9];
  const float* mlpw1 = (const float*)d_in[10];
  const float* mlpb1 = (const float*)d_in[11];
  const float* mlpw2 = (const float*)d_in[12];
  const float* mlpb2 = (const float*)d_in[13];
  const float* glt   = (const float*)d_in[14];
  const float* onw   = (const float*)d_in[15];
  const float* Wo    = (const float*)d_in[16];
  float* ws = (float*)d_ws;

  ushort_t* x_bf   = (ushort_t*)(ws + off_firs);
  ushort_t* Wqkv_t = (ushort_t*)(ws + off_firl);  // 3 x [1024][1024] contiguous
  ushort_t* gin_bf = (ushort_t*)(ws + off_gin);
  ushort_t* w1_t   = (ushort_t*)(ws + off_k);     // kn dead after chunk_prep
  ushort_t* o_bf   = (ushort_t*)(ws + off_xv);
  ushort_t* Wo_t   = (ushort_t*)(ws + off_wot);   // never-aliased window
  ushort_t* mlph_bf= (ushort_t*)(ws + off_mlph);
  ushort_t* wn_bf  = (ushort_t*)(ws + off_firs);
  ushort_t* q_bf   = (ushort_t*)(ws + off_firs + 2097152);
  ushort_t* knT_bf = (ushort_t*)(ws + off_firl);
  ushort_t* kn_bf  = (ushort_t*)(ws + off_xq);    // x3 dead after conv_prep
  float* x3   = ws + off_xq;     // fused [4096][3072] spans xq/xk/xv
  float* kb_f = ws + off_gin;
  float* vb_f = ws + off_mlph;
  float* X_g  = ws + off_gin;            // kb dead after chunk_prep; 8*32*1024 f32
  float* Y_g  = ws + off_gin + 262144;
  float* firs_f = ws + off_xq;   // x3/kn_bf dead after cross_prep
  float* firl_f = ws + off_xk;

  dim3 blk(256);
  // fused q/k/v projection (one N=3072 GEMM) + beta
  to_bf16<<<2048, blk, 0, stream>>>(x, x_bf, 4194304);
  convT<<<dim3(32, 32), blk, 0, stream>>>(Wq, Wqkv_t, 1024, 1024);
  convT<<<dim3(32, 32), blk, 0, stream>>>(Wk, Wqkv_t + 1048576, 1024, 1024);
  convT<<<dim3(32, 32), blk, 0, stream>>>(Wv, Wqkv_t + 2097152, 1024, 1024);
  gemm_bf16<<<dim3(24, 32), blk, 0, stream>>>(x_bf, Wqkv_t, x3, 3072, 1024, nullptr, 0, 0);
  beta_sigmoid<<<4096, blk, 0, stream>>>(x, Wb, ws + off_beta);
  // fused conv4+silu + l2norm + beta products
  conv_prep<<<16384, blk, 0, stream>>>(x3, convq, convk, convv, ws + off_beta,
                                       ws + off_q, ws + off_k, kb_f, vb_f, ws + off_v);
  // per-chunk T inverse, attn, u (->xv), bf16 {-w, q, knT, kn}
  chunk_prep<<<512, blk, 0, stream>>>(kb_f, ws + off_k, ws + off_q, vb_f,
                                      ws + off_attn, ws + off_xv, wn_bf, q_bf,
                                      knT_bf, kn_bf);
  // 32x32 cross matrices per super-chunk (X = wn1 kn0^T, Y = q1 kn0^T)
  cross_prep<<<256, blk, 0, stream>>>(wn_bf, q_bf, kn_bf, X_g, Y_g);
  // merged serial MFMA scan + FIR + input-only weight transposes (idle CUs)
  delta_fir<<<5312, blk, 0, stream>>>(wn_bf, q_bf, knT_bf, ws + off_attn,
                                      ws + off_xv, X_g, Y_g, ws + off_q,
                                      ws + off_v, firlw, firsw, firl_f, firs_f,
                                      mlpw1, w1_t, Wo, Wo_t);
  // gate input (bf16), MLP1 (MFMA, gelu, bf16 out), gates
  build_gate_in_bf<<<4096, blk, 0, stream>>>(x, firs_f, firl_f, ws + off_q,
                                             ws + off_v, gin_bf);
  gemm_bf16<<<dim3(16, 32), blk, 0, stream>>>(gin_bf, w1_t, (float*)mlph_bf,
                                              2048, 1056, mlpb1, 1, 1);
  mlp2_gates<<<4096, blk, 0, stream>>>(mlph_bf, mlpw2, mlpb2, glt, ws + off_gates);
  // combine + RMSNorm -> bf16, output projection (MFMA)
  combine_norm_bf<<<16384, blk, 0, stream>>>(firs_f, firl_f, ws + off_q,
                                             ws + off_v, ws + off_gates, onw, o_bf);
  gemm_bf16<<<dim3(8, 32), blk, 0, stream>>>(o_bf, Wo_t, (float*)d_out, 1024, 1024, nullptr, 0, 0);
}